// Round 14
// baseline (494.503 us; speedup 1.0000x reference)
//
#include <hip/hip_runtime.h>
#include <hip/hip_fp16.h>
#include <hip/hip_cooperative_groups.h>
#include <math.h>

namespace cg = cooperative_groups;

#define NN 4096
#define FF 32
#define DD 16
#define EE 65536

__device__ __forceinline__ int l_of(int i){ return (i==0)?0:(i<4)?1:(i<9)?2:3; }
__device__ __forceinline__ float silu(float v){ return v/(1.f+expf(-v)); }

// ---------- x = per_l_linear(node_feats, W_up), 4 nodes/block ----------
__global__ __launch_bounds__(512) void k_x(const float* __restrict__ feats,
        const float* __restrict__ Wup, float* __restrict__ x){
  __shared__ float sF[4*512];
  __shared__ float sW[4*FF*FF];
  int n0 = blockIdx.x*4, t = threadIdx.x;
  #pragma unroll
  for(int q=0;q<4;q++) sF[q*512+t] = feats[(size_t)(n0+q)*512 + t];
  for (int k=t;k<4*FF*FF;k+=512) sW[k]=Wup[k];
  __syncthreads();
  int f = t>>4, i = t&15;
  const float* W = &sW[l_of(i)*FF*FF];
  #pragma unroll
  for(int q=0;q<4;q++){
    float a=0.f;
    #pragma unroll
    for (int c=0;c<FF;c++) a += sF[q*512 + c*DD+i]*W[c*FF+f];
    x[(size_t)(n0+q)*512 + t] = a;
  }
}

// ---------- cooperative prep: compact + zero -> count -> scan -> fill -> sort ----------
__global__ __launch_bounds__(256) void k_prep(
    const float* __restrict__ U3, const float* __restrict__ U2, const float* __restrict__ U1,
    int* __restrict__ u3i, float* __restrict__ u3v,
    int* __restrict__ u2i, float* __restrict__ u2v,
    int* __restrict__ u1i, float* __restrict__ u1v, int* __restrict__ uoff,
    const int* __restrict__ recv, const int* __restrict__ senders,
    int* __restrict__ cnt, int* __restrict__ off, int* __restrict__ pos,
    int* __restrict__ elist, int* __restrict__ epos, int* __restrict__ ssend)
{
  cg::grid_group grid = cg::this_grid();
  __shared__ int shmem[2048];
  int t=threadIdx.x, b=blockIdx.x;
  int gid = b*256+t;                 // 65536 threads == EE

  // phase 0: zero cnt (one pass) + U-compact on blocks 0..2
  if (gid < NN) cnt[gid] = 0;
  if (b < 3){
    const float* src; int nsz; int* oi; float* ov; int slot=b;
    if(slot==0){src=U3;nsz=16384;oi=u3i;ov=u3v;}
    else if(slot==1){src=U2;nsz=1024;oi=u2i;ov=u2v;}
    else {src=U1;nsz=64;oi=u1i;ov=u1v;}
    int (*cnts)[4]  = (int(*)[4])shmem;
    int (*bases)[4] = (int(*)[4])(shmem+1024);
    int chunk=(nsz+255)/256;
    int lo=t*chunk, hi=min(nsz,lo+chunk); if(lo>nsz) lo=nsz;
    int c0=0,c1=0,c2=0,c3=0;
    for(int q=lo;q<hi;q++) if(src[q]!=0.f){
      int i=q&3;
      if(i==0)c0++; else if(i==1)c1++; else if(i==2)c2++; else c3++;
    }
    cnts[t][0]=c0; cnts[t][1]=c1; cnts[t][2]=c2; cnts[t][3]=c3;
    __syncthreads();
    if(t==0){
      int a=0;
      for(int i=0;i<4;i++){ uoff[slot*5+i]=a;
        for(int q=0;q<256;q++){ bases[q][i]=a; a+=cnts[q][i]; } }
      uoff[slot*5+4]=a;
    }
    __syncthreads();
    int w0=bases[t][0], w1_=bases[t][1], w2_=bases[t][2], w3_=bases[t][3];
    for(int q=lo;q<hi;q++){ float v=src[q]; if(v!=0.f){
      int i=q&3;
      if(i==0){ oi[w0]=q; ov[w0]=v; w0++; }
      else if(i==1){ oi[w1_]=q; ov[w1_]=v; w1_++; }
      else if(i==2){ oi[w2_]=q; ov[w2_]=v; w2_++; }
      else { oi[w3_]=q; ov[w3_]=v; w3_++; }
    } }
  }
  grid.sync();

  // phase 1: count (gid == edge id, exactly EE threads)
  pos[gid] = atomicAdd(&cnt[recv[gid]], 1);
  grid.sync();

  // phase 2: scan (block 0)
  if (b==0){
    int* sums = shmem; int* bss = shmem+256;
    int local[16]; int s=0;
    #pragma unroll
    for(int k=0;k<16;k++){ local[k]=cnt[t*16+k]; s+=local[k]; }
    sums[t]=s; __syncthreads();
    if(t==0){ int a=0; for(int q=0;q<256;q++){ bss[q]=a; a+=sums[q]; } }
    __syncthreads();
    int acc=bss[t];
    #pragma unroll
    for(int k=0;k<16;k++){ off[t*16+k]=acc; acc+=local[k]; }
    if(t==255) off[NN]=acc;
  }
  grid.sync();

  // phase 3: fill
  elist[off[recv[gid]]+pos[gid]] = gid;
  grid.sync();

  // phase 4: sort -> epos, ssend (wave per node, grid-stride)
  {
    int w=t>>6, l=t&63;
    int* buf = shmem;   // per-wave slice [w*256 .. w*256+255]
    for (int n = b*4 + w; n < NN; n += 1024){
      int base = off[n];
      int deg = off[n+1]-base; if (deg>256) deg=256;
      for(int d=l; d<deg; d+=64) buf[w*256+d]=elist[base+d];
      for(int d=l; d<deg; d+=64){
        int v=buf[w*256+d]; int r=0;
        for(int q=0;q<deg;q++) r += (buf[w*256+q]<v);
        epos[v] = base + r;
        ssend[base+r] = senders[v];
      }
    }
  }
}

// ---------- radial MLP -> mix_h (fp16, sorted slots) + fused YM phase ----------
__global__ __launch_bounds__(256) void k_mix(const float* __restrict__ rad,
    const float* __restrict__ W1, const float* __restrict__ W2,
    const float* __restrict__ W3, const float* __restrict__ W4,
    const int* __restrict__ epos, __half* __restrict__ mix_h,
    const float* __restrict__ vec, const float* __restrict__ CG,
    __half* __restrict__ M_h){
  __shared__ float sRadT[8*68];
  __shared__ float sW1[8*64];
  __shared__ float sHA[64*68];
  __shared__ float sHB[64*68];
  int t = threadIdx.x;
  int be = blockIdx.x*64;
  for (int k=t;k<8*64;k+=256) sW1[k]=W1[k];
  for (int idx=t; idx<64*8; idx+=256){ int e=idx>>3, k=idx&7; sRadT[k*68+e]=rad[(size_t)(be+e)*8+k]; }
  __syncthreads();
  int e0 = (t>>4)*4, j0 = (t&15)*4;
  {
    float acc[4][4];
    #pragma unroll
    for(int a=0;a<4;a++){ acc[a][0]=0;acc[a][1]=0;acc[a][2]=0;acc[a][3]=0; }
    #pragma unroll
    for(int k=0;k<8;k++){
      float4 h = *(const float4*)&sRadT[k*68+e0];
      float4 w = *(const float4*)&sW1[k*64+j0];
      acc[0][0]+=h.x*w.x; acc[0][1]+=h.x*w.y; acc[0][2]+=h.x*w.z; acc[0][3]+=h.x*w.w;
      acc[1][0]+=h.y*w.x; acc[1][1]+=h.y*w.y; acc[1][2]+=h.y*w.z; acc[1][3]+=h.y*w.w;
      acc[2][0]+=h.z*w.x; acc[2][1]+=h.z*w.y; acc[2][2]+=h.z*w.z; acc[2][3]+=h.z*w.w;
      acc[3][0]+=h.w*w.x; acc[3][1]+=h.w*w.y; acc[3][2]+=h.w*w.z; acc[3][3]+=h.w*w.w;
    }
    #pragma unroll
    for(int b=0;b<4;b++){
      float4 v; v.x=silu(acc[0][b]); v.y=silu(acc[1][b]); v.z=silu(acc[2][b]); v.w=silu(acc[3][b]);
      *(float4*)&sHA[(j0+b)*68+e0] = v;
    }
  }
  __syncthreads();
  {
    float acc[4][4];
    #pragma unroll
    for(int a=0;a<4;a++){ acc[a][0]=0;acc[a][1]=0;acc[a][2]=0;acc[a][3]=0; }
    for(int k=0;k<64;k++){
      float4 h = *(const float4*)&sHA[k*68+e0];
      float4 w = *(const float4*)&W2[k*64+j0];
      acc[0][0]+=h.x*w.x; acc[0][1]+=h.x*w.y; acc[0][2]+=h.x*w.z; acc[0][3]+=h.x*w.w;
      acc[1][0]+=h.y*w.x; acc[1][1]+=h.y*w.y; acc[1][2]+=h.y*w.z; acc[1][3]+=h.y*w.w;
      acc[2][0]+=h.z*w.x; acc[2][1]+=h.z*w.y; acc[2][2]+=h.z*w.z; acc[2][3]+=h.z*w.w;
      acc[3][0]+=h.w*w.x; acc[3][1]+=h.w*w.y; acc[3][2]+=h.w*w.z; acc[3][3]+=h.w*w.w;
    }
    #pragma unroll
    for(int b=0;b<4;b++){
      float4 v; v.x=silu(acc[0][b]); v.y=silu(acc[1][b]); v.z=silu(acc[2][b]); v.w=silu(acc[3][b]);
      *(float4*)&sHB[(j0+b)*68+e0] = v;
    }
  }
  __syncthreads();
  {
    float acc[4][4];
    #pragma unroll
    for(int a=0;a<4;a++){ acc[a][0]=0;acc[a][1]=0;acc[a][2]=0;acc[a][3]=0; }
    for(int k=0;k<64;k++){
      float4 h = *(const float4*)&sHB[k*68+e0];
      float4 w = *(const float4*)&W3[k*64+j0];
      acc[0][0]+=h.x*w.x; acc[0][1]+=h.x*w.y; acc[0][2]+=h.x*w.z; acc[0][3]+=h.x*w.w;
      acc[1][0]+=h.y*w.x; acc[1][1]+=h.y*w.y; acc[1][2]+=h.y*w.z; acc[1][3]+=h.y*w.w;
      acc[2][0]+=h.z*w.x; acc[2][1]+=h.z*w.y; acc[2][2]+=h.z*w.z; acc[2][3]+=h.z*w.w;
      acc[3][0]+=h.w*w.x; acc[3][1]+=h.w*w.y; acc[3][2]+=h.w*w.z; acc[3][3]+=h.w*w.w;
    }
    #pragma unroll
    for(int b=0;b<4;b++){
      float4 v; v.x=silu(acc[0][b]); v.y=silu(acc[1][b]); v.z=silu(acc[2][b]); v.w=silu(acc[3][b]);
      *(float4*)&sHA[(j0+b)*68+e0] = v;
    }
  }
  __syncthreads();
  {
    int cc0 = (t&63)*4, g = t>>6;
    float acc[4][4][4];
    #pragma unroll
    for(int r=0;r<4;r++)
      #pragma unroll
      for(int a=0;a<4;a++){ acc[r][a][0]=0;acc[r][a][1]=0;acc[r][a][2]=0;acc[r][a][3]=0; }
    for(int k=0;k<64;k++){
      float4 w = *(const float4*)&W4[k*256+cc0];
      #pragma unroll
      for(int r=0;r<4;r++){
        float4 h = *(const float4*)&sHA[k*68 + (g+4*r)*4];
        acc[r][0][0]+=h.x*w.x; acc[r][0][1]+=h.x*w.y; acc[r][0][2]+=h.x*w.z; acc[r][0][3]+=h.x*w.w;
        acc[r][1][0]+=h.y*w.x; acc[r][1][1]+=h.y*w.y; acc[r][1][2]+=h.y*w.z; acc[r][1][3]+=h.y*w.w;
        acc[r][2][0]+=h.z*w.x; acc[r][2][1]+=h.z*w.y; acc[r][2][2]+=h.z*w.z; acc[r][2][3]+=h.z*w.w;
        acc[r][3][0]+=h.w*w.x; acc[r][3][1]+=h.w*w.y; acc[r][3][2]+=h.w*w.z; acc[r][3][3]+=h.w*w.w;
      }
    }
    #pragma unroll
    for(int r=0;r<4;r++)
      #pragma unroll
      for(int a=0;a<4;a++){
        int e = (g+4*r)*4 + a;
        size_t ep = (size_t)epos[be+e];
        __half2* dst = (__half2*)&mix_h[ep*256 + cc0];
        dst[0]=__floats2half2_rn(acc[r][a][0], acc[r][a][1]);
        dst[1]=__floats2half2_rn(acc[r][a][2], acc[r][a][3]);
      }
  }
  // ---- fused YM phase: M = Y.CG for this block's 64 edges (4 per thread) ----
  {
    int i = t&15;
    #pragma unroll
    for(int qq=0;qq<4;qq++){
      int e = be + (t>>4) + qq*16;
      float vx=vec[(size_t)e*3+0], vy=vec[(size_t)e*3+1], vz=vec[(size_t)e*3+2];
      float r2=vx*vx+vy*vy+vz*vz;
      float inv = (r2==0.f)?1.f:rsqrtf(r2);
      float X=vx*inv, Y=vy*inv, Z=vz*inv;
      const float s3=1.7320508075688772f, s5=2.23606797749979f, s7=2.6457513110645907f;
      const float s15=3.872983346207417f, s42=6.48074069840786f, s70=8.366600265340756f, s105=10.246950765959598f;
      float y[15];
      y[0]=s3*X; y[1]=s3*Y; y[2]=s3*Z;
      y[3]=s15*X*Y; y[4]=s15*Y*Z; y[5]=0.5f*s5*(3.f*Z*Z-1.f); y[6]=s15*X*Z; y[7]=0.5f*s15*(X*X-Y*Y);
      y[8]=0.25f*s70*Y*(3.f*X*X-Y*Y); y[9]=s105*X*Y*Z; y[10]=0.25f*s42*Y*(5.f*Z*Z-1.f);
      y[11]=0.5f*s7*Z*(5.f*Z*Z-3.f); y[12]=0.25f*s42*X*(5.f*Z*Z-1.f);
      y[13]=0.5f*s105*Z*(X*X-Y*Y); y[14]=0.25f*s70*X*(X*X-3.f*Y*Y);
      float m[16];
      #pragma unroll
      for(int k=0;k<16;k++) m[k]=0.f;
      const float* cgr = CG + i*240;
      #pragma unroll
      for(int j=0;j<15;j++){
        float yj = y[j];
        #pragma unroll
        for(int q=0;q<4;q++){
          float4 c4 = *(const float4*)&cgr[j*16 + q*4];
          m[q*4+0]+=yj*c4.x; m[q*4+1]+=yj*c4.y; m[q*4+2]+=yj*c4.z; m[q*4+3]+=yj*c4.w;
        }
      }
      size_t slot = (size_t)epos[e];
      __half2* dst = (__half2*)&M_h[slot*256 + i*16];
      #pragma unroll
      for(int q=0;q<8;q++) dst[q] = __floats2half2_rn(m[2*q], m[2*q+1]);
    }
  }
}

// ---------- edge gather: array-free + software-pipelined snd/x-row ----------
__global__ __launch_bounds__(256) void k_gather(
    const float* __restrict__ x, const __half* __restrict__ mix_h,
    const __half* __restrict__ M_h,
    const int* __restrict__ off, const int* __restrict__ ssend,
    float* __restrict__ agg)
{
  __shared__ __align__(16) float sP[4096];
  __shared__ int sSnd[256];
  int t=threadIdx.x, w=t>>6, l=t&63, lc=l&31, kh=(l>>5)*8;
  bool lohalf = (l>>5)==0;
  int n = blockIdx.x;
  int base = off[n];
  int deg  = off[n+1]-base; if (deg>256) deg=256;
  for (int d=t; d<deg; d+=256) sSnd[d]=ssend[base+d];
  __syncthreads();

  float a0=0,a1=0,a2=0,a3=0,a4=0,a5=0,a6=0,a7=0;
  float b0=0,b1=0,b2=0,b3=0,b4=0,b5=0,b6=0,b7=0;

  float4 pa,pb,pc,pd;
  if (w < deg){
    int snd0 = sSnd[w];
    const float* xr = x + (size_t)snd0*512 + lc*16;
    pa = *(const float4*)&xr[0];
    pb = *(const float4*)&xr[4];
    pc = *(const float4*)&xr[8];
    pd = *(const float4*)&xr[12];
  }

  for (int d=w; d<deg; d+=4){
    int slot = base+d;
    float4 xa=pa, xb=pb, xc=pc, xd=pd;
    int dn = d+4;
    if (dn < deg){
      int snd2 = sSnd[dn];
      const float* xr2 = x + (size_t)snd2*512 + lc*16;
      pa = *(const float4*)&xr2[0];
      pb = *(const float4*)&xr2[4];
      pc = *(const float4*)&xr2[8];
      pd = *(const float4*)&xr2[12];
    }
    const float* mrowf = (const float*)(mix_h + (size_t)slot*256);
    float2 mraw = *(const float2*)&mrowf[lc*2];
    float2 traw = *(const float2*)&mrowf[64 + lc*2];
    float2 mf01 = __half22float2(__builtin_bit_cast(__half2, mraw.x));
    float2 mf23 = __half22float2(__builtin_bit_cast(__half2, mraw.y));
    float2 mt01 = __half22float2(__builtin_bit_cast(__half2, traw.x));
    float2 mt23 = __half22float2(__builtin_bit_cast(__half2, traw.y));
    const __half* Mrow = M_h + (size_t)slot*256 + kh;
    float t0=0,t1=0,t2=0,t3=0,t4=0,t5=0,t6=0,t7=0;
#define ACCM(F,IOFF) { \
    float4 mr = *(const float4*)&Mrow[(IOFF)*16]; \
    float2 m01=__half22float2(__builtin_bit_cast(__half2, mr.x)); \
    float2 m23=__half22float2(__builtin_bit_cast(__half2, mr.y)); \
    float2 m45=__half22float2(__builtin_bit_cast(__half2, mr.z)); \
    float2 m67=__half22float2(__builtin_bit_cast(__half2, mr.w)); \
    t0+=(F)*m01.x; t1+=(F)*m01.y; t2+=(F)*m23.x; t3+=(F)*m23.y; \
    t4+=(F)*m45.x; t5+=(F)*m45.y; t6+=(F)*m67.x; t7+=(F)*m67.y; }
    ACCM(xa.x,0)  ACCM(xa.y,1)  ACCM(xa.z,2)  ACCM(xa.w,3)
    ACCM(xb.x,4)  ACCM(xb.y,5)  ACCM(xb.z,6)  ACCM(xb.w,7)
    ACCM(xc.x,8)  ACCM(xc.y,9)  ACCM(xc.z,10) ACCM(xc.w,11)
    ACCM(xd.x,12) ACCM(xd.y,13) ACCM(xd.z,14) ACCM(xd.w,15)
#undef ACCM
    float mg0 = lohalf ? mf01.x : mf23.x;
    float mg1 = lohalf ? mf01.y : mf23.y;
    float mg4 = lohalf ? mf23.x : mf23.y;
    float ng0 = lohalf ? mt01.x : mt23.x;
    float ng1 = lohalf ? mt01.y : mt23.y;
    float ng4 = lohalf ? mt23.x : mt23.y;
    float f0 = lohalf ? xa.x : xc.x;
    float f1 = lohalf ? xa.y : xc.y;
    float f2 = lohalf ? xa.z : xc.z;
    float f3 = lohalf ? xa.w : xc.w;
    float f4 = lohalf ? xb.x : xd.x;
    float f5 = lohalf ? xb.y : xd.y;
    float f6 = lohalf ? xb.z : xd.z;
    float f7 = lohalf ? xb.w : xd.w;
    a0 += f0*mg0;  b0 += t0*ng0;
    a1 += f1*mg1;  b1 += t1*ng1;
    a2 += f2*mg1;  b2 += t2*ng1;
    a3 += f3*mg1;  b3 += t3*ng1;
    a4 += f4*mg4;  b4 += t4*ng4;
    a5 += f5*mg4;  b5 += t5*ng4;
    a6 += f6*mg4;  b6 += t6*ng4;
    a7 += f7*mg4;  b7 += t7*ng4;
  }

  int ibF = w*1024 + lc*16 + kh;
  int ibT = w*1024 + (32+lc)*16 + kh;
  sP[ibF+0]=a0; sP[ibF+1]=a1; sP[ibF+2]=a2; sP[ibF+3]=a3;
  sP[ibF+4]=a4; sP[ibF+5]=a5; sP[ibF+6]=a6; sP[ibF+7]=a7;
  sP[ibT+0]=b0; sP[ibT+1]=b1; sP[ibT+2]=b2; sP[ibT+3]=b3;
  sP[ibT+4]=b4; sP[ibT+5]=b5; sP[ibT+6]=b6; sP[ibT+7]=b7;
  __syncthreads();
  for (int idx=t; idx<1024; idx+=256)
    agg[(size_t)n*1024 + idx] = sP[idx]+sP[1024+idx]+sP[2048+idx]+sP[3072+idx];
}

// ---------- tail: Wdown + sparse contraction + output (4 nodes/block, float2 lanes) ----------
__global__ __launch_bounds__(256) void k_tail(
    const float* __restrict__ agg, const float* __restrict__ x,
    const float* __restrict__ Wdown,
    const int* __restrict__ u3i, const float* __restrict__ u3v,
    const int* __restrict__ u2i, const float* __restrict__ u2v,
    const int* __restrict__ u1i, const float* __restrict__ u1v,
    const int* __restrict__ uoff,
    const float* __restrict__ w3, const float* __restrict__ w2,
    const float* __restrict__ w1,
    const float* __restrict__ Wsc, const float* __restrict__ Wout,
    const int* __restrict__ species,
    float* __restrict__ out)
{
  __shared__ float sAgg[4096];
  __shared__ float sy[2048];
  __shared__ float sPart[2048];

  int n0 = blockIdx.x*4, t = threadIdx.x;
  #pragma unroll
  for(int q=0;q<16;q++) sAgg[q*256+t] = agg[(size_t)n0*1024 + q*256 + t];
  __syncthreads();

  {
    int nq=t>>6, ii=t&15, f0=((t>>4)&3)*8;
    const float* W = Wdown + l_of(ii)*2048;
    float s0=0,s1=0,s2=0,s3=0,s4=0,s5=0,s6=0,s7=0;
    for(int c=0;c<64;c++){
      float a = sAgg[nq*1024 + c*16 + ii];
      float4 wva = *(const float4*)&W[c*32+f0];
      float4 wvb = *(const float4*)&W[c*32+f0+4];
      s0+=a*wva.x; s1+=a*wva.y; s2+=a*wva.z; s3+=a*wva.w;
      s4+=a*wvb.x; s5+=a*wvb.y; s6+=a*wvb.z; s7+=a*wvb.w;
    }
    float* yo = &sy[nq*512 + ii*32 + f0];
    yo[0]=s0*0.0625f; yo[1]=s1*0.0625f; yo[2]=s2*0.0625f; yo[3]=s3*0.0625f;
    yo[4]=s4*0.0625f; yo[5]=s5*0.0625f; yo[6]=s6*0.0625f; yo[7]=s7*0.0625f;
  }
  __syncthreads();

  float* sXn = sAgg;
  float* sB  = sAgg + 2048;
  #pragma unroll
  for(int q=0;q<8;q++){ int idx=q*256+t;
    sXn[idx] = x[(size_t)(n0+(idx>>9))*512 + (idx&511)]; }

  {
    int p = __builtin_amdgcn_readfirstlane(t>>6);
    int l = t&63, nq = l>>4, c0 = (l&15)*2;
    int spec = species[n0+nq];
    const float* syn = &sy[nq*512 + c0];
    #pragma unroll
    for(int i=0;i<4;i++){
      float r3x=0.f, r3y=0.f;
      #pragma unroll 4
      for(int q=uoff[i]+p; q<uoff[i+1]; q+=4){
        int id=u3i[q]; float v=u3v[q];
        int a=(id>>10)&15, b=(id>>6)&15, j=(id>>2)&15;
        float2 ya=*(const float2*)&syn[a*32];
        float2 yb=*(const float2*)&syn[b*32];
        float2 yj=*(const float2*)&syn[j*32];
        r3x += v*ya.x*yb.x*yj.x;
        r3y += v*ya.y*yb.y*yj.y;
      }
      float r2x=0.f, r2y=0.f;
      #pragma unroll 4
      for(int q=uoff[5+i]+p; q<uoff[5+i+1]; q+=4){
        int id=u2i[q]; float v=u2v[q];
        int a=(id>>6)&15, b=(id>>2)&15;
        float2 ya=*(const float2*)&syn[a*32];
        float2 yb=*(const float2*)&syn[b*32];
        r2x += v*ya.x*yb.x;
        r2y += v*ya.y*yb.y;
      }
      float r1x=0.f, r1y=0.f;
      for(int q=uoff[10+i]+p; q<uoff[10+i+1]; q+=4){
        int id=u1i[q]; float v=u1v[q];
        int a=(id>>2)&15;
        float2 ya=*(const float2*)&syn[a*32];
        r1x += v*ya.x;
        r1y += v*ya.y;
      }
      int wo = spec*64 + ((i==0)?0:32) + c0;
      float2 wa = *(const float2*)&w3[wo];
      float2 wb = *(const float2*)&w2[wo];
      float2 wc = *(const float2*)&w1[wo];
      float2 res;
      res.x = r3x*wa.x + r2x*wb.x + r1x*wc.x;
      res.y = r3y*wa.y + r2y*wb.y + r1y*wc.y;
      *(float2*)&sPart[p*512 + i*128 + nq*32 + c0] = res;
    }
  }
  __syncthreads();

  #pragma unroll
  for(int q=0;q<2;q++){
    int idx=q*256+t;
    int nq=idx>>7, rem=idx&127, c=rem>>2, i=rem&3;
    int o = i*128 + nq*32 + c;
    sB[nq*128 + c*4 + i] = sPart[o]+sPart[512+o]+sPart[1024+o]+sPart[1536+o];
  }
  __syncthreads();

  #pragma unroll
  for(int q=0;q<2;q++){
    int idx=q*256+t;
    int nq=idx>>7, rem=idx&127, f=rem>>2, i3=rem&3;
    int sp2 = species[n0+nq];
    int sel = (i3==0)?0:1;
    const float* Wo = Wout + sel*1024;
    const float* Ws = Wsc + (size_t)(sel*64+sp2)*1024;
    float o=0.f, sc=0.f;
    for(int c2=0;c2<32;c2++){
      o  += sB[nq*128 + c2*4 + i3]*Wo[c2*32+f];
      sc += sXn[nq*512 + c2*16 + i3]*Ws[c2*32+f];
    }
    out[(size_t)(n0+nq)*128 + f*4 + i3] = o + sc;
  }
}

extern "C" void kernel_launch(void* const* d_in, const int* in_sizes, int n_in,
                              void* d_out, int out_size, void* d_ws, size_t ws_size,
                              hipStream_t stream){
  (void)in_sizes; (void)n_in; (void)out_size; (void)ws_size;
  const float* feats = (const float*)d_in[0];
  const float* vec   = (const float*)d_in[1];
  const float* rad   = (const float*)d_in[2];
  const float* Wup   = (const float*)d_in[3];
  const float* CG    = (const float*)d_in[4];
  const float* Wr1   = (const float*)d_in[5];
  const float* Wr2   = (const float*)d_in[6];
  const float* Wr3   = (const float*)d_in[7];
  const float* Wr4   = (const float*)d_in[8];
  const float* Wdown = (const float*)d_in[9];
  const float* U3    = (const float*)d_in[10];
  const float* U2    = (const float*)d_in[11];
  const float* U1    = (const float*)d_in[12];
  const float* w3    = (const float*)d_in[13];
  const float* w2    = (const float*)d_in[14];
  const float* w1    = (const float*)d_in[15];
  const float* Wsc   = (const float*)d_in[16];
  const float* Wout  = (const float*)d_in[17];
  const int* species = (const int*)d_in[18];
  const int* senders = (const int*)d_in[19];
  const int* recv    = (const int*)d_in[20];
  float* out = (float*)d_out;

  char* w = (char*)d_ws;
  float* x     = (float*)w;  w += (size_t)NN*512*4;
  __half* mixh = (__half*)w; w += (size_t)EE*256*2;
  __half* Mh   = (__half*)w; w += (size_t)EE*256*2;
  float* agg   = (float*)w;  w += (size_t)NN*1024*4;
  int* cnt    = (int*)w;    w += (size_t)NN*4;
  int* off    = (int*)w;    w += (size_t)(NN+1)*4;
  int* pos    = (int*)w;    w += (size_t)EE*4;
  int* elist  = (int*)w;    w += (size_t)EE*4;
  int* epos   = (int*)w;    w += (size_t)EE*4;
  int* ssend  = (int*)w;    w += (size_t)EE*4;
  int* u3i    = (int*)w;    w += 16384*4;
  float* u3v  = (float*)w;  w += 16384*4;
  int* u2i    = (int*)w;    w += 1024*4;
  float* u2v  = (float*)w;  w += 1024*4;
  int* u1i    = (int*)w;    w += 64*4;
  float* u1v  = (float*)w;  w += 64*4;
  int* uoff   = (int*)w;    w += 16*4;

  {
    void* args[] = {
      (void*)&U3, (void*)&U2, (void*)&U1,
      (void*)&u3i, (void*)&u3v, (void*)&u2i, (void*)&u2v,
      (void*)&u1i, (void*)&u1v, (void*)&uoff,
      (void*)&recv, (void*)&senders,
      (void*)&cnt, (void*)&off, (void*)&pos,
      (void*)&elist, (void*)&epos, (void*)&ssend };
    hipLaunchCooperativeKernel((void*)k_prep, dim3(256), dim3(256), args, 0, stream);
  }
  k_x<<<NN/4,512,0,stream>>>(feats,Wup,x);
  k_mix<<<EE/64,256,0,stream>>>(rad,Wr1,Wr2,Wr3,Wr4,epos,mixh,vec,CG,Mh);
  k_gather<<<NN,256,0,stream>>>(x,mixh,Mh,off,ssend,agg);
  k_tail<<<NN/4,256,0,stream>>>(agg,x,Wdown,u3i,u3v,u2i,u2v,u1i,u1v,uoff,
                                w3,w2,w1,Wsc,Wout,species,out);
}

// Round 15
// 422.426 us; speedup vs baseline: 1.1706x; 1.1706x over previous
//
#include <hip/hip_runtime.h>
#include <hip/hip_fp16.h>
#include <hip/hip_cooperative_groups.h>
#include <math.h>

namespace cg = cooperative_groups;

#define NN 4096
#define FF 32
#define DD 16
#define EE 65536

__device__ __forceinline__ int l_of(int i){ return (i==0)?0:(i<4)?1:(i<9)?2:3; }
__device__ __forceinline__ float silu(float v){ return v/(1.f+expf(-v)); }

// ---------- x = per_l_linear(node_feats, W_up), 4 nodes/block ----------
__global__ __launch_bounds__(512) void k_x(const float* __restrict__ feats,
        const float* __restrict__ Wup, float* __restrict__ x){
  __shared__ float sF[4*512];
  __shared__ float sW[4*FF*FF];
  int n0 = blockIdx.x*4, t = threadIdx.x;
  #pragma unroll
  for(int q=0;q<4;q++) sF[q*512+t] = feats[(size_t)(n0+q)*512 + t];
  for (int k=t;k<4*FF*FF;k+=512) sW[k]=Wup[k];
  __syncthreads();
  int f = t>>4, i = t&15;
  const float* W = &sW[l_of(i)*FF*FF];
  #pragma unroll
  for(int q=0;q<4;q++){
    float a=0.f;
    #pragma unroll
    for (int c=0;c<FF;c++) a += sF[q*512 + c*DD+i]*W[c*FF+f];
    x[(size_t)(n0+q)*512 + t] = a;
  }
}

// ---------- cooperative prep: compact + zero -> count -> scan -> fill -> sort ----------
__global__ __launch_bounds__(256) void k_prep(
    const float* __restrict__ U3, const float* __restrict__ U2, const float* __restrict__ U1,
    int* __restrict__ u3i, float* __restrict__ u3v,
    int* __restrict__ u2i, float* __restrict__ u2v,
    int* __restrict__ u1i, float* __restrict__ u1v, int* __restrict__ uoff,
    const int* __restrict__ recv, const int* __restrict__ senders,
    int* __restrict__ cnt, int* __restrict__ off, int* __restrict__ pos,
    int* __restrict__ elist, int* __restrict__ epos, int* __restrict__ ssend)
{
  cg::grid_group grid = cg::this_grid();
  __shared__ int shmem[2048];
  int t=threadIdx.x, b=blockIdx.x;
  int gid = b*256+t;                 // 65536 threads == EE

  if (gid < NN) cnt[gid] = 0;
  if (b < 3){
    const float* src; int nsz; int* oi; float* ov; int slot=b;
    if(slot==0){src=U3;nsz=16384;oi=u3i;ov=u3v;}
    else if(slot==1){src=U2;nsz=1024;oi=u2i;ov=u2v;}
    else {src=U1;nsz=64;oi=u1i;ov=u1v;}
    int (*cnts)[4]  = (int(*)[4])shmem;
    int (*bases)[4] = (int(*)[4])(shmem+1024);
    int chunk=(nsz+255)/256;
    int lo=t*chunk, hi=min(nsz,lo+chunk); if(lo>nsz) lo=nsz;
    int c0=0,c1=0,c2=0,c3=0;
    for(int q=lo;q<hi;q++) if(src[q]!=0.f){
      int i=q&3;
      if(i==0)c0++; else if(i==1)c1++; else if(i==2)c2++; else c3++;
    }
    cnts[t][0]=c0; cnts[t][1]=c1; cnts[t][2]=c2; cnts[t][3]=c3;
    __syncthreads();
    if(t==0){
      int a=0;
      for(int i=0;i<4;i++){ uoff[slot*5+i]=a;
        for(int q=0;q<256;q++){ bases[q][i]=a; a+=cnts[q][i]; } }
      uoff[slot*5+4]=a;
    }
    __syncthreads();
    int w0=bases[t][0], w1_=bases[t][1], w2_=bases[t][2], w3_=bases[t][3];
    for(int q=lo;q<hi;q++){ float v=src[q]; if(v!=0.f){
      int i=q&3;
      if(i==0){ oi[w0]=q; ov[w0]=v; w0++; }
      else if(i==1){ oi[w1_]=q; ov[w1_]=v; w1_++; }
      else if(i==2){ oi[w2_]=q; ov[w2_]=v; w2_++; }
      else { oi[w3_]=q; ov[w3_]=v; w3_++; }
    } }
  }
  grid.sync();

  pos[gid] = atomicAdd(&cnt[recv[gid]], 1);
  grid.sync();

  if (b==0){
    int* sums = shmem; int* bss = shmem+256;
    int local[16]; int s=0;
    #pragma unroll
    for(int k=0;k<16;k++){ local[k]=cnt[t*16+k]; s+=local[k]; }
    sums[t]=s; __syncthreads();
    if(t==0){ int a=0; for(int q=0;q<256;q++){ bss[q]=a; a+=sums[q]; } }
    __syncthreads();
    int acc=bss[t];
    #pragma unroll
    for(int k=0;k<16;k++){ off[t*16+k]=acc; acc+=local[k]; }
    if(t==255) off[NN]=acc;
  }
  grid.sync();

  elist[off[recv[gid]]+pos[gid]] = gid;
  grid.sync();

  {
    int w=t>>6, l=t&63;
    int* buf = shmem;
    for (int n = b*4 + w; n < NN; n += 1024){
      int base = off[n];
      int deg = off[n+1]-base; if (deg>256) deg=256;
      for(int d=l; d<deg; d+=64) buf[w*256+d]=elist[base+d];
      for(int d=l; d<deg; d+=64){
        int v=buf[w*256+d]; int r=0;
        for(int q=0;q<deg;q++) r += (buf[w*256+q]<v);
        epos[v] = base + r;
        ssend[base+r] = senders[v];
      }
    }
  }
}

// ---------- Y then M = Y.CG per edge -> fp16 sorted slots ----------
__global__ __launch_bounds__(256) void k_YM(const float* __restrict__ vec,
    const float* __restrict__ CG, const int* __restrict__ epos,
    __half* __restrict__ M_h){
  int t = threadIdx.x;
  int e = blockIdx.x*16 + (t>>4);
  int i = t&15;
  float vx=vec[(size_t)e*3+0], vy=vec[(size_t)e*3+1], vz=vec[(size_t)e*3+2];
  float r2=vx*vx+vy*vy+vz*vz;
  float inv = (r2==0.f)?1.f:rsqrtf(r2);
  float X=vx*inv, Y=vy*inv, Z=vz*inv;
  const float s3=1.7320508075688772f, s5=2.23606797749979f, s7=2.6457513110645907f;
  const float s15=3.872983346207417f, s42=6.48074069840786f, s70=8.366600265340756f, s105=10.246950765959598f;
  float y[15];
  y[0]=s3*X; y[1]=s3*Y; y[2]=s3*Z;
  y[3]=s15*X*Y; y[4]=s15*Y*Z; y[5]=0.5f*s5*(3.f*Z*Z-1.f); y[6]=s15*X*Z; y[7]=0.5f*s15*(X*X-Y*Y);
  y[8]=0.25f*s70*Y*(3.f*X*X-Y*Y); y[9]=s105*X*Y*Z; y[10]=0.25f*s42*Y*(5.f*Z*Z-1.f);
  y[11]=0.5f*s7*Z*(5.f*Z*Z-3.f); y[12]=0.25f*s42*X*(5.f*Z*Z-1.f);
  y[13]=0.5f*s105*Z*(X*X-Y*Y); y[14]=0.25f*s70*X*(X*X-3.f*Y*Y);
  float m[16];
  #pragma unroll
  for(int k=0;k<16;k++) m[k]=0.f;
  const float* cgr = CG + i*240;
  #pragma unroll
  for(int j=0;j<15;j++){
    float yj = y[j];
    #pragma unroll
    for(int q=0;q<4;q++){
      float4 c4 = *(const float4*)&cgr[j*16 + q*4];
      m[q*4+0]+=yj*c4.x; m[q*4+1]+=yj*c4.y; m[q*4+2]+=yj*c4.z; m[q*4+3]+=yj*c4.w;
    }
  }
  size_t slot = (size_t)epos[e];
  __half2* dst = (__half2*)&M_h[slot*256 + i*16];
  #pragma unroll
  for(int q=0;q<8;q++) dst[q] = __floats2half2_rn(m[2*q], m[2*q+1]);
}

// ---------- radial MLP -> mix_h (fp16, sorted slots) ----------
__global__ __launch_bounds__(256) void k_mix(const float* __restrict__ rad,
    const float* __restrict__ W1, const float* __restrict__ W2,
    const float* __restrict__ W3, const float* __restrict__ W4,
    const int* __restrict__ epos, __half* __restrict__ mix_h){
  __shared__ float sRadT[8*68];
  __shared__ float sW1[8*64];
  __shared__ float sHA[64*68];
  __shared__ float sHB[64*68];
  int t = threadIdx.x;
  int be = blockIdx.x*64;
  for (int k=t;k<8*64;k+=256) sW1[k]=W1[k];
  for (int idx=t; idx<64*8; idx+=256){ int e=idx>>3, k=idx&7; sRadT[k*68+e]=rad[(size_t)(be+e)*8+k]; }
  __syncthreads();
  int e0 = (t>>4)*4, j0 = (t&15)*4;
  {
    float acc[4][4];
    #pragma unroll
    for(int a=0;a<4;a++){ acc[a][0]=0;acc[a][1]=0;acc[a][2]=0;acc[a][3]=0; }
    #pragma unroll
    for(int k=0;k<8;k++){
      float4 h = *(const float4*)&sRadT[k*68+e0];
      float4 w = *(const float4*)&sW1[k*64+j0];
      acc[0][0]+=h.x*w.x; acc[0][1]+=h.x*w.y; acc[0][2]+=h.x*w.z; acc[0][3]+=h.x*w.w;
      acc[1][0]+=h.y*w.x; acc[1][1]+=h.y*w.y; acc[1][2]+=h.y*w.z; acc[1][3]+=h.y*w.w;
      acc[2][0]+=h.z*w.x; acc[2][1]+=h.z*w.y; acc[2][2]+=h.z*w.z; acc[2][3]+=h.z*w.w;
      acc[3][0]+=h.w*w.x; acc[3][1]+=h.w*w.y; acc[3][2]+=h.w*w.z; acc[3][3]+=h.w*w.w;
    }
    #pragma unroll
    for(int b=0;b<4;b++){
      float4 v; v.x=silu(acc[0][b]); v.y=silu(acc[1][b]); v.z=silu(acc[2][b]); v.w=silu(acc[3][b]);
      *(float4*)&sHA[(j0+b)*68+e0] = v;
    }
  }
  __syncthreads();
  {
    float acc[4][4];
    #pragma unroll
    for(int a=0;a<4;a++){ acc[a][0]=0;acc[a][1]=0;acc[a][2]=0;acc[a][3]=0; }
    for(int k=0;k<64;k++){
      float4 h = *(const float4*)&sHA[k*68+e0];
      float4 w = *(const float4*)&W2[k*64+j0];
      acc[0][0]+=h.x*w.x; acc[0][1]+=h.x*w.y; acc[0][2]+=h.x*w.z; acc[0][3]+=h.x*w.w;
      acc[1][0]+=h.y*w.x; acc[1][1]+=h.y*w.y; acc[1][2]+=h.y*w.z; acc[1][3]+=h.y*w.w;
      acc[2][0]+=h.z*w.x; acc[2][1]+=h.z*w.y; acc[2][2]+=h.z*w.z; acc[2][3]+=h.z*w.w;
      acc[3][0]+=h.w*w.x; acc[3][1]+=h.w*w.y; acc[3][2]+=h.w*w.z; acc[3][3]+=h.w*w.w;
    }
    #pragma unroll
    for(int b=0;b<4;b++){
      float4 v; v.x=silu(acc[0][b]); v.y=silu(acc[1][b]); v.z=silu(acc[2][b]); v.w=silu(acc[3][b]);
      *(float4*)&sHB[(j0+b)*68+e0] = v;
    }
  }
  __syncthreads();
  {
    float acc[4][4];
    #pragma unroll
    for(int a=0;a<4;a++){ acc[a][0]=0;acc[a][1]=0;acc[a][2]=0;acc[a][3]=0; }
    for(int k=0;k<64;k++){
      float4 h = *(const float4*)&sHB[k*68+e0];
      float4 w = *(const float4*)&W3[k*64+j0];
      acc[0][0]+=h.x*w.x; acc[0][1]+=h.x*w.y; acc[0][2]+=h.x*w.z; acc[0][3]+=h.x*w.w;
      acc[1][0]+=h.y*w.x; acc[1][1]+=h.y*w.y; acc[1][2]+=h.y*w.z; acc[1][3]+=h.y*w.w;
      acc[2][0]+=h.z*w.x; acc[2][1]+=h.z*w.y; acc[2][2]+=h.z*w.z; acc[2][3]+=h.z*w.w;
      acc[3][0]+=h.w*w.x; acc[3][1]+=h.w*w.y; acc[3][2]+=h.w*w.z; acc[3][3]+=h.w*w.w;
    }
    #pragma unroll
    for(int b=0;b<4;b++){
      float4 v; v.x=silu(acc[0][b]); v.y=silu(acc[1][b]); v.z=silu(acc[2][b]); v.w=silu(acc[3][b]);
      *(float4*)&sHA[(j0+b)*68+e0] = v;
    }
  }
  __syncthreads();
  {
    int cc0 = (t&63)*4, g = t>>6;
    float acc[4][4][4];
    #pragma unroll
    for(int r=0;r<4;r++)
      #pragma unroll
      for(int a=0;a<4;a++){ acc[r][a][0]=0;acc[r][a][1]=0;acc[r][a][2]=0;acc[r][a][3]=0; }
    for(int k=0;k<64;k++){
      float4 w = *(const float4*)&W4[k*256+cc0];
      #pragma unroll
      for(int r=0;r<4;r++){
        float4 h = *(const float4*)&sHA[k*68 + (g+4*r)*4];
        acc[r][0][0]+=h.x*w.x; acc[r][0][1]+=h.x*w.y; acc[r][0][2]+=h.x*w.z; acc[r][0][3]+=h.x*w.w;
        acc[r][1][0]+=h.y*w.x; acc[r][1][1]+=h.y*w.y; acc[r][1][2]+=h.y*w.z; acc[r][1][3]+=h.y*w.w;
        acc[r][2][0]+=h.z*w.x; acc[r][2][1]+=h.z*w.y; acc[r][2][2]+=h.z*w.z; acc[r][2][3]+=h.z*w.w;
        acc[r][3][0]+=h.w*w.x; acc[r][3][1]+=h.w*w.y; acc[r][3][2]+=h.w*w.z; acc[r][3][3]+=h.w*w.w;
      }
    }
    #pragma unroll
    for(int r=0;r<4;r++)
      #pragma unroll
      for(int a=0;a<4;a++){
        int e = (g+4*r)*4 + a;
        size_t ep = (size_t)epos[be+e];
        __half2* dst = (__half2*)&mix_h[ep*256 + cc0];
        dst[0]=__floats2half2_rn(acc[r][a][0], acc[r][a][1]);
        dst[1]=__floats2half2_rn(acc[r][a][2], acc[r][a][3]);
      }
  }
}

// ---------- edge gather: array-free + software-pipelined snd/x-row ----------
__global__ __launch_bounds__(256) void k_gather(
    const float* __restrict__ x, const __half* __restrict__ mix_h,
    const __half* __restrict__ M_h,
    const int* __restrict__ off, const int* __restrict__ ssend,
    float* __restrict__ agg)
{
  __shared__ __align__(16) float sP[4096];
  __shared__ int sSnd[256];
  int t=threadIdx.x, w=t>>6, l=t&63, lc=l&31, kh=(l>>5)*8;
  bool lohalf = (l>>5)==0;
  int n = blockIdx.x;
  int base = off[n];
  int deg  = off[n+1]-base; if (deg>256) deg=256;
  for (int d=t; d<deg; d+=256) sSnd[d]=ssend[base+d];
  __syncthreads();

  float a0=0,a1=0,a2=0,a3=0,a4=0,a5=0,a6=0,a7=0;
  float b0=0,b1=0,b2=0,b3=0,b4=0,b5=0,b6=0,b7=0;

  float4 pa,pb,pc,pd;
  if (w < deg){
    int snd0 = sSnd[w];
    const float* xr = x + (size_t)snd0*512 + lc*16;
    pa = *(const float4*)&xr[0];
    pb = *(const float4*)&xr[4];
    pc = *(const float4*)&xr[8];
    pd = *(const float4*)&xr[12];
  }

  for (int d=w; d<deg; d+=4){
    int slot = base+d;
    float4 xa=pa, xb=pb, xc=pc, xd=pd;
    int dn = d+4;
    if (dn < deg){
      int snd2 = sSnd[dn];
      const float* xr2 = x + (size_t)snd2*512 + lc*16;
      pa = *(const float4*)&xr2[0];
      pb = *(const float4*)&xr2[4];
      pc = *(const float4*)&xr2[8];
      pd = *(const float4*)&xr2[12];
    }
    const float* mrowf = (const float*)(mix_h + (size_t)slot*256);
    float2 mraw = *(const float2*)&mrowf[lc*2];
    float2 traw = *(const float2*)&mrowf[64 + lc*2];
    float2 mf01 = __half22float2(__builtin_bit_cast(__half2, mraw.x));
    float2 mf23 = __half22float2(__builtin_bit_cast(__half2, mraw.y));
    float2 mt01 = __half22float2(__builtin_bit_cast(__half2, traw.x));
    float2 mt23 = __half22float2(__builtin_bit_cast(__half2, traw.y));
    const __half* Mrow = M_h + (size_t)slot*256 + kh;
    float t0=0,t1=0,t2=0,t3=0,t4=0,t5=0,t6=0,t7=0;
#define ACCM(F,IOFF) { \
    float4 mr = *(const float4*)&Mrow[(IOFF)*16]; \
    float2 m01=__half22float2(__builtin_bit_cast(__half2, mr.x)); \
    float2 m23=__half22float2(__builtin_bit_cast(__half2, mr.y)); \
    float2 m45=__half22float2(__builtin_bit_cast(__half2, mr.z)); \
    float2 m67=__half22float2(__builtin_bit_cast(__half2, mr.w)); \
    t0+=(F)*m01.x; t1+=(F)*m01.y; t2+=(F)*m23.x; t3+=(F)*m23.y; \
    t4+=(F)*m45.x; t5+=(F)*m45.y; t6+=(F)*m67.x; t7+=(F)*m67.y; }
    ACCM(xa.x,0)  ACCM(xa.y,1)  ACCM(xa.z,2)  ACCM(xa.w,3)
    ACCM(xb.x,4)  ACCM(xb.y,5)  ACCM(xb.z,6)  ACCM(xb.w,7)
    ACCM(xc.x,8)  ACCM(xc.y,9)  ACCM(xc.z,10) ACCM(xc.w,11)
    ACCM(xd.x,12) ACCM(xd.y,13) ACCM(xd.z,14) ACCM(xd.w,15)
#undef ACCM
    float mg0 = lohalf ? mf01.x : mf23.x;
    float mg1 = lohalf ? mf01.y : mf23.y;
    float mg4 = lohalf ? mf23.x : mf23.y;
    float ng0 = lohalf ? mt01.x : mt23.x;
    float ng1 = lohalf ? mt01.y : mt23.y;
    float ng4 = lohalf ? mt23.x : mt23.y;
    float f0 = lohalf ? xa.x : xc.x;
    float f1 = lohalf ? xa.y : xc.y;
    float f2 = lohalf ? xa.z : xc.z;
    float f3 = lohalf ? xa.w : xc.w;
    float f4 = lohalf ? xb.x : xd.x;
    float f5 = lohalf ? xb.y : xd.y;
    float f6 = lohalf ? xb.z : xd.z;
    float f7 = lohalf ? xb.w : xd.w;
    a0 += f0*mg0;  b0 += t0*ng0;
    a1 += f1*mg1;  b1 += t1*ng1;
    a2 += f2*mg1;  b2 += t2*ng1;
    a3 += f3*mg1;  b3 += t3*ng1;
    a4 += f4*mg4;  b4 += t4*ng4;
    a5 += f5*mg4;  b5 += t5*ng4;
    a6 += f6*mg4;  b6 += t6*ng4;
    a7 += f7*mg4;  b7 += t7*ng4;
  }

  int ibF = w*1024 + lc*16 + kh;
  int ibT = w*1024 + (32+lc)*16 + kh;
  sP[ibF+0]=a0; sP[ibF+1]=a1; sP[ibF+2]=a2; sP[ibF+3]=a3;
  sP[ibF+4]=a4; sP[ibF+5]=a5; sP[ibF+6]=a6; sP[ibF+7]=a7;
  sP[ibT+0]=b0; sP[ibT+1]=b1; sP[ibT+2]=b2; sP[ibT+3]=b3;
  sP[ibT+4]=b4; sP[ibT+5]=b5; sP[ibT+6]=b6; sP[ibT+7]=b7;
  __syncthreads();
  for (int idx=t; idx<1024; idx+=256)
    agg[(size_t)n*1024 + idx] = sP[idx]+sP[1024+idx]+sP[2048+idx]+sP[3072+idx];
}

// ---------- tail: Wdown + sparse contraction + output (4 nodes/block, float2 lanes) ----------
__global__ __launch_bounds__(256) void k_tail(
    const float* __restrict__ agg, const float* __restrict__ x,
    const float* __restrict__ Wdown,
    const int* __restrict__ u3i, const float* __restrict__ u3v,
    const int* __restrict__ u2i, const float* __restrict__ u2v,
    const int* __restrict__ u1i, const float* __restrict__ u1v,
    const int* __restrict__ uoff,
    const float* __restrict__ w3, const float* __restrict__ w2,
    const float* __restrict__ w1,
    const float* __restrict__ Wsc, const float* __restrict__ Wout,
    const int* __restrict__ species,
    float* __restrict__ out)
{
  __shared__ float sAgg[4096];
  __shared__ float sy[2048];
  __shared__ float sPart[2048];

  int n0 = blockIdx.x*4, t = threadIdx.x;
  #pragma unroll
  for(int q=0;q<16;q++) sAgg[q*256+t] = agg[(size_t)n0*1024 + q*256 + t];
  __syncthreads();

  {
    int nq=t>>6, ii=t&15, f0=((t>>4)&3)*8;
    const float* W = Wdown + l_of(ii)*2048;
    float s0=0,s1=0,s2=0,s3=0,s4=0,s5=0,s6=0,s7=0;
    for(int c=0;c<64;c++){
      float a = sAgg[nq*1024 + c*16 + ii];
      float4 wva = *(const float4*)&W[c*32+f0];
      float4 wvb = *(const float4*)&W[c*32+f0+4];
      s0+=a*wva.x; s1+=a*wva.y; s2+=a*wva.z; s3+=a*wva.w;
      s4+=a*wvb.x; s5+=a*wvb.y; s6+=a*wvb.z; s7+=a*wvb.w;
    }
    float* yo = &sy[nq*512 + ii*32 + f0];
    yo[0]=s0*0.0625f; yo[1]=s1*0.0625f; yo[2]=s2*0.0625f; yo[3]=s3*0.0625f;
    yo[4]=s4*0.0625f; yo[5]=s5*0.0625f; yo[6]=s6*0.0625f; yo[7]=s7*0.0625f;
  }
  __syncthreads();

  float* sXn = sAgg;
  float* sB  = sAgg + 2048;
  #pragma unroll
  for(int q=0;q<8;q++){ int idx=q*256+t;
    sXn[idx] = x[(size_t)(n0+(idx>>9))*512 + (idx&511)]; }

  {
    int p = __builtin_amdgcn_readfirstlane(t>>6);
    int l = t&63, nq = l>>4, c0 = (l&15)*2;
    int spec = species[n0+nq];
    const float* syn = &sy[nq*512 + c0];
    #pragma unroll
    for(int i=0;i<4;i++){
      float r3x=0.f, r3y=0.f;
      #pragma unroll 4
      for(int q=uoff[i]+p; q<uoff[i+1]; q+=4){
        int id=u3i[q]; float v=u3v[q];
        int a=(id>>10)&15, b=(id>>6)&15, j=(id>>2)&15;
        float2 ya=*(const float2*)&syn[a*32];
        float2 yb=*(const float2*)&syn[b*32];
        float2 yj=*(const float2*)&syn[j*32];
        r3x += v*ya.x*yb.x*yj.x;
        r3y += v*ya.y*yb.y*yj.y;
      }
      float r2x=0.f, r2y=0.f;
      #pragma unroll 4
      for(int q=uoff[5+i]+p; q<uoff[5+i+1]; q+=4){
        int id=u2i[q]; float v=u2v[q];
        int a=(id>>6)&15, b=(id>>2)&15;
        float2 ya=*(const float2*)&syn[a*32];
        float2 yb=*(const float2*)&syn[b*32];
        r2x += v*ya.x*yb.x;
        r2y += v*ya.y*yb.y;
      }
      float r1x=0.f, r1y=0.f;
      for(int q=uoff[10+i]+p; q<uoff[10+i+1]; q+=4){
        int id=u1i[q]; float v=u1v[q];
        int a=(id>>2)&15;
        float2 ya=*(const float2*)&syn[a*32];
        r1x += v*ya.x;
        r1y += v*ya.y;
      }
      int wo = spec*64 + ((i==0)?0:32) + c0;
      float2 wa = *(const float2*)&w3[wo];
      float2 wb = *(const float2*)&w2[wo];
      float2 wc = *(const float2*)&w1[wo];
      float2 res;
      res.x = r3x*wa.x + r2x*wb.x + r1x*wc.x;
      res.y = r3y*wa.y + r2y*wb.y + r1y*wc.y;
      *(float2*)&sPart[p*512 + i*128 + nq*32 + c0] = res;
    }
  }
  __syncthreads();

  #pragma unroll
  for(int q=0;q<2;q++){
    int idx=q*256+t;
    int nq=idx>>7, rem=idx&127, c=rem>>2, i=rem&3;
    int o = i*128 + nq*32 + c;
    sB[nq*128 + c*4 + i] = sPart[o]+sPart[512+o]+sPart[1024+o]+sPart[1536+o];
  }
  __syncthreads();

  #pragma unroll
  for(int q=0;q<2;q++){
    int idx=q*256+t;
    int nq=idx>>7, rem=idx&127, f=rem>>2, i3=rem&3;
    int sp2 = species[n0+nq];
    int sel = (i3==0)?0:1;
    const float* Wo = Wout + sel*1024;
    const float* Ws = Wsc + (size_t)(sel*64+sp2)*1024;
    float o=0.f, sc=0.f;
    for(int c2=0;c2<32;c2++){
      o  += sB[nq*128 + c2*4 + i3]*Wo[c2*32+f];
      sc += sXn[nq*512 + c2*16 + i3]*Ws[c2*32+f];
    }
    out[(size_t)(n0+nq)*128 + f*4 + i3] = o + sc;
  }
}

extern "C" void kernel_launch(void* const* d_in, const int* in_sizes, int n_in,
                              void* d_out, int out_size, void* d_ws, size_t ws_size,
                              hipStream_t stream){
  (void)in_sizes; (void)n_in; (void)out_size; (void)ws_size;
  const float* feats = (const float*)d_in[0];
  const float* vec   = (const float*)d_in[1];
  const float* rad   = (const float*)d_in[2];
  const float* Wup   = (const float*)d_in[3];
  const float* CG    = (const float*)d_in[4];
  const float* Wr1   = (const float*)d_in[5];
  const float* Wr2   = (const float*)d_in[6];
  const float* Wr3   = (const float*)d_in[7];
  const float* Wr4   = (const float*)d_in[8];
  const float* Wdown = (const float*)d_in[9];
  const float* U3    = (const float*)d_in[10];
  const float* U2    = (const float*)d_in[11];
  const float* U1    = (const float*)d_in[12];
  const float* w3    = (const float*)d_in[13];
  const float* w2    = (const float*)d_in[14];
  const float* w1    = (const float*)d_in[15];
  const float* Wsc   = (const float*)d_in[16];
  const float* Wout  = (const float*)d_in[17];
  const int* species = (const int*)d_in[18];
  const int* senders = (const int*)d_in[19];
  const int* recv    = (const int*)d_in[20];
  float* out = (float*)d_out;

  char* w = (char*)d_ws;
  float* x     = (float*)w;  w += (size_t)NN*512*4;
  __half* mixh = (__half*)w; w += (size_t)EE*256*2;
  __half* Mh   = (__half*)w; w += (size_t)EE*256*2;
  float* agg   = (float*)w;  w += (size_t)NN*1024*4;
  int* cnt    = (int*)w;    w += (size_t)NN*4;
  int* off    = (int*)w;    w += (size_t)(NN+1)*4;
  int* pos    = (int*)w;    w += (size_t)EE*4;
  int* elist  = (int*)w;    w += (size_t)EE*4;
  int* epos   = (int*)w;    w += (size_t)EE*4;
  int* ssend  = (int*)w;    w += (size_t)EE*4;
  int* u3i    = (int*)w;    w += 16384*4;
  float* u3v  = (float*)w;  w += 16384*4;
  int* u2i    = (int*)w;    w += 1024*4;
  float* u2v  = (float*)w;  w += 1024*4;
  int* u1i    = (int*)w;    w += 64*4;
  float* u1v  = (float*)w;  w += 64*4;
  int* uoff   = (int*)w;    w += 16*4;

  {
    void* args[] = {
      (void*)&U3, (void*)&U2, (void*)&U1,
      (void*)&u3i, (void*)&u3v, (void*)&u2i, (void*)&u2v,
      (void*)&u1i, (void*)&u1v, (void*)&uoff,
      (void*)&recv, (void*)&senders,
      (void*)&cnt, (void*)&off, (void*)&pos,
      (void*)&elist, (void*)&epos, (void*)&ssend };
    hipLaunchCooperativeKernel((void*)k_prep, dim3(256), dim3(256), args, 0, stream);
  }
  k_x<<<NN/4,512,0,stream>>>(feats,Wup,x);
  k_YM<<<EE/16,256,0,stream>>>(vec,CG,epos,Mh);
  k_mix<<<EE/64,256,0,stream>>>(rad,Wr1,Wr2,Wr3,Wr4,epos,mixh);
  k_gather<<<NN,256,0,stream>>>(x,mixh,Mh,off,ssend,agg);
  k_tail<<<NN/4,256,0,stream>>>(agg,x,Wdown,u3i,u3v,u2i,u2v,u1i,u1v,uoff,
                                w3,w2,w1,Wsc,Wout,species,out);
}

// Round 16
// 367.345 us; speedup vs baseline: 1.3462x; 1.1499x over previous
//
#include <hip/hip_runtime.h>
#include <hip/hip_fp16.h>
#include <math.h>

#define NN 4096
#define FF 32
#define DD 16
#define EE 65536

__device__ __forceinline__ int l_of(int i){ return (i==0)?0:(i<4)?1:(i<9)?2:3; }
__device__ __forceinline__ float silu(float v){ return v/(1.f+expf(-v)); }

// ---------- x = per_l_linear(node_feats, W_up), 4 nodes/block ----------
__global__ __launch_bounds__(512) void k_x(const float* __restrict__ feats,
        const float* __restrict__ Wup, float* __restrict__ x){
  __shared__ float sF[4*512];
  __shared__ float sW[4*FF*FF];
  int n0 = blockIdx.x*4, t = threadIdx.x;
  #pragma unroll
  for(int q=0;q<4;q++) sF[q*512+t] = feats[(size_t)(n0+q)*512 + t];
  for (int k=t;k<4*FF*FF;k+=512) sW[k]=Wup[k];
  __syncthreads();
  int f = t>>4, i = t&15;
  const float* W = &sW[l_of(i)*FF*FF];
  #pragma unroll
  for(int q=0;q<4;q++){
    float a=0.f;
    #pragma unroll
    for (int c=0;c<FF;c++) a += sF[q*512 + c*DD+i]*W[c*FF+f];
    x[(size_t)(n0+q)*512 + t] = a;
  }
}

// ---------- Y then M = Y.CG per edge -> fp16 sorted slots ----------
__global__ __launch_bounds__(256) void k_YM(const float* __restrict__ vec,
    const float* __restrict__ CG, const int* __restrict__ epos,
    __half* __restrict__ M_h){
  int t = threadIdx.x;
  int e = blockIdx.x*16 + (t>>4);
  int i = t&15;
  float vx=vec[(size_t)e*3+0], vy=vec[(size_t)e*3+1], vz=vec[(size_t)e*3+2];
  float r2=vx*vx+vy*vy+vz*vz;
  float inv = (r2==0.f)?1.f:rsqrtf(r2);
  float X=vx*inv, Y=vy*inv, Z=vz*inv;
  const float s3=1.7320508075688772f, s5=2.23606797749979f, s7=2.6457513110645907f;
  const float s15=3.872983346207417f, s42=6.48074069840786f, s70=8.366600265340756f, s105=10.246950765959598f;
  float y[15];
  y[0]=s3*X; y[1]=s3*Y; y[2]=s3*Z;
  y[3]=s15*X*Y; y[4]=s15*Y*Z; y[5]=0.5f*s5*(3.f*Z*Z-1.f); y[6]=s15*X*Z; y[7]=0.5f*s15*(X*X-Y*Y);
  y[8]=0.25f*s70*Y*(3.f*X*X-Y*Y); y[9]=s105*X*Y*Z; y[10]=0.25f*s42*Y*(5.f*Z*Z-1.f);
  y[11]=0.5f*s7*Z*(5.f*Z*Z-3.f); y[12]=0.25f*s42*X*(5.f*Z*Z-1.f);
  y[13]=0.5f*s105*Z*(X*X-Y*Y); y[14]=0.25f*s70*X*(X*X-3.f*Y*Y);
  float m[16];
  #pragma unroll
  for(int k=0;k<16;k++) m[k]=0.f;
  const float* cgr = CG + i*240;
  #pragma unroll
  for(int j=0;j<15;j++){
    float yj = y[j];
    #pragma unroll
    for(int q=0;q<4;q++){
      float4 c4 = *(const float4*)&cgr[j*16 + q*4];
      m[q*4+0]+=yj*c4.x; m[q*4+1]+=yj*c4.y; m[q*4+2]+=yj*c4.z; m[q*4+3]+=yj*c4.w;
    }
  }
  size_t slot = (size_t)epos[e];
  __half2* dst = (__half2*)&M_h[slot*256 + i*16];
  #pragma unroll
  for(int q=0;q<8;q++) dst[q] = __floats2half2_rn(m[2*q], m[2*q+1]);
}

// ---------- radial MLP -> mix_h (fp16, sorted slots) ----------
__global__ __launch_bounds__(256) void k_mix(const float* __restrict__ rad,
    const float* __restrict__ W1, const float* __restrict__ W2,
    const float* __restrict__ W3, const float* __restrict__ W4,
    const int* __restrict__ epos, __half* __restrict__ mix_h){
  __shared__ float sRadT[8*68];
  __shared__ float sW1[8*64];
  __shared__ float sHA[64*68];
  __shared__ float sHB[64*68];
  int t = threadIdx.x;
  int be = blockIdx.x*64;
  for (int k=t;k<8*64;k+=256) sW1[k]=W1[k];
  for (int idx=t; idx<64*8; idx+=256){ int e=idx>>3, k=idx&7; sRadT[k*68+e]=rad[(size_t)(be+e)*8+k]; }
  __syncthreads();
  int e0 = (t>>4)*4, j0 = (t&15)*4;
  {
    float acc[4][4];
    #pragma unroll
    for(int a=0;a<4;a++){ acc[a][0]=0;acc[a][1]=0;acc[a][2]=0;acc[a][3]=0; }
    #pragma unroll
    for(int k=0;k<8;k++){
      float4 h = *(const float4*)&sRadT[k*68+e0];
      float4 w = *(const float4*)&sW1[k*64+j0];
      acc[0][0]+=h.x*w.x; acc[0][1]+=h.x*w.y; acc[0][2]+=h.x*w.z; acc[0][3]+=h.x*w.w;
      acc[1][0]+=h.y*w.x; acc[1][1]+=h.y*w.y; acc[1][2]+=h.y*w.z; acc[1][3]+=h.y*w.w;
      acc[2][0]+=h.z*w.x; acc[2][1]+=h.z*w.y; acc[2][2]+=h.z*w.z; acc[2][3]+=h.z*w.w;
      acc[3][0]+=h.w*w.x; acc[3][1]+=h.w*w.y; acc[3][2]+=h.w*w.z; acc[3][3]+=h.w*w.w;
    }
    #pragma unroll
    for(int b=0;b<4;b++){
      float4 v; v.x=silu(acc[0][b]); v.y=silu(acc[1][b]); v.z=silu(acc[2][b]); v.w=silu(acc[3][b]);
      *(float4*)&sHA[(j0+b)*68+e0] = v;
    }
  }
  __syncthreads();
  {
    float acc[4][4];
    #pragma unroll
    for(int a=0;a<4;a++){ acc[a][0]=0;acc[a][1]=0;acc[a][2]=0;acc[a][3]=0; }
    for(int k=0;k<64;k++){
      float4 h = *(const float4*)&sHA[k*68+e0];
      float4 w = *(const float4*)&W2[k*64+j0];
      acc[0][0]+=h.x*w.x; acc[0][1]+=h.x*w.y; acc[0][2]+=h.x*w.z; acc[0][3]+=h.x*w.w;
      acc[1][0]+=h.y*w.x; acc[1][1]+=h.y*w.y; acc[1][2]+=h.y*w.z; acc[1][3]+=h.y*w.w;
      acc[2][0]+=h.z*w.x; acc[2][1]+=h.z*w.y; acc[2][2]+=h.z*w.z; acc[2][3]+=h.z*w.w;
      acc[3][0]+=h.w*w.x; acc[3][1]+=h.w*w.y; acc[3][2]+=h.w*w.z; acc[3][3]+=h.w*w.w;
    }
    #pragma unroll
    for(int b=0;b<4;b++){
      float4 v; v.x=silu(acc[0][b]); v.y=silu(acc[1][b]); v.z=silu(acc[2][b]); v.w=silu(acc[3][b]);
      *(float4*)&sHB[(j0+b)*68+e0] = v;
    }
  }
  __syncthreads();
  {
    float acc[4][4];
    #pragma unroll
    for(int a=0;a<4;a++){ acc[a][0]=0;acc[a][1]=0;acc[a][2]=0;acc[a][3]=0; }
    for(int k=0;k<64;k++){
      float4 h = *(const float4*)&sHB[k*68+e0];
      float4 w = *(const float4*)&W3[k*64+j0];
      acc[0][0]+=h.x*w.x; acc[0][1]+=h.x*w.y; acc[0][2]+=h.x*w.z; acc[0][3]+=h.x*w.w;
      acc[1][0]+=h.y*w.x; acc[1][1]+=h.y*w.y; acc[1][2]+=h.y*w.z; acc[1][3]+=h.y*w.w;
      acc[2][0]+=h.z*w.x; acc[2][1]+=h.z*w.y; acc[2][2]+=h.z*w.z; acc[2][3]+=h.z*w.w;
      acc[3][0]+=h.w*w.x; acc[3][1]+=h.w*w.y; acc[3][2]+=h.w*w.z; acc[3][3]+=h.w*w.w;
    }
    #pragma unroll
    for(int b=0;b<4;b++){
      float4 v; v.x=silu(acc[0][b]); v.y=silu(acc[1][b]); v.z=silu(acc[2][b]); v.w=silu(acc[3][b]);
      *(float4*)&sHA[(j0+b)*68+e0] = v;
    }
  }
  __syncthreads();
  {
    int cc0 = (t&63)*4, g = t>>6;
    float acc[4][4][4];
    #pragma unroll
    for(int r=0;r<4;r++)
      #pragma unroll
      for(int a=0;a<4;a++){ acc[r][a][0]=0;acc[r][a][1]=0;acc[r][a][2]=0;acc[r][a][3]=0; }
    for(int k=0;k<64;k++){
      float4 w = *(const float4*)&W4[k*256+cc0];
      #pragma unroll
      for(int r=0;r<4;r++){
        float4 h = *(const float4*)&sHA[k*68 + (g+4*r)*4];
        acc[r][0][0]+=h.x*w.x; acc[r][0][1]+=h.x*w.y; acc[r][0][2]+=h.x*w.z; acc[r][0][3]+=h.x*w.w;
        acc[r][1][0]+=h.y*w.x; acc[r][1][1]+=h.y*w.y; acc[r][1][2]+=h.y*w.z; acc[r][1][3]+=h.y*w.w;
        acc[r][2][0]+=h.z*w.x; acc[r][2][1]+=h.z*w.y; acc[r][2][2]+=h.z*w.z; acc[r][2][3]+=h.z*w.w;
        acc[r][3][0]+=h.w*w.x; acc[r][3][1]+=h.w*w.y; acc[r][3][2]+=h.w*w.z; acc[r][3][3]+=h.w*w.w;
      }
    }
    #pragma unroll
    for(int r=0;r<4;r++)
      #pragma unroll
      for(int a=0;a<4;a++){
        int e = (g+4*r)*4 + a;
        size_t ep = (size_t)epos[be+e];
        __half2* dst = (__half2*)&mix_h[ep*256 + cc0];
        dst[0]=__floats2half2_rn(acc[r][a][0], acc[r][a][1]);
        dst[1]=__floats2half2_rn(acc[r][a][2], acc[r][a][3]);
      }
  }
}

// ---------- CSR build ----------
__global__ void k_zero(int* cnt){ int t=blockIdx.x*256+threadIdx.x; if(t<NN) cnt[t]=0; }
__global__ void k_count(const int* __restrict__ recv, int* cnt, int* pos){
  int e=blockIdx.x*256+threadIdx.x; pos[e]=atomicAdd(&cnt[recv[e]],1); }
__global__ __launch_bounds__(256) void k_scan(const int* __restrict__ cnt, int* __restrict__ off){
  __shared__ int sums[256]; __shared__ int bases[256];
  int t=threadIdx.x;
  int local[16]; int s=0;
  #pragma unroll
  for(int k=0;k<16;k++){ local[k]=cnt[t*16+k]; s+=local[k]; }
  sums[t]=s; __syncthreads();
  if(t==0){ int a=0; for(int q=0;q<256;q++){ bases[q]=a; a+=sums[q]; } }
  __syncthreads();
  int acc=bases[t];
  #pragma unroll
  for(int k=0;k<16;k++){ off[t*16+k]=acc; acc+=local[k]; }
  if(t==255) off[NN]=acc;
}
__global__ void k_fill(const int* __restrict__ recv, const int* __restrict__ off,
                       const int* __restrict__ pos, int* __restrict__ elist){
  int e=blockIdx.x*256+threadIdx.x; elist[off[recv[e]]+pos[e]]=e; }

// ---------- per-node rank sort -> epos (edge->slot), ssend (slot->sender) ----------
__global__ __launch_bounds__(256) void k_sort(const int* __restrict__ senders,
    const int* __restrict__ off, const int* __restrict__ elist,
    int* __restrict__ epos, int* __restrict__ ssend){
  __shared__ int buf[4][256];
  int t=threadIdx.x, w=t>>6, l=t&63;
  int n = blockIdx.x*4 + w;
  int base = off[n];
  int deg = off[n+1]-base; if (deg>256) deg=256;
  for(int d=l; d<deg; d+=64) buf[w][d]=elist[base+d];
  __syncthreads();
  for(int d=l; d<deg; d+=64){
    int v=buf[w][d]; int r=0;
    for(int q=0;q<deg;q++) r += (buf[w][q]<v);
    epos[v] = base + r;
    ssend[base+r] = senders[v];
  }
}

// ---------- compact U3/U2/U1 into per-i sorted lists ----------
__global__ __launch_bounds__(256) void k_compact(const float* __restrict__ U3,
    const float* __restrict__ U2, const float* __restrict__ U1,
    int* u3i, float* u3v, int* u2i, float* u2v, int* u1i, float* u1v, int* uoff){
  const float* src; int n; int* oi; float* ov; int slot=blockIdx.x;
  if(slot==0){src=U3;n=16384;oi=u3i;ov=u3v;}
  else if(slot==1){src=U2;n=1024;oi=u2i;ov=u2v;}
  else {src=U1;n=64;oi=u1i;ov=u1v;}
  __shared__ int cnts[256][4]; __shared__ int bases[256][4];
  int t=threadIdx.x;
  int chunk=(n+255)/256;
  int lo=t*chunk, hi=min(n,lo+chunk); if(lo>n) lo=n;
  int c0=0,c1=0,c2=0,c3=0;
  for(int q=lo;q<hi;q++) if(src[q]!=0.f){
    int i=q&3;
    if(i==0)c0++; else if(i==1)c1++; else if(i==2)c2++; else c3++;
  }
  cnts[t][0]=c0; cnts[t][1]=c1; cnts[t][2]=c2; cnts[t][3]=c3;
  __syncthreads();
  if(t==0){
    int a=0;
    for(int i=0;i<4;i++){ uoff[slot*5+i]=a;
      for(int q=0;q<256;q++){ bases[q][i]=a; a+=cnts[q][i]; } }
    uoff[slot*5+4]=a;
  }
  __syncthreads();
  int w0=bases[t][0], w1_=bases[t][1], w2_=bases[t][2], w3_=bases[t][3];
  for(int q=lo;q<hi;q++){ float v=src[q]; if(v!=0.f){
    int i=q&3;
    if(i==0){ oi[w0]=q; ov[w0]=v; w0++; }
    else if(i==1){ oi[w1_]=q; ov[w1_]=v; w1_++; }
    else if(i==2){ oi[w2_]=q; ov[w2_]=v; w2_++; }
    else { oi[w3_]=q; ov[w3_]=v; w3_++; }
  } }
}

// ---------- fused: edge gather + Wdown + contraction + output (1 node/block) ----------
__global__ __launch_bounds__(256) void k_fused(
    const float* __restrict__ x, const __half* __restrict__ mix_h,
    const __half* __restrict__ M_h,
    const int* __restrict__ off, const int* __restrict__ ssend,
    const float* __restrict__ Wdown,
    const int* __restrict__ u3i, const float* __restrict__ u3v,
    const int* __restrict__ u2i, const float* __restrict__ u2v,
    const int* __restrict__ u1i, const float* __restrict__ u1v,
    const int* __restrict__ uoff,
    const float* __restrict__ w3, const float* __restrict__ w2,
    const float* __restrict__ w1,
    const float* __restrict__ Wsc, const float* __restrict__ Wout,
    const int* __restrict__ species,
    float* __restrict__ out)
{
  __shared__ __align__(16) float sP[4096];
  __shared__ int sSnd[256];
  // aliases (live after the reduce):
  float* sAgg = sP;           // [1024]
  float* sy   = sP + 1024;    // [512]  i*32+c
  float* sPrt = sP + 1536;    // [512]  p*128 + i*32 + c
  float* sXn  = sP + 2048;    // [512]
  float* sB   = sP + 2560;    // [128]

  int t=threadIdx.x, w=t>>6, l=t&63, lc=l&31, kh=(l>>5)*8;
  bool lohalf = (l>>5)==0;
  int n = blockIdx.x;
  int base = off[n];
  int deg  = off[n+1]-base; if (deg>256) deg=256;
  for (int d=t; d<deg; d+=256) sSnd[d]=ssend[base+d];
  __syncthreads();

  float a0=0,a1=0,a2=0,a3=0,a4=0,a5=0,a6=0,a7=0;
  float b0=0,b1=0,b2=0,b3=0,b4=0,b5=0,b6=0,b7=0;

  float4 pa,pb,pc,pd;
  if (w < deg){
    int snd0 = sSnd[w];
    const float* xr = x + (size_t)snd0*512 + lc*16;
    pa = *(const float4*)&xr[0];
    pb = *(const float4*)&xr[4];
    pc = *(const float4*)&xr[8];
    pd = *(const float4*)&xr[12];
  }

  for (int d=w; d<deg; d+=4){
    int slot = base+d;
    float4 xa=pa, xb=pb, xc=pc, xd=pd;
    int dn = d+4;
    if (dn < deg){
      int snd2 = sSnd[dn];
      const float* xr2 = x + (size_t)snd2*512 + lc*16;
      pa = *(const float4*)&xr2[0];
      pb = *(const float4*)&xr2[4];
      pc = *(const float4*)&xr2[8];
      pd = *(const float4*)&xr2[12];
    }
    const float* mrowf = (const float*)(mix_h + (size_t)slot*256);
    float2 mraw = *(const float2*)&mrowf[lc*2];
    float2 traw = *(const float2*)&mrowf[64 + lc*2];
    float2 mf01 = __half22float2(__builtin_bit_cast(__half2, mraw.x));
    float2 mf23 = __half22float2(__builtin_bit_cast(__half2, mraw.y));
    float2 mt01 = __half22float2(__builtin_bit_cast(__half2, traw.x));
    float2 mt23 = __half22float2(__builtin_bit_cast(__half2, traw.y));
    const __half* Mrow = M_h + (size_t)slot*256 + kh;
    float t0=0,t1=0,t2=0,t3=0,t4=0,t5=0,t6=0,t7=0;
#define ACCM(F,IOFF) { \
    float4 mr = *(const float4*)&Mrow[(IOFF)*16]; \
    float2 m01=__half22float2(__builtin_bit_cast(__half2, mr.x)); \
    float2 m23=__half22float2(__builtin_bit_cast(__half2, mr.y)); \
    float2 m45=__half22float2(__builtin_bit_cast(__half2, mr.z)); \
    float2 m67=__half22float2(__builtin_bit_cast(__half2, mr.w)); \
    t0+=(F)*m01.x; t1+=(F)*m01.y; t2+=(F)*m23.x; t3+=(F)*m23.y; \
    t4+=(F)*m45.x; t5+=(F)*m45.y; t6+=(F)*m67.x; t7+=(F)*m67.y; }
    ACCM(xa.x,0)  ACCM(xa.y,1)  ACCM(xa.z,2)  ACCM(xa.w,3)
    ACCM(xb.x,4)  ACCM(xb.y,5)  ACCM(xb.z,6)  ACCM(xb.w,7)
    ACCM(xc.x,8)  ACCM(xc.y,9)  ACCM(xc.z,10) ACCM(xc.w,11)
    ACCM(xd.x,12) ACCM(xd.y,13) ACCM(xd.z,14) ACCM(xd.w,15)
#undef ACCM
    float mg0 = lohalf ? mf01.x : mf23.x;
    float mg1 = lohalf ? mf01.y : mf23.y;
    float mg4 = lohalf ? mf23.x : mf23.y;
    float ng0 = lohalf ? mt01.x : mt23.x;
    float ng1 = lohalf ? mt01.y : mt23.y;
    float ng4 = lohalf ? mt23.x : mt23.y;
    float f0 = lohalf ? xa.x : xc.x;
    float f1 = lohalf ? xa.y : xc.y;
    float f2 = lohalf ? xa.z : xc.z;
    float f3 = lohalf ? xa.w : xc.w;
    float f4 = lohalf ? xb.x : xd.x;
    float f5 = lohalf ? xb.y : xd.y;
    float f6 = lohalf ? xb.z : xd.z;
    float f7 = lohalf ? xb.w : xd.w;
    a0 += f0*mg0;  b0 += t0*ng0;
    a1 += f1*mg1;  b1 += t1*ng1;
    a2 += f2*mg1;  b2 += t2*ng1;
    a3 += f3*mg1;  b3 += t3*ng1;
    a4 += f4*mg4;  b4 += t4*ng4;
    a5 += f5*mg4;  b5 += t5*ng4;
    a6 += f6*mg4;  b6 += t6*ng4;
    a7 += f7*mg4;  b7 += t7*ng4;
  }

  int ibF = w*1024 + lc*16 + kh;
  int ibT = w*1024 + (32+lc)*16 + kh;
  sP[ibF+0]=a0; sP[ibF+1]=a1; sP[ibF+2]=a2; sP[ibF+3]=a3;
  sP[ibF+4]=a4; sP[ibF+5]=a5; sP[ibF+6]=a6; sP[ibF+7]=a7;
  sP[ibT+0]=b0; sP[ibT+1]=b1; sP[ibT+2]=b2; sP[ibT+3]=b3;
  sP[ibT+4]=b4; sP[ibT+5]=b5; sP[ibT+6]=b6; sP[ibT+7]=b7;
  __syncthreads();
  // reduce 4 wave partials into sAgg (writes only idx<1024; reads >=1024 untouched)
  for (int idx=t; idx<1024; idx+=256)
    sAgg[idx] = sP[idx]+sP[1024+idx]+sP[2048+idx]+sP[3072+idx];
  __syncthreads();

  // Wdown: thread -> (ii=t&15, f0=(t>>4)*2); sy[ii*32+f0..f0+1]; stage sXn too
  sXn[t]     = x[(size_t)n*512 + t];
  sXn[256+t] = x[(size_t)n*512 + 256 + t];
  {
    int ii=t&15, f0=(t>>4)*2;
    const float* W = Wdown + l_of(ii)*2048;
    float s0=0.f, s1=0.f;
    for(int c=0;c<64;c++){
      float a = sAgg[c*16 + ii];
      float2 wv = *(const float2*)&W[c*32+f0];
      s0+=a*wv.x; s1+=a*wv.y;
    }
    sy[ii*32 + f0+0]=s0*0.0625f;
    sy[ii*32 + f0+1]=s1*0.0625f;
  }
  __syncthreads();

  // contraction: wave = term stream p; lanes: c=l&31, half-wave splits i-pairs
  int spec = species[n];
  {
    int p = __builtin_amdgcn_readfirstlane(t>>6);
    int c = l&31, hi2 = l>>5;
    const float* syc = &sy[c];
    #pragma unroll
    for(int ii2=0; ii2<2; ii2++){
      int i = hi2*2 + ii2;
      float r3=0.f;
      #pragma unroll 4
      for(int q=uoff[i]+p; q<uoff[i+1]; q+=4){
        int id=u3i[q]; float v=u3v[q];
        int a=(id>>10)&15, b=(id>>6)&15, j=(id>>2)&15;
        r3 += v*syc[a*32]*syc[b*32]*syc[j*32];
      }
      float r2=0.f;
      #pragma unroll 4
      for(int q=uoff[5+i]+p; q<uoff[5+i+1]; q+=4){
        int id=u2i[q]; float v=u2v[q];
        int a=(id>>6)&15, b=(id>>2)&15;
        r2 += v*syc[a*32]*syc[b*32];
      }
      float r1=0.f;
      for(int q=uoff[10+i]+p; q<uoff[10+i+1]; q+=4){
        int id=u1i[q]; float v=u1v[q];
        int a=(id>>2)&15;
        r1 += v*syc[a*32];
      }
      int wo = spec*64 + ((i==0)?0:32) + c;
      float wa = w3[wo], wb = w2[wo], wc = w1[wo];
      sPrt[p*128 + i*32 + c] = r3*wa + r2*wb + r1*wc;
    }
  }
  __syncthreads();

  if (t<128){
    int i=t>>5, c=t&31;
    int o = i*32 + c;
    sB[c*4 + i] = sPrt[o] + sPrt[128+o] + sPrt[256+o] + sPrt[384+o];
  }
  __syncthreads();

  if (t<128){
    int f=t>>2, i3=t&3;
    int sel = (i3==0)?0:1;
    const float* Wo = Wout + sel*1024;
    const float* Ws = Wsc + (size_t)(sel*64+spec)*1024;
    float o=0.f, sc=0.f;
    for(int c2=0;c2<32;c2++){
      o  += sB[c2*4 + i3]*Wo[c2*32+f];
      sc += sXn[c2*16 + i3]*Ws[c2*32+f];
    }
    out[(size_t)n*128 + f*4 + i3] = o + sc;
  }
}

extern "C" void kernel_launch(void* const* d_in, const int* in_sizes, int n_in,
                              void* d_out, int out_size, void* d_ws, size_t ws_size,
                              hipStream_t stream){
  (void)in_sizes; (void)n_in; (void)out_size; (void)ws_size;
  const float* feats = (const float*)d_in[0];
  const float* vec   = (const float*)d_in[1];
  const float* rad   = (const float*)d_in[2];
  const float* Wup   = (const float*)d_in[3];
  const float* CG    = (const float*)d_in[4];
  const float* Wr1   = (const float*)d_in[5];
  const float* Wr2   = (const float*)d_in[6];
  const float* Wr3   = (const float*)d_in[7];
  const float* Wr4   = (const float*)d_in[8];
  const float* Wdown = (const float*)d_in[9];
  const float* U3    = (const float*)d_in[10];
  const float* U2    = (const float*)d_in[11];
  const float* U1    = (const float*)d_in[12];
  const float* w3    = (const float*)d_in[13];
  const float* w2    = (const float*)d_in[14];
  const float* w1    = (const float*)d_in[15];
  const float* Wsc   = (const float*)d_in[16];
  const float* Wout  = (const float*)d_in[17];
  const int* species = (const int*)d_in[18];
  const int* senders = (const int*)d_in[19];
  const int* recv    = (const int*)d_in[20];
  float* out = (float*)d_out;

  char* w = (char*)d_ws;
  float* x     = (float*)w;  w += (size_t)NN*512*4;
  __half* mixh = (__half*)w; w += (size_t)EE*256*2;
  __half* Mh   = (__half*)w; w += (size_t)EE*256*2;
  int* cnt    = (int*)w;    w += (size_t)NN*4;
  int* off    = (int*)w;    w += (size_t)(NN+1)*4;
  int* pos    = (int*)w;    w += (size_t)EE*4;
  int* elist  = (int*)w;    w += (size_t)EE*4;
  int* epos   = (int*)w;    w += (size_t)EE*4;
  int* ssend  = (int*)w;    w += (size_t)EE*4;
  int* u3i    = (int*)w;    w += 16384*4;
  float* u3v  = (float*)w;  w += 16384*4;
  int* u2i    = (int*)w;    w += 1024*4;
  float* u2v  = (float*)w;  w += 1024*4;
  int* u1i    = (int*)w;    w += 64*4;
  float* u1v  = (float*)w;  w += 64*4;
  int* uoff   = (int*)w;    w += 16*4;

  k_compact<<<3,256,0,stream>>>(U3,U2,U1,u3i,u3v,u2i,u2v,u1i,u1v,uoff);
  k_x<<<NN/4,512,0,stream>>>(feats,Wup,x);
  k_zero<<<NN/256,256,0,stream>>>(cnt);
  k_count<<<EE/256,256,0,stream>>>(recv,cnt,pos);
  k_scan<<<1,256,0,stream>>>(cnt,off);
  k_fill<<<EE/256,256,0,stream>>>(recv,off,pos,elist);
  k_sort<<<NN/4,256,0,stream>>>(senders,off,elist,epos,ssend);
  k_YM<<<EE/16,256,0,stream>>>(vec,CG,epos,Mh);
  k_mix<<<EE/64,256,0,stream>>>(rad,Wr1,Wr2,Wr3,Wr4,epos,mixh);
  k_fused<<<NN,256,0,stream>>>(x,mixh,Mh,off,ssend,Wdown,
                               u3i,u3v,u2i,u2v,u1i,u1v,uoff,
                               w3,w2,w1,Wsc,Wout,species,out);
}

// Round 17
// 320.268 us; speedup vs baseline: 1.5440x; 1.1470x over previous
//
#include <hip/hip_runtime.h>
#include <hip/hip_fp16.h>
#include <math.h>

#define NN 4096
#define FF 32
#define DD 16
#define EE 65536

__device__ __forceinline__ int l_of(int i){ return (i==0)?0:(i<4)?1:(i<9)?2:3; }
__device__ __forceinline__ float silu(float v){ return v/(1.f+expf(-v)); }

// ---------- x = per_l_linear(node_feats, W_up), 4 nodes/block ----------
__global__ __launch_bounds__(512) void k_x(const float* __restrict__ feats,
        const float* __restrict__ Wup, float* __restrict__ x){
  __shared__ float sF[4*512];
  __shared__ float sW[4*FF*FF];
  int n0 = blockIdx.x*4, t = threadIdx.x;
  #pragma unroll
  for(int q=0;q<4;q++) sF[q*512+t] = feats[(size_t)(n0+q)*512 + t];
  for (int k=t;k<4*FF*FF;k+=512) sW[k]=Wup[k];
  __syncthreads();
  int f = t>>4, i = t&15;
  const float* W = &sW[l_of(i)*FF*FF];
  #pragma unroll
  for(int q=0;q<4;q++){
    float a=0.f;
    #pragma unroll
    for (int c=0;c<FF;c++) a += sF[q*512 + c*DD+i]*W[c*FF+f];
    x[(size_t)(n0+q)*512 + t] = a;
  }
}

// ---------- Y then M = Y.CG per edge -> fp16 sorted slots ----------
__global__ __launch_bounds__(256) void k_YM(const float* __restrict__ vec,
    const float* __restrict__ CG, const int* __restrict__ epos,
    __half* __restrict__ M_h){
  int t = threadIdx.x;
  int e = blockIdx.x*16 + (t>>4);
  int i = t&15;
  float vx=vec[(size_t)e*3+0], vy=vec[(size_t)e*3+1], vz=vec[(size_t)e*3+2];
  float r2=vx*vx+vy*vy+vz*vz;
  float inv = (r2==0.f)?1.f:rsqrtf(r2);
  float X=vx*inv, Y=vy*inv, Z=vz*inv;
  const float s3=1.7320508075688772f, s5=2.23606797749979f, s7=2.6457513110645907f;
  const float s15=3.872983346207417f, s42=6.48074069840786f, s70=8.366600265340756f, s105=10.246950765959598f;
  float y[15];
  y[0]=s3*X; y[1]=s3*Y; y[2]=s3*Z;
  y[3]=s15*X*Y; y[4]=s15*Y*Z; y[5]=0.5f*s5*(3.f*Z*Z-1.f); y[6]=s15*X*Z; y[7]=0.5f*s15*(X*X-Y*Y);
  y[8]=0.25f*s70*Y*(3.f*X*X-Y*Y); y[9]=s105*X*Y*Z; y[10]=0.25f*s42*Y*(5.f*Z*Z-1.f);
  y[11]=0.5f*s7*Z*(5.f*Z*Z-3.f); y[12]=0.25f*s42*X*(5.f*Z*Z-1.f);
  y[13]=0.5f*s105*Z*(X*X-Y*Y); y[14]=0.25f*s70*X*(X*X-3.f*Y*Y);
  float m[16];
  #pragma unroll
  for(int k=0;k<16;k++) m[k]=0.f;
  const float* cgr = CG + i*240;
  #pragma unroll
  for(int j=0;j<15;j++){
    float yj = y[j];
    #pragma unroll
    for(int q=0;q<4;q++){
      float4 c4 = *(const float4*)&cgr[j*16 + q*4];
      m[q*4+0]+=yj*c4.x; m[q*4+1]+=yj*c4.y; m[q*4+2]+=yj*c4.z; m[q*4+3]+=yj*c4.w;
    }
  }
  size_t slot = (size_t)epos[e];
  __half2* dst = (__half2*)&M_h[slot*256 + i*16];
  #pragma unroll
  for(int q=0;q<8;q++) dst[q] = __floats2half2_rn(m[2*q], m[2*q+1]);
}

// ---------- radial MLP -> mix_h (fp16, sorted slots) ----------
__global__ __launch_bounds__(256) void k_mix(const float* __restrict__ rad,
    const float* __restrict__ W1, const float* __restrict__ W2,
    const float* __restrict__ W3, const float* __restrict__ W4,
    const int* __restrict__ epos, __half* __restrict__ mix_h){
  __shared__ float sRadT[8*68];
  __shared__ float sW1[8*64];
  __shared__ float sHA[64*68];
  __shared__ float sHB[64*68];
  int t = threadIdx.x;
  int be = blockIdx.x*64;
  for (int k=t;k<8*64;k+=256) sW1[k]=W1[k];
  for (int idx=t; idx<64*8; idx+=256){ int e=idx>>3, k=idx&7; sRadT[k*68+e]=rad[(size_t)(be+e)*8+k]; }
  __syncthreads();
  int e0 = (t>>4)*4, j0 = (t&15)*4;
  {
    float acc[4][4];
    #pragma unroll
    for(int a=0;a<4;a++){ acc[a][0]=0;acc[a][1]=0;acc[a][2]=0;acc[a][3]=0; }
    #pragma unroll
    for(int k=0;k<8;k++){
      float4 h = *(const float4*)&sRadT[k*68+e0];
      float4 w = *(const float4*)&sW1[k*64+j0];
      acc[0][0]+=h.x*w.x; acc[0][1]+=h.x*w.y; acc[0][2]+=h.x*w.z; acc[0][3]+=h.x*w.w;
      acc[1][0]+=h.y*w.x; acc[1][1]+=h.y*w.y; acc[1][2]+=h.y*w.z; acc[1][3]+=h.y*w.w;
      acc[2][0]+=h.z*w.x; acc[2][1]+=h.z*w.y; acc[2][2]+=h.z*w.z; acc[2][3]+=h.z*w.w;
      acc[3][0]+=h.w*w.x; acc[3][1]+=h.w*w.y; acc[3][2]+=h.w*w.z; acc[3][3]+=h.w*w.w;
    }
    #pragma unroll
    for(int b=0;b<4;b++){
      float4 v; v.x=silu(acc[0][b]); v.y=silu(acc[1][b]); v.z=silu(acc[2][b]); v.w=silu(acc[3][b]);
      *(float4*)&sHA[(j0+b)*68+e0] = v;
    }
  }
  __syncthreads();
  {
    float acc[4][4];
    #pragma unroll
    for(int a=0;a<4;a++){ acc[a][0]=0;acc[a][1]=0;acc[a][2]=0;acc[a][3]=0; }
    for(int k=0;k<64;k++){
      float4 h = *(const float4*)&sHA[k*68+e0];
      float4 w = *(const float4*)&W2[k*64+j0];
      acc[0][0]+=h.x*w.x; acc[0][1]+=h.x*w.y; acc[0][2]+=h.x*w.z; acc[0][3]+=h.x*w.w;
      acc[1][0]+=h.y*w.x; acc[1][1]+=h.y*w.y; acc[1][2]+=h.y*w.z; acc[1][3]+=h.y*w.w;
      acc[2][0]+=h.z*w.x; acc[2][1]+=h.z*w.y; acc[2][2]+=h.z*w.z; acc[2][3]+=h.z*w.w;
      acc[3][0]+=h.w*w.x; acc[3][1]+=h.w*w.y; acc[3][2]+=h.w*w.z; acc[3][3]+=h.w*w.w;
    }
    #pragma unroll
    for(int b=0;b<4;b++){
      float4 v; v.x=silu(acc[0][b]); v.y=silu(acc[1][b]); v.z=silu(acc[2][b]); v.w=silu(acc[3][b]);
      *(float4*)&sHB[(j0+b)*68+e0] = v;
    }
  }
  __syncthreads();
  {
    float acc[4][4];
    #pragma unroll
    for(int a=0;a<4;a++){ acc[a][0]=0;acc[a][1]=0;acc[a][2]=0;acc[a][3]=0; }
    for(int k=0;k<64;k++){
      float4 h = *(const float4*)&sHB[k*68+e0];
      float4 w = *(const float4*)&W3[k*64+j0];
      acc[0][0]+=h.x*w.x; acc[0][1]+=h.x*w.y; acc[0][2]+=h.x*w.z; acc[0][3]+=h.x*w.w;
      acc[1][0]+=h.y*w.x; acc[1][1]+=h.y*w.y; acc[1][2]+=h.y*w.z; acc[1][3]+=h.y*w.w;
      acc[2][0]+=h.z*w.x; acc[2][1]+=h.z*w.y; acc[2][2]+=h.z*w.z; acc[2][3]+=h.z*w.w;
      acc[3][0]+=h.w*w.x; acc[3][1]+=h.w*w.y; acc[3][2]+=h.w*w.z; acc[3][3]+=h.w*w.w;
    }
    #pragma unroll
    for(int b=0;b<4;b++){
      float4 v; v.x=silu(acc[0][b]); v.y=silu(acc[1][b]); v.z=silu(acc[2][b]); v.w=silu(acc[3][b]);
      *(float4*)&sHA[(j0+b)*68+e0] = v;
    }
  }
  __syncthreads();
  {
    int cc0 = (t&63)*4, g = t>>6;
    float acc[4][4][4];
    #pragma unroll
    for(int r=0;r<4;r++)
      #pragma unroll
      for(int a=0;a<4;a++){ acc[r][a][0]=0;acc[r][a][1]=0;acc[r][a][2]=0;acc[r][a][3]=0; }
    for(int k=0;k<64;k++){
      float4 w = *(const float4*)&W4[k*256+cc0];
      #pragma unroll
      for(int r=0;r<4;r++){
        float4 h = *(const float4*)&sHA[k*68 + (g+4*r)*4];
        acc[r][0][0]+=h.x*w.x; acc[r][0][1]+=h.x*w.y; acc[r][0][2]+=h.x*w.z; acc[r][0][3]+=h.x*w.w;
        acc[r][1][0]+=h.y*w.x; acc[r][1][1]+=h.y*w.y; acc[r][1][2]+=h.y*w.z; acc[r][1][3]+=h.y*w.w;
        acc[r][2][0]+=h.z*w.x; acc[r][2][1]+=h.z*w.y; acc[r][2][2]+=h.z*w.z; acc[r][2][3]+=h.z*w.w;
        acc[r][3][0]+=h.w*w.x; acc[r][3][1]+=h.w*w.y; acc[r][3][2]+=h.w*w.z; acc[r][3][3]+=h.w*w.w;
      }
    }
    #pragma unroll
    for(int r=0;r<4;r++)
      #pragma unroll
      for(int a=0;a<4;a++){
        int e = (g+4*r)*4 + a;
        size_t ep = (size_t)epos[be+e];
        __half2* dst = (__half2*)&mix_h[ep*256 + cc0];
        dst[0]=__floats2half2_rn(acc[r][a][0], acc[r][a][1]);
        dst[1]=__floats2half2_rn(acc[r][a][2], acc[r][a][3]);
      }
  }
}

// ---------- CSR build ----------
__global__ void k_count(const int* __restrict__ recv, int* cnt, int* pos){
  int e=blockIdx.x*256+threadIdx.x; pos[e]=atomicAdd(&cnt[recv[e]],1); }
__global__ __launch_bounds__(256) void k_scan(const int* __restrict__ cnt, int* __restrict__ off){
  __shared__ int sums[256]; __shared__ int bases[256];
  int t=threadIdx.x;
  int local[16]; int s=0;
  #pragma unroll
  for(int k=0;k<16;k++){ local[k]=cnt[t*16+k]; s+=local[k]; }
  sums[t]=s; __syncthreads();
  if(t==0){ int a=0; for(int q=0;q<256;q++){ bases[q]=a; a+=sums[q]; } }
  __syncthreads();
  int acc=bases[t];
  #pragma unroll
  for(int k=0;k<16;k++){ off[t*16+k]=acc; acc+=local[k]; }
  if(t==255) off[NN]=acc;
}
__global__ void k_fill(const int* __restrict__ recv, const int* __restrict__ off,
                       const int* __restrict__ pos, int* __restrict__ elist){
  int e=blockIdx.x*256+threadIdx.x; elist[off[recv[e]]+pos[e]]=e; }

// ---------- per-node rank sort -> epos (edge->slot), ssend (slot->sender) ----------
__global__ __launch_bounds__(256) void k_sort(const int* __restrict__ senders,
    const int* __restrict__ off, const int* __restrict__ elist,
    int* __restrict__ epos, int* __restrict__ ssend){
  __shared__ int buf[4][256];
  int t=threadIdx.x, w=t>>6, l=t&63;
  int n = blockIdx.x*4 + w;
  int base = off[n];
  int deg = off[n+1]-base; if (deg>256) deg=256;
  for(int d=l; d<deg; d+=64) buf[w][d]=elist[base+d];
  __syncthreads();
  for(int d=l; d<deg; d+=64){
    int v=buf[w][d]; int r=0;
    for(int q=0;q<deg;q++) r += (buf[w][q]<v);
    epos[v] = base + r;
    ssend[base+r] = senders[v];
  }
}

// ---------- compact U3/U2/U1 into per-i sorted lists ----------
__global__ __launch_bounds__(256) void k_compact(const float* __restrict__ U3,
    const float* __restrict__ U2, const float* __restrict__ U1,
    int* u3i, float* u3v, int* u2i, float* u2v, int* u1i, float* u1v, int* uoff){
  const float* src; int n; int* oi; float* ov; int slot=blockIdx.x;
  if(slot==0){src=U3;n=16384;oi=u3i;ov=u3v;}
  else if(slot==1){src=U2;n=1024;oi=u2i;ov=u2v;}
  else {src=U1;n=64;oi=u1i;ov=u1v;}
  __shared__ int cnts[256][4]; __shared__ int bases[256][4];
  int t=threadIdx.x;
  int chunk=(n+255)/256;
  int lo=t*chunk, hi=min(n,lo+chunk); if(lo>n) lo=n;
  int c0=0,c1=0,c2=0,c3=0;
  for(int q=lo;q<hi;q++) if(src[q]!=0.f){
    int i=q&3;
    if(i==0)c0++; else if(i==1)c1++; else if(i==2)c2++; else c3++;
  }
  cnts[t][0]=c0; cnts[t][1]=c1; cnts[t][2]=c2; cnts[t][3]=c3;
  __syncthreads();
  if(t==0){
    int a=0;
    for(int i=0;i<4;i++){ uoff[slot*5+i]=a;
      for(int q=0;q<256;q++){ bases[q][i]=a; a+=cnts[q][i]; } }
    uoff[slot*5+4]=a;
  }
  __syncthreads();
  int w0=bases[t][0], w1_=bases[t][1], w2_=bases[t][2], w3_=bases[t][3];
  for(int q=lo;q<hi;q++){ float v=src[q]; if(v!=0.f){
    int i=q&3;
    if(i==0){ oi[w0]=q; ov[w0]=v; w0++; }
    else if(i==1){ oi[w1_]=q; ov[w1_]=v; w1_++; }
    else if(i==2){ oi[w2_]=q; ov[w2_]=v; w2_++; }
    else { oi[w3_]=q; ov[w3_]=v; w3_++; }
  } }
}

// ---------- edge gather: array-free + software-pipelined snd/x-row ----------
__global__ __launch_bounds__(256) void k_gather(
    const float* __restrict__ x, const __half* __restrict__ mix_h,
    const __half* __restrict__ M_h,
    const int* __restrict__ off, const int* __restrict__ ssend,
    float* __restrict__ agg)
{
  __shared__ __align__(16) float sP[4096];
  __shared__ int sSnd[256];
  int t=threadIdx.x, w=t>>6, l=t&63, lc=l&31, kh=(l>>5)*8;
  bool lohalf = (l>>5)==0;
  int n = blockIdx.x;
  int base = off[n];
  int deg  = off[n+1]-base; if (deg>256) deg=256;
  for (int d=t; d<deg; d+=256) sSnd[d]=ssend[base+d];
  __syncthreads();

  float a0=0,a1=0,a2=0,a3=0,a4=0,a5=0,a6=0,a7=0;
  float b0=0,b1=0,b2=0,b3=0,b4=0,b5=0,b6=0,b7=0;

  float4 pa,pb,pc,pd;
  if (w < deg){
    int snd0 = sSnd[w];
    const float* xr = x + (size_t)snd0*512 + lc*16;
    pa = *(const float4*)&xr[0];
    pb = *(const float4*)&xr[4];
    pc = *(const float4*)&xr[8];
    pd = *(const float4*)&xr[12];
  }

  for (int d=w; d<deg; d+=4){
    int slot = base+d;
    float4 xa=pa, xb=pb, xc=pc, xd=pd;
    int dn = d+4;
    if (dn < deg){
      int snd2 = sSnd[dn];
      const float* xr2 = x + (size_t)snd2*512 + lc*16;
      pa = *(const float4*)&xr2[0];
      pb = *(const float4*)&xr2[4];
      pc = *(const float4*)&xr2[8];
      pd = *(const float4*)&xr2[12];
    }
    const float* mrowf = (const float*)(mix_h + (size_t)slot*256);
    float2 mraw = *(const float2*)&mrowf[lc*2];
    float2 traw = *(const float2*)&mrowf[64 + lc*2];
    float2 mf01 = __half22float2(__builtin_bit_cast(__half2, mraw.x));
    float2 mf23 = __half22float2(__builtin_bit_cast(__half2, mraw.y));
    float2 mt01 = __half22float2(__builtin_bit_cast(__half2, traw.x));
    float2 mt23 = __half22float2(__builtin_bit_cast(__half2, traw.y));
    const __half* Mrow = M_h + (size_t)slot*256 + kh;
    float t0=0,t1=0,t2=0,t3=0,t4=0,t5=0,t6=0,t7=0;
#define ACCM(F,IOFF) { \
    float4 mr = *(const float4*)&Mrow[(IOFF)*16]; \
    float2 m01=__half22float2(__builtin_bit_cast(__half2, mr.x)); \
    float2 m23=__half22float2(__builtin_bit_cast(__half2, mr.y)); \
    float2 m45=__half22float2(__builtin_bit_cast(__half2, mr.z)); \
    float2 m67=__half22float2(__builtin_bit_cast(__half2, mr.w)); \
    t0+=(F)*m01.x; t1+=(F)*m01.y; t2+=(F)*m23.x; t3+=(F)*m23.y; \
    t4+=(F)*m45.x; t5+=(F)*m45.y; t6+=(F)*m67.x; t7+=(F)*m67.y; }
    ACCM(xa.x,0)  ACCM(xa.y,1)  ACCM(xa.z,2)  ACCM(xa.w,3)
    ACCM(xb.x,4)  ACCM(xb.y,5)  ACCM(xb.z,6)  ACCM(xb.w,7)
    ACCM(xc.x,8)  ACCM(xc.y,9)  ACCM(xc.z,10) ACCM(xc.w,11)
    ACCM(xd.x,12) ACCM(xd.y,13) ACCM(xd.z,14) ACCM(xd.w,15)
#undef ACCM
    float mg0 = lohalf ? mf01.x : mf23.x;
    float mg1 = lohalf ? mf01.y : mf23.y;
    float mg4 = lohalf ? mf23.x : mf23.y;
    float ng0 = lohalf ? mt01.x : mt23.x;
    float ng1 = lohalf ? mt01.y : mt23.y;
    float ng4 = lohalf ? mt23.x : mt23.y;
    float f0 = lohalf ? xa.x : xc.x;
    float f1 = lohalf ? xa.y : xc.y;
    float f2 = lohalf ? xa.z : xc.z;
    float f3 = lohalf ? xa.w : xc.w;
    float f4 = lohalf ? xb.x : xd.x;
    float f5 = lohalf ? xb.y : xd.y;
    float f6 = lohalf ? xb.z : xd.z;
    float f7 = lohalf ? xb.w : xd.w;
    a0 += f0*mg0;  b0 += t0*ng0;
    a1 += f1*mg1;  b1 += t1*ng1;
    a2 += f2*mg1;  b2 += t2*ng1;
    a3 += f3*mg1;  b3 += t3*ng1;
    a4 += f4*mg4;  b4 += t4*ng4;
    a5 += f5*mg4;  b5 += t5*ng4;
    a6 += f6*mg4;  b6 += t6*ng4;
    a7 += f7*mg4;  b7 += t7*ng4;
  }

  int ibF = w*1024 + lc*16 + kh;
  int ibT = w*1024 + (32+lc)*16 + kh;
  sP[ibF+0]=a0; sP[ibF+1]=a1; sP[ibF+2]=a2; sP[ibF+3]=a3;
  sP[ibF+4]=a4; sP[ibF+5]=a5; sP[ibF+6]=a6; sP[ibF+7]=a7;
  sP[ibT+0]=b0; sP[ibT+1]=b1; sP[ibT+2]=b2; sP[ibT+3]=b3;
  sP[ibT+4]=b4; sP[ibT+5]=b5; sP[ibT+6]=b6; sP[ibT+7]=b7;
  __syncthreads();
  for (int idx=t; idx<1024; idx+=256)
    agg[(size_t)n*1024 + idx] = sP[idx]+sP[1024+idx]+sP[2048+idx]+sP[3072+idx];
}

// ---------- tail: Wdown + contraction + output (2 nodes/block, float2 lanes, 16KB LDS) ----------
__global__ __launch_bounds__(256) void k_tail(
    const float* __restrict__ agg, const float* __restrict__ x,
    const float* __restrict__ Wdown,
    const int* __restrict__ u3i, const float* __restrict__ u3v,
    const int* __restrict__ u2i, const float* __restrict__ u2v,
    const int* __restrict__ u1i, const float* __restrict__ u1v,
    const int* __restrict__ uoff,
    const float* __restrict__ w3, const float* __restrict__ w2,
    const float* __restrict__ w1,
    const float* __restrict__ Wsc, const float* __restrict__ Wout,
    const int* __restrict__ species,
    float* __restrict__ out)
{
  __shared__ float sAgg[2048];   // phase1; phase2 alias: sXn[1024] + sB[256]
  __shared__ float sy[1024];     // [nq][i][c] : nq*512 + i*32 + c
  __shared__ float sPart[1024];  // p*256 + i*64 + nq*32 + c

  int n0 = blockIdx.x*2, t = threadIdx.x;
  #pragma unroll
  for(int q=0;q<8;q++) sAgg[q*256+t] = agg[(size_t)n0*1024 + q*256 + t];
  __syncthreads();

  // Wdown: t -> (h=t>>7, ii=(t>>3)&15, f0=(t&7)*4)
  {
    int h=t>>7, ii=(t>>3)&15, f0=(t&7)*4;
    const float* W = Wdown + l_of(ii)*2048;
    float ax=0.f, ay=0.f, az=0.f, aw=0.f;
    for(int c=0;c<64;c++){
      float a = sAgg[h*1024 + c*16 + ii];
      float4 wv = *(const float4*)&W[c*32+f0];
      ax+=a*wv.x; ay+=a*wv.y; az+=a*wv.z; aw+=a*wv.w;
    }
    sy[h*512 + ii*32 + f0+0]=ax*0.0625f;
    sy[h*512 + ii*32 + f0+1]=ay*0.0625f;
    sy[h*512 + ii*32 + f0+2]=az*0.0625f;
    sy[h*512 + ii*32 + f0+3]=aw*0.0625f;
  }
  __syncthreads();

  float* sXn = sAgg;          // [nq][512]
  float* sB  = sAgg + 1024;   // [nq][128]
  #pragma unroll
  for(int q=0;q<4;q++){ int idx=q*256+t;
    sXn[idx] = x[(size_t)(n0+(idx>>9))*512 + (idx&511)]; }

  // contraction: wave = stream p; lane group g=l>>4: nq=g&1, ihalf=g>>1; c0=(l&15)*2
  {
    int p = __builtin_amdgcn_readfirstlane(t>>6);
    int l = t&63, g = l>>4, nq = g&1, ihalf = g>>1, c0 = (l&15)*2;
    int spec = species[n0+nq];
    const float* syn = &sy[nq*512 + c0];
    #pragma unroll
    for(int ii2=0; ii2<2; ii2++){
      int i = ihalf*2 + ii2;
      float r3x=0.f, r3y=0.f;
      #pragma unroll 4
      for(int q=uoff[i]+p; q<uoff[i+1]; q+=4){
        int id=u3i[q]; float v=u3v[q];
        int a=(id>>10)&15, b=(id>>6)&15, j=(id>>2)&15;
        float2 ya=*(const float2*)&syn[a*32];
        float2 yb=*(const float2*)&syn[b*32];
        float2 yj=*(const float2*)&syn[j*32];
        r3x += v*ya.x*yb.x*yj.x;
        r3y += v*ya.y*yb.y*yj.y;
      }
      float r2x=0.f, r2y=0.f;
      #pragma unroll 4
      for(int q=uoff[5+i]+p; q<uoff[5+i+1]; q+=4){
        int id=u2i[q]; float v=u2v[q];
        int a=(id>>6)&15, b=(id>>2)&15;
        float2 ya=*(const float2*)&syn[a*32];
        float2 yb=*(const float2*)&syn[b*32];
        r2x += v*ya.x*yb.x;
        r2y += v*ya.y*yb.y;
      }
      float r1x=0.f, r1y=0.f;
      for(int q=uoff[10+i]+p; q<uoff[10+i+1]; q+=4){
        int id=u1i[q]; float v=u1v[q];
        int a=(id>>2)&15;
        float2 ya=*(const float2*)&syn[a*32];
        r1x += v*ya.x;
        r1y += v*ya.y;
      }
      int wo = spec*64 + ((i==0)?0:32) + c0;
      float2 wa = *(const float2*)&w3[wo];
      float2 wb = *(const float2*)&w2[wo];
      float2 wc = *(const float2*)&w1[wo];
      float2 res;
      res.x = r3x*wa.x + r2x*wb.x + r1x*wc.x;
      res.y = r3y*wa.y + r2y*wb.y + r1y*wc.y;
      *(float2*)&sPart[p*256 + i*64 + nq*32 + c0] = res;
    }
  }
  __syncthreads();

  // reduce over 4 streams -> sB[nq][c*4+i]  (256 values, 1/thread)
  {
    int nq=t>>7, rem=t&127, c=rem>>2, i=rem&3;
    int o = i*64 + nq*32 + c;
    sB[nq*128 + c*4 + i] = sPart[o]+sPart[256+o]+sPart[512+o]+sPart[768+o];
  }
  __syncthreads();

  // output (256 values, 1/thread)
  {
    int nq=t>>7, rem=t&127, f=rem>>2, i3=rem&3;
    int sp2 = species[n0+nq];
    int sel = (i3==0)?0:1;
    const float* Wo = Wout + sel*1024;
    const float* Ws = Wsc + (size_t)(sel*64+sp2)*1024;
    float o=0.f, sc=0.f;
    for(int c2=0;c2<32;c2++){
      o  += sB[nq*128 + c2*4 + i3]*Wo[c2*32+f];
      sc += sXn[nq*512 + c2*16 + i3]*Ws[c2*32+f];
    }
    out[(size_t)(n0+nq)*128 + f*4 + i3] = o + sc;
  }
}

extern "C" void kernel_launch(void* const* d_in, const int* in_sizes, int n_in,
                              void* d_out, int out_size, void* d_ws, size_t ws_size,
                              hipStream_t stream){
  (void)in_sizes; (void)n_in; (void)out_size; (void)ws_size;
  const float* feats = (const float*)d_in[0];
  const float* vec   = (const float*)d_in[1];
  const float* rad   = (const float*)d_in[2];
  const float* Wup   = (const float*)d_in[3];
  const float* CG    = (const float*)d_in[4];
  const float* Wr1   = (const float*)d_in[5];
  const float* Wr2   = (const float*)d_in[6];
  const float* Wr3   = (const float*)d_in[7];
  const float* Wr4   = (const float*)d_in[8];
  const float* Wdown = (const float*)d_in[9];
  const float* U3    = (const float*)d_in[10];
  const float* U2    = (const float*)d_in[11];
  const float* U1    = (const float*)d_in[12];
  const float* w3    = (const float*)d_in[13];
  const float* w2    = (const float*)d_in[14];
  const float* w1    = (const float*)d_in[15];
  const float* Wsc   = (const float*)d_in[16];
  const float* Wout  = (const float*)d_in[17];
  const int* species = (const int*)d_in[18];
  const int* senders = (const int*)d_in[19];
  const int* recv    = (const int*)d_in[20];
  float* out = (float*)d_out;

  char* w = (char*)d_ws;
  float* x     = (float*)w;  w += (size_t)NN*512*4;
  __half* mixh = (__half*)w; w += (size_t)EE*256*2;
  __half* Mh   = (__half*)w; w += (size_t)EE*256*2;
  float* agg   = (float*)w;  w += (size_t)NN*1024*4;
  int* cnt    = (int*)w;    w += (size_t)NN*4;
  int* off    = (int*)w;    w += (size_t)(NN+1)*4;
  int* pos    = (int*)w;    w += (size_t)EE*4;
  int* elist  = (int*)w;    w += (size_t)EE*4;
  int* epos   = (int*)w;    w += (size_t)EE*4;
  int* ssend  = (int*)w;    w += (size_t)EE*4;
  int* u3i    = (int*)w;    w += 16384*4;
  float* u3v  = (float*)w;  w += 16384*4;
  int* u2i    = (int*)w;    w += 1024*4;
  float* u2v  = (float*)w;  w += 1024*4;
  int* u1i    = (int*)w;    w += 64*4;
  float* u1v  = (float*)w;  w += 64*4;
  int* uoff   = (int*)w;    w += 16*4;

  hipMemsetAsync(cnt, 0, (size_t)NN*4, stream);
  k_compact<<<3,256,0,stream>>>(U3,U2,U1,u3i,u3v,u2i,u2v,u1i,u1v,uoff);
  k_x<<<NN/4,512,0,stream>>>(feats,Wup,x);
  k_count<<<EE/256,256,0,stream>>>(recv,cnt,pos);
  k_scan<<<1,256,0,stream>>>(cnt,off);
  k_fill<<<EE/256,256,0,stream>>>(recv,off,pos,elist);
  k_sort<<<NN/4,256,0,stream>>>(senders,off,elist,epos,ssend);
  k_YM<<<EE/16,256,0,stream>>>(vec,CG,epos,Mh);
  k_mix<<<EE/64,256,0,stream>>>(rad,Wr1,Wr2,Wr3,Wr4,epos,mixh);
  k_gather<<<NN,256,0,stream>>>(x,mixh,Mh,off,ssend,agg);
  k_tail<<<NN/2,256,0,stream>>>(agg,x,Wdown,u3i,u3v,u2i,u2v,u1i,u1v,uoff,
                                w3,w2,w1,Wsc,Wout,species,out);
}

// Round 18
// 298.442 us; speedup vs baseline: 1.6569x; 1.0731x over previous
//
#include <hip/hip_runtime.h>
#include <hip/hip_fp16.h>
#include <math.h>

#define NN 4096
#define FF 32
#define DD 16
#define EE 65536

__device__ __forceinline__ int l_of(int i){ return (i==0)?0:(i<4)?1:(i<9)?2:3; }
__device__ __forceinline__ float silu(float v){ return v/(1.f+expf(-v)); }

// ---------- x (4 nodes/block) + U-compact merged via block ranges ----------
__global__ __launch_bounds__(512) void k_xc(const float* __restrict__ feats,
        const float* __restrict__ Wup, float* __restrict__ x,
        const float* __restrict__ U3, const float* __restrict__ U2,
        const float* __restrict__ U1,
        int* __restrict__ u3i, float* __restrict__ u3v,
        int* __restrict__ u2i, float* __restrict__ u2v,
        int* __restrict__ u1i, float* __restrict__ u1v, int* __restrict__ uoff){
  __shared__ float sF[4*512];
  __shared__ float sW[4*FF*FF];
  int b = blockIdx.x, t = threadIdx.x;
  if (b < NN/4){
    int n0 = b*4;
    #pragma unroll
    for(int q=0;q<4;q++) sF[q*512+t] = feats[(size_t)(n0+q)*512 + t];
    for (int k=t;k<4*FF*FF;k+=512) sW[k]=Wup[k];
    __syncthreads();
    int f = t>>4, i = t&15;
    const float* W = &sW[l_of(i)*FF*FF];
    #pragma unroll
    for(int q=0;q<4;q++){
      float a=0.f;
      #pragma unroll
      for (int c=0;c<FF;c++) a += sF[q*512 + c*DD+i]*W[c*FF+f];
      x[(size_t)(n0+q)*512 + t] = a;
    }
  } else {
    // compact: blocks NN/4 .. NN/4+2, threads 0..255 active
    int slot = b - NN/4;
    int (*cnts)[4]  = (int(*)[4])sF;           // reuse LDS
    int (*bases)[4] = (int(*)[4])(sF+1024);
    const float* src; int nsz; int* oi; float* ov;
    if(slot==0){src=U3;nsz=16384;oi=u3i;ov=u3v;}
    else if(slot==1){src=U2;nsz=1024;oi=u2i;ov=u2v;}
    else {src=U1;nsz=64;oi=u1i;ov=u1v;}
    if (t < 256){
      int chunk=(nsz+255)/256;
      int lo=t*chunk, hi=min(nsz,lo+chunk); if(lo>nsz) lo=nsz;
      int c0=0,c1=0,c2=0,c3=0;
      for(int q=lo;q<hi;q++) if(src[q]!=0.f){
        int i=q&3;
        if(i==0)c0++; else if(i==1)c1++; else if(i==2)c2++; else c3++;
      }
      cnts[t][0]=c0; cnts[t][1]=c1; cnts[t][2]=c2; cnts[t][3]=c3;
    }
    __syncthreads();
    if(t==0){
      int a=0;
      for(int i=0;i<4;i++){ uoff[slot*5+i]=a;
        for(int q=0;q<256;q++){ bases[q][i]=a; a+=cnts[q][i]; } }
      uoff[slot*5+4]=a;
    }
    __syncthreads();
    if (t < 256){
      int chunk=(nsz+255)/256;
      int lo=t*chunk, hi=min(nsz,lo+chunk); if(lo>nsz) lo=nsz;
      int w0=bases[t][0], w1_=bases[t][1], w2_=bases[t][2], w3_=bases[t][3];
      for(int q=lo;q<hi;q++){ float v=src[q]; if(v!=0.f){
        int i=q&3;
        if(i==0){ oi[w0]=q; ov[w0]=v; w0++; }
        else if(i==1){ oi[w1_]=q; ov[w1_]=v; w1_++; }
        else if(i==2){ oi[w2_]=q; ov[w2_]=v; w2_++; }
        else { oi[w3_]=q; ov[w3_]=v; w3_++; }
      } }
    }
  }
}

// ---------- CSR build ----------
__global__ void k_count(const int* __restrict__ recv, int* cnt, int* pos){
  int e=blockIdx.x*256+threadIdx.x; pos[e]=atomicAdd(&cnt[recv[e]],1); }
__global__ __launch_bounds__(256) void k_scan(const int* __restrict__ cnt, int* __restrict__ off){
  __shared__ int sums[256]; __shared__ int bases[256];
  int t=threadIdx.x;
  int local[16]; int s=0;
  #pragma unroll
  for(int k=0;k<16;k++){ local[k]=cnt[t*16+k]; s+=local[k]; }
  sums[t]=s; __syncthreads();
  if(t==0){ int a=0; for(int q=0;q<256;q++){ bases[q]=a; a+=sums[q]; } }
  __syncthreads();
  int acc=bases[t];
  #pragma unroll
  for(int k=0;k<16;k++){ off[t*16+k]=acc; acc+=local[k]; }
  if(t==255) off[NN]=acc;
}
__global__ void k_fill(const int* __restrict__ recv, const int* __restrict__ off,
                       const int* __restrict__ pos, int* __restrict__ elist){
  int e=blockIdx.x*256+threadIdx.x; elist[off[recv[e]]+pos[e]]=e; }

// ---------- per-node rank sort -> epos (edge->slot), ssend (slot->sender) ----------
__global__ __launch_bounds__(256) void k_sort(const int* __restrict__ senders,
    const int* __restrict__ off, const int* __restrict__ elist,
    int* __restrict__ epos, int* __restrict__ ssend){
  __shared__ int buf[4][256];
  int t=threadIdx.x, w=t>>6, l=t&63;
  int n = blockIdx.x*4 + w;
  int base = off[n];
  int deg = off[n+1]-base; if (deg>256) deg=256;
  for(int d=l; d<deg; d+=64) buf[w][d]=elist[base+d];
  __syncthreads();
  for(int d=l; d<deg; d+=64){
    int v=buf[w][d]; int r=0;
    for(int q=0;q<deg;q++) r += (buf[w][q]<v);
    epos[v] = base + r;
    ssend[base+r] = senders[v];
  }
}

// ---------- radial MLP (blocks 0..1023) + YM (blocks 1024..5119) merged ----------
__global__ __launch_bounds__(256) void k_mixYM(const float* __restrict__ rad,
    const float* __restrict__ W1, const float* __restrict__ W2,
    const float* __restrict__ W3, const float* __restrict__ W4,
    const int* __restrict__ epos, __half* __restrict__ mix_h,
    const float* __restrict__ vec, const float* __restrict__ CG,
    __half* __restrict__ M_h){
  __shared__ float sRadT[8*68];
  __shared__ float sW1[8*64];
  __shared__ float sHA[64*68];
  __shared__ float sHB[64*68];
  int t = threadIdx.x;
  int blk = blockIdx.x;
  if (blk < EE/64){
    int be = blk*64;
    for (int k=t;k<8*64;k+=256) sW1[k]=W1[k];
    for (int idx=t; idx<64*8; idx+=256){ int e=idx>>3, k=idx&7; sRadT[k*68+e]=rad[(size_t)(be+e)*8+k]; }
    __syncthreads();
    int e0 = (t>>4)*4, j0 = (t&15)*4;
    {
      float acc[4][4];
      #pragma unroll
      for(int a=0;a<4;a++){ acc[a][0]=0;acc[a][1]=0;acc[a][2]=0;acc[a][3]=0; }
      #pragma unroll
      for(int k=0;k<8;k++){
        float4 h = *(const float4*)&sRadT[k*68+e0];
        float4 w = *(const float4*)&sW1[k*64+j0];
        acc[0][0]+=h.x*w.x; acc[0][1]+=h.x*w.y; acc[0][2]+=h.x*w.z; acc[0][3]+=h.x*w.w;
        acc[1][0]+=h.y*w.x; acc[1][1]+=h.y*w.y; acc[1][2]+=h.y*w.z; acc[1][3]+=h.y*w.w;
        acc[2][0]+=h.z*w.x; acc[2][1]+=h.z*w.y; acc[2][2]+=h.z*w.z; acc[2][3]+=h.z*w.w;
        acc[3][0]+=h.w*w.x; acc[3][1]+=h.w*w.y; acc[3][2]+=h.w*w.z; acc[3][3]+=h.w*w.w;
      }
      #pragma unroll
      for(int b=0;b<4;b++){
        float4 v; v.x=silu(acc[0][b]); v.y=silu(acc[1][b]); v.z=silu(acc[2][b]); v.w=silu(acc[3][b]);
        *(float4*)&sHA[(j0+b)*68+e0] = v;
      }
    }
    __syncthreads();
    {
      float acc[4][4];
      #pragma unroll
      for(int a=0;a<4;a++){ acc[a][0]=0;acc[a][1]=0;acc[a][2]=0;acc[a][3]=0; }
      for(int k=0;k<64;k++){
        float4 h = *(const float4*)&sHA[k*68+e0];
        float4 w = *(const float4*)&W2[k*64+j0];
        acc[0][0]+=h.x*w.x; acc[0][1]+=h.x*w.y; acc[0][2]+=h.x*w.z; acc[0][3]+=h.x*w.w;
        acc[1][0]+=h.y*w.x; acc[1][1]+=h.y*w.y; acc[1][2]+=h.y*w.z; acc[1][3]+=h.y*w.w;
        acc[2][0]+=h.z*w.x; acc[2][1]+=h.z*w.y; acc[2][2]+=h.z*w.z; acc[2][3]+=h.z*w.w;
        acc[3][0]+=h.w*w.x; acc[3][1]+=h.w*w.y; acc[3][2]+=h.w*w.z; acc[3][3]+=h.w*w.w;
      }
      #pragma unroll
      for(int b=0;b<4;b++){
        float4 v; v.x=silu(acc[0][b]); v.y=silu(acc[1][b]); v.z=silu(acc[2][b]); v.w=silu(acc[3][b]);
        *(float4*)&sHB[(j0+b)*68+e0] = v;
      }
    }
    __syncthreads();
    {
      float acc[4][4];
      #pragma unroll
      for(int a=0;a<4;a++){ acc[a][0]=0;acc[a][1]=0;acc[a][2]=0;acc[a][3]=0; }
      for(int k=0;k<64;k++){
        float4 h = *(const float4*)&sHB[k*68+e0];
        float4 w = *(const float4*)&W3[k*64+j0];
        acc[0][0]+=h.x*w.x; acc[0][1]+=h.x*w.y; acc[0][2]+=h.x*w.z; acc[0][3]+=h.x*w.w;
        acc[1][0]+=h.y*w.x; acc[1][1]+=h.y*w.y; acc[1][2]+=h.y*w.z; acc[1][3]+=h.y*w.w;
        acc[2][0]+=h.z*w.x; acc[2][1]+=h.z*w.y; acc[2][2]+=h.z*w.z; acc[2][3]+=h.z*w.w;
        acc[3][0]+=h.w*w.x; acc[3][1]+=h.w*w.y; acc[3][2]+=h.w*w.z; acc[3][3]+=h.w*w.w;
      }
      #pragma unroll
      for(int b=0;b<4;b++){
        float4 v; v.x=silu(acc[0][b]); v.y=silu(acc[1][b]); v.z=silu(acc[2][b]); v.w=silu(acc[3][b]);
        *(float4*)&sHA[(j0+b)*68+e0] = v;
      }
    }
    __syncthreads();
    {
      int cc0 = (t&63)*4, g = t>>6;
      float acc[4][4][4];
      #pragma unroll
      for(int r=0;r<4;r++)
        #pragma unroll
        for(int a=0;a<4;a++){ acc[r][a][0]=0;acc[r][a][1]=0;acc[r][a][2]=0;acc[r][a][3]=0; }
      for(int k=0;k<64;k++){
        float4 w = *(const float4*)&W4[k*256+cc0];
        #pragma unroll
        for(int r=0;r<4;r++){
          float4 h = *(const float4*)&sHA[k*68 + (g+4*r)*4];
          acc[r][0][0]+=h.x*w.x; acc[r][0][1]+=h.x*w.y; acc[r][0][2]+=h.x*w.z; acc[r][0][3]+=h.x*w.w;
          acc[r][1][0]+=h.y*w.x; acc[r][1][1]+=h.y*w.y; acc[r][1][2]+=h.y*w.z; acc[r][1][3]+=h.y*w.w;
          acc[r][2][0]+=h.z*w.x; acc[r][2][1]+=h.z*w.y; acc[r][2][2]+=h.z*w.z; acc[r][2][3]+=h.z*w.w;
          acc[r][3][0]+=h.w*w.x; acc[r][3][1]+=h.w*w.y; acc[r][3][2]+=h.w*w.z; acc[r][3][3]+=h.w*w.w;
        }
      }
      #pragma unroll
      for(int r=0;r<4;r++)
        #pragma unroll
        for(int a=0;a<4;a++){
          int e = (g+4*r)*4 + a;
          size_t ep = (size_t)epos[be+e];
          __half2* dst = (__half2*)&mix_h[ep*256 + cc0];
          dst[0]=__floats2half2_rn(acc[r][a][0], acc[r][a][1]);
          dst[1]=__floats2half2_rn(acc[r][a][2], acc[r][a][3]);
        }
    }
  } else {
    // YM blocks: 16 edges per block
    int e = (blk - EE/64)*16 + (t>>4);
    int i = t&15;
    float vx=vec[(size_t)e*3+0], vy=vec[(size_t)e*3+1], vz=vec[(size_t)e*3+2];
    float r2=vx*vx+vy*vy+vz*vz;
    float inv = (r2==0.f)?1.f:rsqrtf(r2);
    float X=vx*inv, Y=vy*inv, Z=vz*inv;
    const float s3=1.7320508075688772f, s5=2.23606797749979f, s7=2.6457513110645907f;
    const float s15=3.872983346207417f, s42=6.48074069840786f, s70=8.366600265340756f, s105=10.246950765959598f;
    float y[15];
    y[0]=s3*X; y[1]=s3*Y; y[2]=s3*Z;
    y[3]=s15*X*Y; y[4]=s15*Y*Z; y[5]=0.5f*s5*(3.f*Z*Z-1.f); y[6]=s15*X*Z; y[7]=0.5f*s15*(X*X-Y*Y);
    y[8]=0.25f*s70*Y*(3.f*X*X-Y*Y); y[9]=s105*X*Y*Z; y[10]=0.25f*s42*Y*(5.f*Z*Z-1.f);
    y[11]=0.5f*s7*Z*(5.f*Z*Z-3.f); y[12]=0.25f*s42*X*(5.f*Z*Z-1.f);
    y[13]=0.5f*s105*Z*(X*X-Y*Y); y[14]=0.25f*s70*X*(X*X-3.f*Y*Y);
    float m[16];
    #pragma unroll
    for(int k=0;k<16;k++) m[k]=0.f;
    const float* cgr = CG + i*240;
    #pragma unroll
    for(int j=0;j<15;j++){
      float yj = y[j];
      #pragma unroll
      for(int q=0;q<4;q++){
        float4 c4 = *(const float4*)&cgr[j*16 + q*4];
        m[q*4+0]+=yj*c4.x; m[q*4+1]+=yj*c4.y; m[q*4+2]+=yj*c4.z; m[q*4+3]+=yj*c4.w;
      }
    }
    size_t slot = (size_t)epos[e];
    __half2* dst = (__half2*)&M_h[slot*256 + i*16];
    #pragma unroll
    for(int q=0;q<8;q++) dst[q] = __floats2half2_rn(m[2*q], m[2*q+1]);
  }
}

// ---------- edge gather: array-free + software-pipelined snd/x-row ----------
__global__ __launch_bounds__(256) void k_gather(
    const float* __restrict__ x, const __half* __restrict__ mix_h,
    const __half* __restrict__ M_h,
    const int* __restrict__ off, const int* __restrict__ ssend,
    float* __restrict__ agg)
{
  __shared__ __align__(16) float sP[4096];
  __shared__ int sSnd[256];
  int t=threadIdx.x, w=t>>6, l=t&63, lc=l&31, kh=(l>>5)*8;
  bool lohalf = (l>>5)==0;
  int n = blockIdx.x;
  int base = off[n];
  int deg  = off[n+1]-base; if (deg>256) deg=256;
  for (int d=t; d<deg; d+=256) sSnd[d]=ssend[base+d];
  __syncthreads();

  float a0=0,a1=0,a2=0,a3=0,a4=0,a5=0,a6=0,a7=0;
  float b0=0,b1=0,b2=0,b3=0,b4=0,b5=0,b6=0,b7=0;

  float4 pa,pb,pc,pd;
  if (w < deg){
    int snd0 = sSnd[w];
    const float* xr = x + (size_t)snd0*512 + lc*16;
    pa = *(const float4*)&xr[0];
    pb = *(const float4*)&xr[4];
    pc = *(const float4*)&xr[8];
    pd = *(const float4*)&xr[12];
  }

  for (int d=w; d<deg; d+=4){
    int slot = base+d;
    float4 xa=pa, xb=pb, xc=pc, xd=pd;
    int dn = d+4;
    if (dn < deg){
      int snd2 = sSnd[dn];
      const float* xr2 = x + (size_t)snd2*512 + lc*16;
      pa = *(const float4*)&xr2[0];
      pb = *(const float4*)&xr2[4];
      pc = *(const float4*)&xr2[8];
      pd = *(const float4*)&xr2[12];
    }
    const float* mrowf = (const float*)(mix_h + (size_t)slot*256);
    float2 mraw = *(const float2*)&mrowf[lc*2];
    float2 traw = *(const float2*)&mrowf[64 + lc*2];
    float2 mf01 = __half22float2(__builtin_bit_cast(__half2, mraw.x));
    float2 mf23 = __half22float2(__builtin_bit_cast(__half2, mraw.y));
    float2 mt01 = __half22float2(__builtin_bit_cast(__half2, traw.x));
    float2 mt23 = __half22float2(__builtin_bit_cast(__half2, traw.y));
    const __half* Mrow = M_h + (size_t)slot*256 + kh;
    float t0=0,t1=0,t2=0,t3=0,t4=0,t5=0,t6=0,t7=0;
#define ACCM(F,IOFF) { \
    float4 mr = *(const float4*)&Mrow[(IOFF)*16]; \
    float2 m01=__half22float2(__builtin_bit_cast(__half2, mr.x)); \
    float2 m23=__half22float2(__builtin_bit_cast(__half2, mr.y)); \
    float2 m45=__half22float2(__builtin_bit_cast(__half2, mr.z)); \
    float2 m67=__half22float2(__builtin_bit_cast(__half2, mr.w)); \
    t0+=(F)*m01.x; t1+=(F)*m01.y; t2+=(F)*m23.x; t3+=(F)*m23.y; \
    t4+=(F)*m45.x; t5+=(F)*m45.y; t6+=(F)*m67.x; t7+=(F)*m67.y; }
    ACCM(xa.x,0)  ACCM(xa.y,1)  ACCM(xa.z,2)  ACCM(xa.w,3)
    ACCM(xb.x,4)  ACCM(xb.y,5)  ACCM(xb.z,6)  ACCM(xb.w,7)
    ACCM(xc.x,8)  ACCM(xc.y,9)  ACCM(xc.z,10) ACCM(xc.w,11)
    ACCM(xd.x,12) ACCM(xd.y,13) ACCM(xd.z,14) ACCM(xd.w,15)
#undef ACCM
    float mg0 = lohalf ? mf01.x : mf23.x;
    float mg1 = lohalf ? mf01.y : mf23.y;
    float mg4 = lohalf ? mf23.x : mf23.y;
    float ng0 = lohalf ? mt01.x : mt23.x;
    float ng1 = lohalf ? mt01.y : mt23.y;
    float ng4 = lohalf ? mt23.x : mt23.y;
    float f0 = lohalf ? xa.x : xc.x;
    float f1 = lohalf ? xa.y : xc.y;
    float f2 = lohalf ? xa.z : xc.z;
    float f3 = lohalf ? xa.w : xc.w;
    float f4 = lohalf ? xb.x : xd.x;
    float f5 = lohalf ? xb.y : xd.y;
    float f6 = lohalf ? xb.z : xd.z;
    float f7 = lohalf ? xb.w : xd.w;
    a0 += f0*mg0;  b0 += t0*ng0;
    a1 += f1*mg1;  b1 += t1*ng1;
    a2 += f2*mg1;  b2 += t2*ng1;
    a3 += f3*mg1;  b3 += t3*ng1;
    a4 += f4*mg4;  b4 += t4*ng4;
    a5 += f5*mg4;  b5 += t5*ng4;
    a6 += f6*mg4;  b6 += t6*ng4;
    a7 += f7*mg4;  b7 += t7*ng4;
  }

  int ibF = w*1024 + lc*16 + kh;
  int ibT = w*1024 + (32+lc)*16 + kh;
  sP[ibF+0]=a0; sP[ibF+1]=a1; sP[ibF+2]=a2; sP[ibF+3]=a3;
  sP[ibF+4]=a4; sP[ibF+5]=a5; sP[ibF+6]=a6; sP[ibF+7]=a7;
  sP[ibT+0]=b0; sP[ibT+1]=b1; sP[ibT+2]=b2; sP[ibT+3]=b3;
  sP[ibT+4]=b4; sP[ibT+5]=b5; sP[ibT+6]=b6; sP[ibT+7]=b7;
  __syncthreads();
  for (int idx=t; idx<1024; idx+=256)
    agg[(size_t)n*1024 + idx] = sP[idx]+sP[1024+idx]+sP[2048+idx]+sP[3072+idx];
}

// ---------- tail: Wdown + contraction + output (2 nodes/block, float2 lanes) ----------
__global__ __launch_bounds__(256) void k_tail(
    const float* __restrict__ agg, const float* __restrict__ x,
    const float* __restrict__ Wdown,
    const int* __restrict__ u3i, const float* __restrict__ u3v,
    const int* __restrict__ u2i, const float* __restrict__ u2v,
    const int* __restrict__ u1i, const float* __restrict__ u1v,
    const int* __restrict__ uoff,
    const float* __restrict__ w3, const float* __restrict__ w2,
    const float* __restrict__ w1,
    const float* __restrict__ Wsc, const float* __restrict__ Wout,
    const int* __restrict__ species,
    float* __restrict__ out)
{
  __shared__ float sAgg[2048];
  __shared__ float sy[1024];
  __shared__ float sPart[1024];

  int n0 = blockIdx.x*2, t = threadIdx.x;
  #pragma unroll
  for(int q=0;q<8;q++) sAgg[q*256+t] = agg[(size_t)n0*1024 + q*256 + t];
  __syncthreads();

  {
    int h=t>>7, ii=(t>>3)&15, f0=(t&7)*4;
    const float* W = Wdown + l_of(ii)*2048;
    float ax=0.f, ay=0.f, az=0.f, aw=0.f;
    for(int c=0;c<64;c++){
      float a = sAgg[h*1024 + c*16 + ii];
      float4 wv = *(const float4*)&W[c*32+f0];
      ax+=a*wv.x; ay+=a*wv.y; az+=a*wv.z; aw+=a*wv.w;
    }
    sy[h*512 + ii*32 + f0+0]=ax*0.0625f;
    sy[h*512 + ii*32 + f0+1]=ay*0.0625f;
    sy[h*512 + ii*32 + f0+2]=az*0.0625f;
    sy[h*512 + ii*32 + f0+3]=aw*0.0625f;
  }
  __syncthreads();

  float* sXn = sAgg;
  float* sB  = sAgg + 1024;
  #pragma unroll
  for(int q=0;q<4;q++){ int idx=q*256+t;
    sXn[idx] = x[(size_t)(n0+(idx>>9))*512 + (idx&511)]; }

  {
    int p = __builtin_amdgcn_readfirstlane(t>>6);
    int l = t&63, g = l>>4, nq = g&1, ihalf = g>>1, c0 = (l&15)*2;
    int spec = species[n0+nq];
    const float* syn = &sy[nq*512 + c0];
    #pragma unroll
    for(int ii2=0; ii2<2; ii2++){
      int i = ihalf*2 + ii2;
      float r3x=0.f, r3y=0.f;
      #pragma unroll 4
      for(int q=uoff[i]+p; q<uoff[i+1]; q+=4){
        int id=u3i[q]; float v=u3v[q];
        int a=(id>>10)&15, b=(id>>6)&15, j=(id>>2)&15;
        float2 ya=*(const float2*)&syn[a*32];
        float2 yb=*(const float2*)&syn[b*32];
        float2 yj=*(const float2*)&syn[j*32];
        r3x += v*ya.x*yb.x*yj.x;
        r3y += v*ya.y*yb.y*yj.y;
      }
      float r2x=0.f, r2y=0.f;
      #pragma unroll 4
      for(int q=uoff[5+i]+p; q<uoff[5+i+1]; q+=4){
        int id=u2i[q]; float v=u2v[q];
        int a=(id>>6)&15, b=(id>>2)&15;
        float2 ya=*(const float2*)&syn[a*32];
        float2 yb=*(const float2*)&syn[b*32];
        r2x += v*ya.x*yb.x;
        r2y += v*ya.y*yb.y;
      }
      float r1x=0.f, r1y=0.f;
      for(int q=uoff[10+i]+p; q<uoff[10+i+1]; q+=4){
        int id=u1i[q]; float v=u1v[q];
        int a=(id>>2)&15;
        float2 ya=*(const float2*)&syn[a*32];
        r1x += v*ya.x;
        r1y += v*ya.y;
      }
      int wo = spec*64 + ((i==0)?0:32) + c0;
      float2 wa = *(const float2*)&w3[wo];
      float2 wb = *(const float2*)&w2[wo];
      float2 wc = *(const float2*)&w1[wo];
      float2 res;
      res.x = r3x*wa.x + r2x*wb.x + r1x*wc.x;
      res.y = r3y*wa.y + r2y*wb.y + r1y*wc.y;
      *(float2*)&sPart[p*256 + i*64 + nq*32 + c0] = res;
    }
  }
  __syncthreads();

  {
    int nq=t>>7, rem=t&127, c=rem>>2, i=rem&3;
    int o = i*64 + nq*32 + c;
    sB[nq*128 + c*4 + i] = sPart[o]+sPart[256+o]+sPart[512+o]+sPart[768+o];
  }
  __syncthreads();

  {
    int nq=t>>7, rem=t&127, f=rem>>2, i3=rem&3;
    int sp2 = species[n0+nq];
    int sel = (i3==0)?0:1;
    const float* Wo = Wout + sel*1024;
    const float* Ws = Wsc + (size_t)(sel*64+sp2)*1024;
    float o=0.f, sc=0.f;
    for(int c2=0;c2<32;c2++){
      o  += sB[nq*128 + c2*4 + i3]*Wo[c2*32+f];
      sc += sXn[nq*512 + c2*16 + i3]*Ws[c2*32+f];
    }
    out[(size_t)(n0+nq)*128 + f*4 + i3] = o + sc;
  }
}

extern "C" void kernel_launch(void* const* d_in, const int* in_sizes, int n_in,
                              void* d_out, int out_size, void* d_ws, size_t ws_size,
                              hipStream_t stream){
  (void)in_sizes; (void)n_in; (void)out_size; (void)ws_size;
  const float* feats = (const float*)d_in[0];
  const float* vec   = (const float*)d_in[1];
  const float* rad   = (const float*)d_in[2];
  const float* Wup   = (const float*)d_in[3];
  const float* CG    = (const float*)d_in[4];
  const float* Wr1   = (const float*)d_in[5];
  const float* Wr2   = (const float*)d_in[6];
  const float* Wr3   = (const float*)d_in[7];
  const float* Wr4   = (const float*)d_in[8];
  const float* Wdown = (const float*)d_in[9];
  const float* U3    = (const float*)d_in[10];
  const float* U2    = (const float*)d_in[11];
  const float* U1    = (const float*)d_in[12];
  const float* w3    = (const float*)d_in[13];
  const float* w2    = (const float*)d_in[14];
  const float* w1    = (const float*)d_in[15];
  const float* Wsc   = (const float*)d_in[16];
  const float* Wout  = (const float*)d_in[17];
  const int* species = (const int*)d_in[18];
  const int* senders = (const int*)d_in[19];
  const int* recv    = (const int*)d_in[20];
  float* out = (float*)d_out;

  char* w = (char*)d_ws;
  float* x     = (float*)w;  w += (size_t)NN*512*4;
  __half* mixh = (__half*)w; w += (size_t)EE*256*2;
  __half* Mh   = (__half*)w; w += (size_t)EE*256*2;
  float* agg   = (float*)w;  w += (size_t)NN*1024*4;
  int* cnt    = (int*)w;    w += (size_t)NN*4;
  int* off    = (int*)w;    w += (size_t)(NN+1)*4;
  int* pos    = (int*)w;    w += (size_t)EE*4;
  int* elist  = (int*)w;    w += (size_t)EE*4;
  int* epos   = (int*)w;    w += (size_t)EE*4;
  int* ssend  = (int*)w;    w += (size_t)EE*4;
  int* u3i    = (int*)w;    w += 16384*4;
  float* u3v  = (float*)w;  w += 16384*4;
  int* u2i    = (int*)w;    w += 1024*4;
  float* u2v  = (float*)w;  w += 1024*4;
  int* u1i    = (int*)w;    w += 64*4;
  float* u1v  = (float*)w;  w += 64*4;
  int* uoff   = (int*)w;    w += 16*4;

  hipMemsetAsync(cnt, 0, (size_t)NN*4, stream);
  k_xc<<<NN/4+3,512,0,stream>>>(feats,Wup,x,U3,U2,U1,u3i,u3v,u2i,u2v,u1i,u1v,uoff);
  k_count<<<EE/256,256,0,stream>>>(recv,cnt,pos);
  k_scan<<<1,256,0,stream>>>(cnt,off);
  k_fill<<<EE/256,256,0,stream>>>(recv,off,pos,elist);
  k_sort<<<NN/4,256,0,stream>>>(senders,off,elist,epos,ssend);
  k_mixYM<<<EE/64+EE/16,256,0,stream>>>(rad,Wr1,Wr2,Wr3,Wr4,epos,mixh,vec,CG,Mh);
  k_gather<<<NN,256,0,stream>>>(x,mixh,Mh,off,ssend,agg);
  k_tail<<<NN/2,256,0,stream>>>(agg,x,Wdown,u3i,u3v,u2i,u2v,u1i,u1v,uoff,
                                w3,w2,w1,Wsc,Wout,species,out);
}

// Round 19
// 296.028 us; speedup vs baseline: 1.6705x; 1.0082x over previous
//
#include <hip/hip_runtime.h>
#include <hip/hip_fp16.h>
#include <math.h>

#define NN 4096
#define FF 32
#define DD 16
#define EE 65536

__device__ __forceinline__ int l_of(int i){ return (i==0)?0:(i<4)?1:(i<9)?2:3; }
__device__ __forceinline__ float silu(float v){ return v/(1.f+expf(-v)); }

// ---------- x (4 nodes/block) + U-compact merged via block ranges ----------
__global__ __launch_bounds__(512) void k_xc(const float* __restrict__ feats,
        const float* __restrict__ Wup, float* __restrict__ x,
        const float* __restrict__ U3, const float* __restrict__ U2,
        const float* __restrict__ U1,
        int* __restrict__ u3i, float* __restrict__ u3v,
        int* __restrict__ u2i, float* __restrict__ u2v,
        int* __restrict__ u1i, float* __restrict__ u1v, int* __restrict__ uoff){
  __shared__ float sF[4*512];
  __shared__ float sW[4*FF*FF];
  int b = blockIdx.x, t = threadIdx.x;
  if (b < NN/4){
    int n0 = b*4;
    #pragma unroll
    for(int q=0;q<4;q++) sF[q*512+t] = feats[(size_t)(n0+q)*512 + t];
    for (int k=t;k<4*FF*FF;k+=512) sW[k]=Wup[k];
    __syncthreads();
    int f = t>>4, i = t&15;
    const float* W = &sW[l_of(i)*FF*FF];
    #pragma unroll
    for(int q=0;q<4;q++){
      float a=0.f;
      #pragma unroll
      for (int c=0;c<FF;c++) a += sF[q*512 + c*DD+i]*W[c*FF+f];
      x[(size_t)(n0+q)*512 + t] = a;
    }
  } else {
    int slot = b - NN/4;
    int (*cnts)[4]  = (int(*)[4])sF;
    int (*bases)[4] = (int(*)[4])(sF+1024);
    const float* src; int nsz; int* oi; float* ov;
    if(slot==0){src=U3;nsz=16384;oi=u3i;ov=u3v;}
    else if(slot==1){src=U2;nsz=1024;oi=u2i;ov=u2v;}
    else {src=U1;nsz=64;oi=u1i;ov=u1v;}
    if (t < 256){
      int chunk=(nsz+255)/256;
      int lo=t*chunk, hi=min(nsz,lo+chunk); if(lo>nsz) lo=nsz;
      int c0=0,c1=0,c2=0,c3=0;
      for(int q=lo;q<hi;q++) if(src[q]!=0.f){
        int i=q&3;
        if(i==0)c0++; else if(i==1)c1++; else if(i==2)c2++; else c3++;
      }
      cnts[t][0]=c0; cnts[t][1]=c1; cnts[t][2]=c2; cnts[t][3]=c3;
    }
    __syncthreads();
    if(t==0){
      int a=0;
      for(int i=0;i<4;i++){ uoff[slot*5+i]=a;
        for(int q=0;q<256;q++){ bases[q][i]=a; a+=cnts[q][i]; } }
      uoff[slot*5+4]=a;
    }
    __syncthreads();
    if (t < 256){
      int chunk=(nsz+255)/256;
      int lo=t*chunk, hi=min(nsz,lo+chunk); if(lo>nsz) lo=nsz;
      int w0=bases[t][0], w1_=bases[t][1], w2_=bases[t][2], w3_=bases[t][3];
      for(int q=lo;q<hi;q++){ float v=src[q]; if(v!=0.f){
        int i=q&3;
        if(i==0){ oi[w0]=q; ov[w0]=v; w0++; }
        else if(i==1){ oi[w1_]=q; ov[w1_]=v; w1_++; }
        else if(i==2){ oi[w2_]=q; ov[w2_]=v; w2_++; }
        else { oi[w3_]=q; ov[w3_]=v; w3_++; }
      } }
    }
  }
}

// ---------- CSR build ----------
__global__ void k_count(const int* __restrict__ recv, int* cnt, int* pos){
  int e=blockIdx.x*256+threadIdx.x; pos[e]=atomicAdd(&cnt[recv[e]],1); }
__global__ __launch_bounds__(256) void k_scan(const int* __restrict__ cnt, int* __restrict__ off){
  __shared__ int sums[256]; __shared__ int bases[256];
  int t=threadIdx.x;
  int local[16]; int s=0;
  #pragma unroll
  for(int k=0;k<16;k++){ local[k]=cnt[t*16+k]; s+=local[k]; }
  sums[t]=s; __syncthreads();
  if(t==0){ int a=0; for(int q=0;q<256;q++){ bases[q]=a; a+=sums[q]; } }
  __syncthreads();
  int acc=bases[t];
  #pragma unroll
  for(int k=0;k<16;k++){ off[t*16+k]=acc; acc+=local[k]; }
  if(t==255) off[NN]=acc;
}
__global__ void k_fill(const int* __restrict__ recv, const int* __restrict__ off,
                       const int* __restrict__ pos, int* __restrict__ elist){
  int e=blockIdx.x*256+threadIdx.x; elist[off[recv[e]]+pos[e]]=e; }

// ---------- per-node rank sort -> epos (edge->slot), ssend (slot->sender) ----------
__global__ __launch_bounds__(256) void k_sort(const int* __restrict__ senders,
    const int* __restrict__ off, const int* __restrict__ elist,
    int* __restrict__ epos, int* __restrict__ ssend){
  __shared__ int buf[4][256];
  int t=threadIdx.x, w=t>>6, l=t&63;
  int n = blockIdx.x*4 + w;
  int base = off[n];
  int deg = off[n+1]-base; if (deg>256) deg=256;
  for(int d=l; d<deg; d+=64) buf[w][d]=elist[base+d];
  __syncthreads();
  for(int d=l; d<deg; d+=64){
    int v=buf[w][d]; int r=0;
    for(int q=0;q<deg;q++) r += (buf[w][q]<v);
    epos[v] = base + r;
    ssend[base+r] = senders[v];
  }
}

// ---------- radial MLP (blocks 0..1023, single-H-buffer) + YM (blocks 1024..5119) ----------
__global__ __launch_bounds__(256) void k_mixYM(const float* __restrict__ rad,
    const float* __restrict__ W1, const float* __restrict__ W2,
    const float* __restrict__ W3, const float* __restrict__ W4,
    const int* __restrict__ epos, __half* __restrict__ mix_h,
    const float* __restrict__ vec, const float* __restrict__ CG,
    __half* __restrict__ M_h){
  __shared__ float sRadT[8*68];
  __shared__ float sW1[8*64];
  __shared__ float sH[64*68];     // single buffer, ping-pong via extra barriers
  int t = threadIdx.x;
  int blk = blockIdx.x;
  if (blk < EE/64){
    int be = blk*64;
    for (int k=t;k<8*64;k+=256) sW1[k]=W1[k];
    for (int idx=t; idx<64*8; idx+=256){ int e=idx>>3, k=idx&7; sRadT[k*68+e]=rad[(size_t)(be+e)*8+k]; }
    __syncthreads();
    int e0 = (t>>4)*4, j0 = (t&15)*4;
    // L1: sH = silu(radT @ W1)
    {
      float acc[4][4];
      #pragma unroll
      for(int a=0;a<4;a++){ acc[a][0]=0;acc[a][1]=0;acc[a][2]=0;acc[a][3]=0; }
      #pragma unroll
      for(int k=0;k<8;k++){
        float4 h = *(const float4*)&sRadT[k*68+e0];
        float4 w = *(const float4*)&sW1[k*64+j0];
        acc[0][0]+=h.x*w.x; acc[0][1]+=h.x*w.y; acc[0][2]+=h.x*w.z; acc[0][3]+=h.x*w.w;
        acc[1][0]+=h.y*w.x; acc[1][1]+=h.y*w.y; acc[1][2]+=h.y*w.z; acc[1][3]+=h.y*w.w;
        acc[2][0]+=h.z*w.x; acc[2][1]+=h.z*w.y; acc[2][2]+=h.z*w.z; acc[2][3]+=h.z*w.w;
        acc[3][0]+=h.w*w.x; acc[3][1]+=h.w*w.y; acc[3][2]+=h.w*w.z; acc[3][3]+=h.w*w.w;
      }
      #pragma unroll
      for(int b=0;b<4;b++){
        float4 v; v.x=silu(acc[0][b]); v.y=silu(acc[1][b]); v.z=silu(acc[2][b]); v.w=silu(acc[3][b]);
        *(float4*)&sH[(j0+b)*68+e0] = v;
      }
    }
    __syncthreads();
    // L2: acc = sH @ W2 (read-complete) ; sync ; sH = silu(acc) ; sync
    {
      float acc[4][4];
      #pragma unroll
      for(int a=0;a<4;a++){ acc[a][0]=0;acc[a][1]=0;acc[a][2]=0;acc[a][3]=0; }
      for(int k=0;k<64;k++){
        float4 h = *(const float4*)&sH[k*68+e0];
        float4 w = *(const float4*)&W2[k*64+j0];
        acc[0][0]+=h.x*w.x; acc[0][1]+=h.x*w.y; acc[0][2]+=h.x*w.z; acc[0][3]+=h.x*w.w;
        acc[1][0]+=h.y*w.x; acc[1][1]+=h.y*w.y; acc[1][2]+=h.y*w.z; acc[1][3]+=h.y*w.w;
        acc[2][0]+=h.z*w.x; acc[2][1]+=h.z*w.y; acc[2][2]+=h.z*w.z; acc[2][3]+=h.z*w.w;
        acc[3][0]+=h.w*w.x; acc[3][1]+=h.w*w.y; acc[3][2]+=h.w*w.z; acc[3][3]+=h.w*w.w;
      }
      __syncthreads();
      #pragma unroll
      for(int b=0;b<4;b++){
        float4 v; v.x=silu(acc[0][b]); v.y=silu(acc[1][b]); v.z=silu(acc[2][b]); v.w=silu(acc[3][b]);
        *(float4*)&sH[(j0+b)*68+e0] = v;
      }
    }
    __syncthreads();
    // L3: same pattern with W3
    {
      float acc[4][4];
      #pragma unroll
      for(int a=0;a<4;a++){ acc[a][0]=0;acc[a][1]=0;acc[a][2]=0;acc[a][3]=0; }
      for(int k=0;k<64;k++){
        float4 h = *(const float4*)&sH[k*68+e0];
        float4 w = *(const float4*)&W3[k*64+j0];
        acc[0][0]+=h.x*w.x; acc[0][1]+=h.x*w.y; acc[0][2]+=h.x*w.z; acc[0][3]+=h.x*w.w;
        acc[1][0]+=h.y*w.x; acc[1][1]+=h.y*w.y; acc[1][2]+=h.y*w.z; acc[1][3]+=h.y*w.w;
        acc[2][0]+=h.z*w.x; acc[2][1]+=h.z*w.y; acc[2][2]+=h.z*w.z; acc[2][3]+=h.z*w.w;
        acc[3][0]+=h.w*w.x; acc[3][1]+=h.w*w.y; acc[3][2]+=h.w*w.z; acc[3][3]+=h.w*w.w;
      }
      __syncthreads();
      #pragma unroll
      for(int b=0;b<4;b++){
        float4 v; v.x=silu(acc[0][b]); v.y=silu(acc[1][b]); v.z=silu(acc[2][b]); v.w=silu(acc[3][b]);
        *(float4*)&sH[(j0+b)*68+e0] = v;
      }
    }
    __syncthreads();
    // L4: mix = sH @ W4 -> fp16 sorted slots
    {
      int cc0 = (t&63)*4, g = t>>6;
      float acc[4][4][4];
      #pragma unroll
      for(int r=0;r<4;r++)
        #pragma unroll
        for(int a=0;a<4;a++){ acc[r][a][0]=0;acc[r][a][1]=0;acc[r][a][2]=0;acc[r][a][3]=0; }
      for(int k=0;k<64;k++){
        float4 w = *(const float4*)&W4[k*256+cc0];
        #pragma unroll
        for(int r=0;r<4;r++){
          float4 h = *(const float4*)&sH[k*68 + (g+4*r)*4];
          acc[r][0][0]+=h.x*w.x; acc[r][0][1]+=h.x*w.y; acc[r][0][2]+=h.x*w.z; acc[r][0][3]+=h.x*w.w;
          acc[r][1][0]+=h.y*w.x; acc[r][1][1]+=h.y*w.y; acc[r][1][2]+=h.y*w.z; acc[r][1][3]+=h.y*w.w;
          acc[r][2][0]+=h.z*w.x; acc[r][2][1]+=h.z*w.y; acc[r][2][2]+=h.z*w.z; acc[r][2][3]+=h.z*w.w;
          acc[r][3][0]+=h.w*w.x; acc[r][3][1]+=h.w*w.y; acc[r][3][2]+=h.w*w.z; acc[r][3][3]+=h.w*w.w;
        }
      }
      #pragma unroll
      for(int r=0;r<4;r++)
        #pragma unroll
        for(int a=0;a<4;a++){
          int e = (g+4*r)*4 + a;
          size_t ep = (size_t)epos[be+e];
          __half2* dst = (__half2*)&mix_h[ep*256 + cc0];
          dst[0]=__floats2half2_rn(acc[r][a][0], acc[r][a][1]);
          dst[1]=__floats2half2_rn(acc[r][a][2], acc[r][a][3]);
        }
    }
  } else {
    // YM blocks: 16 edges per block
    int e = (blk - EE/64)*16 + (t>>4);
    int i = t&15;
    float vx=vec[(size_t)e*3+0], vy=vec[(size_t)e*3+1], vz=vec[(size_t)e*3+2];
    float r2=vx*vx+vy*vy+vz*vz;
    float inv = (r2==0.f)?1.f:rsqrtf(r2);
    float X=vx*inv, Y=vy*inv, Z=vz*inv;
    const float s3=1.7320508075688772f, s5=2.23606797749979f, s7=2.6457513110645907f;
    const float s15=3.872983346207417f, s42=6.48074069840786f, s70=8.366600265340756f, s105=10.246950765959598f;
    float y[15];
    y[0]=s3*X; y[1]=s3*Y; y[2]=s3*Z;
    y[3]=s15*X*Y; y[4]=s15*Y*Z; y[5]=0.5f*s5*(3.f*Z*Z-1.f); y[6]=s15*X*Z; y[7]=0.5f*s15*(X*X-Y*Y);
    y[8]=0.25f*s70*Y*(3.f*X*X-Y*Y); y[9]=s105*X*Y*Z; y[10]=0.25f*s42*Y*(5.f*Z*Z-1.f);
    y[11]=0.5f*s7*Z*(5.f*Z*Z-3.f); y[12]=0.25f*s42*X*(5.f*Z*Z-1.f);
    y[13]=0.5f*s105*Z*(X*X-Y*Y); y[14]=0.25f*s70*X*(X*X-3.f*Y*Y);
    float m[16];
    #pragma unroll
    for(int k=0;k<16;k++) m[k]=0.f;
    const float* cgr = CG + i*240;
    #pragma unroll
    for(int j=0;j<15;j++){
      float yj = y[j];
      #pragma unroll
      for(int q=0;q<4;q++){
        float4 c4 = *(const float4*)&cgr[j*16 + q*4];
        m[q*4+0]+=yj*c4.x; m[q*4+1]+=yj*c4.y; m[q*4+2]+=yj*c4.z; m[q*4+3]+=yj*c4.w;
      }
    }
    size_t slot = (size_t)epos[e];
    __half2* dst = (__half2*)&M_h[slot*256 + i*16];
    #pragma unroll
    for(int q=0;q<8;q++) dst[q] = __floats2half2_rn(m[2*q], m[2*q+1]);
  }
}

// ---------- edge gather: array-free + software-pipelined snd/x-row ----------
__global__ __launch_bounds__(256) void k_gather(
    const float* __restrict__ x, const __half* __restrict__ mix_h,
    const __half* __restrict__ M_h,
    const int* __restrict__ off, const int* __restrict__ ssend,
    float* __restrict__ agg)
{
  __shared__ __align__(16) float sP[4096];
  __shared__ int sSnd[256];
  int t=threadIdx.x, w=t>>6, l=t&63, lc=l&31, kh=(l>>5)*8;
  bool lohalf = (l>>5)==0;
  int n = blockIdx.x;
  int base = off[n];
  int deg  = off[n+1]-base; if (deg>256) deg=256;
  for (int d=t; d<deg; d+=256) sSnd[d]=ssend[base+d];
  __syncthreads();

  float a0=0,a1=0,a2=0,a3=0,a4=0,a5=0,a6=0,a7=0;
  float b0=0,b1=0,b2=0,b3=0,b4=0,b5=0,b6=0,b7=0;

  float4 pa,pb,pc,pd;
  if (w < deg){
    int snd0 = sSnd[w];
    const float* xr = x + (size_t)snd0*512 + lc*16;
    pa = *(const float4*)&xr[0];
    pb = *(const float4*)&xr[4];
    pc = *(const float4*)&xr[8];
    pd = *(const float4*)&xr[12];
  }

  for (int d=w; d<deg; d+=4){
    int slot = base+d;
    float4 xa=pa, xb=pb, xc=pc, xd=pd;
    int dn = d+4;
    if (dn < deg){
      int snd2 = sSnd[dn];
      const float* xr2 = x + (size_t)snd2*512 + lc*16;
      pa = *(const float4*)&xr2[0];
      pb = *(const float4*)&xr2[4];
      pc = *(const float4*)&xr2[8];
      pd = *(const float4*)&xr2[12];
    }
    const float* mrowf = (const float*)(mix_h + (size_t)slot*256);
    float2 mraw = *(const float2*)&mrowf[lc*2];
    float2 traw = *(const float2*)&mrowf[64 + lc*2];
    float2 mf01 = __half22float2(__builtin_bit_cast(__half2, mraw.x));
    float2 mf23 = __half22float2(__builtin_bit_cast(__half2, mraw.y));
    float2 mt01 = __half22float2(__builtin_bit_cast(__half2, traw.x));
    float2 mt23 = __half22float2(__builtin_bit_cast(__half2, traw.y));
    const __half* Mrow = M_h + (size_t)slot*256 + kh;
    float t0=0,t1=0,t2=0,t3=0,t4=0,t5=0,t6=0,t7=0;
#define ACCM(F,IOFF) { \
    float4 mr = *(const float4*)&Mrow[(IOFF)*16]; \
    float2 m01=__half22float2(__builtin_bit_cast(__half2, mr.x)); \
    float2 m23=__half22float2(__builtin_bit_cast(__half2, mr.y)); \
    float2 m45=__half22float2(__builtin_bit_cast(__half2, mr.z)); \
    float2 m67=__half22float2(__builtin_bit_cast(__half2, mr.w)); \
    t0+=(F)*m01.x; t1+=(F)*m01.y; t2+=(F)*m23.x; t3+=(F)*m23.y; \
    t4+=(F)*m45.x; t5+=(F)*m45.y; t6+=(F)*m67.x; t7+=(F)*m67.y; }
    ACCM(xa.x,0)  ACCM(xa.y,1)  ACCM(xa.z,2)  ACCM(xa.w,3)
    ACCM(xb.x,4)  ACCM(xb.y,5)  ACCM(xb.z,6)  ACCM(xb.w,7)
    ACCM(xc.x,8)  ACCM(xc.y,9)  ACCM(xc.z,10) ACCM(xc.w,11)
    ACCM(xd.x,12) ACCM(xd.y,13) ACCM(xd.z,14) ACCM(xd.w,15)
#undef ACCM
    float mg0 = lohalf ? mf01.x : mf23.x;
    float mg1 = lohalf ? mf01.y : mf23.y;
    float mg4 = lohalf ? mf23.x : mf23.y;
    float ng0 = lohalf ? mt01.x : mt23.x;
    float ng1 = lohalf ? mt01.y : mt23.y;
    float ng4 = lohalf ? mt23.x : mt23.y;
    float f0 = lohalf ? xa.x : xc.x;
    float f1 = lohalf ? xa.y : xc.y;
    float f2 = lohalf ? xa.z : xc.z;
    float f3 = lohalf ? xa.w : xc.w;
    float f4 = lohalf ? xb.x : xd.x;
    float f5 = lohalf ? xb.y : xd.y;
    float f6 = lohalf ? xb.z : xd.z;
    float f7 = lohalf ? xb.w : xd.w;
    a0 += f0*mg0;  b0 += t0*ng0;
    a1 += f1*mg1;  b1 += t1*ng1;
    a2 += f2*mg1;  b2 += t2*ng1;
    a3 += f3*mg1;  b3 += t3*ng1;
    a4 += f4*mg4;  b4 += t4*ng4;
    a5 += f5*mg4;  b5 += t5*ng4;
    a6 += f6*mg4;  b6 += t6*ng4;
    a7 += f7*mg4;  b7 += t7*ng4;
  }

  int ibF = w*1024 + lc*16 + kh;
  int ibT = w*1024 + (32+lc)*16 + kh;
  sP[ibF+0]=a0; sP[ibF+1]=a1; sP[ibF+2]=a2; sP[ibF+3]=a3;
  sP[ibF+4]=a4; sP[ibF+5]=a5; sP[ibF+6]=a6; sP[ibF+7]=a7;
  sP[ibT+0]=b0; sP[ibT+1]=b1; sP[ibT+2]=b2; sP[ibT+3]=b3;
  sP[ibT+4]=b4; sP[ibT+5]=b5; sP[ibT+6]=b6; sP[ibT+7]=b7;
  __syncthreads();
  for (int idx=t; idx<1024; idx+=256)
    agg[(size_t)n*1024 + idx] = sP[idx]+sP[1024+idx]+sP[2048+idx]+sP[3072+idx];
}

// ---------- tail: Wdown + contraction + output (2 nodes/block, float2 lanes) ----------
__global__ __launch_bounds__(256) void k_tail(
    const float* __restrict__ agg, const float* __restrict__ x,
    const float* __restrict__ Wdown,
    const int* __restrict__ u3i, const float* __restrict__ u3v,
    const int* __restrict__ u2i, const float* __restrict__ u2v,
    const int* __restrict__ u1i, const float* __restrict__ u1v,
    const int* __restrict__ uoff,
    const float* __restrict__ w3, const float* __restrict__ w2,
    const float* __restrict__ w1,
    const float* __restrict__ Wsc, const float* __restrict__ Wout,
    const int* __restrict__ species,
    float* __restrict__ out)
{
  __shared__ float sAgg[2048];
  __shared__ float sy[1024];
  __shared__ float sPart[1024];

  int n0 = blockIdx.x*2, t = threadIdx.x;
  #pragma unroll
  for(int q=0;q<8;q++) sAgg[q*256+t] = agg[(size_t)n0*1024 + q*256 + t];
  __syncthreads();

  {
    int h=t>>7, ii=(t>>3)&15, f0=(t&7)*4;
    const float* W = Wdown + l_of(ii)*2048;
    float ax=0.f, ay=0.f, az=0.f, aw=0.f;
    for(int c=0;c<64;c++){
      float a = sAgg[h*1024 + c*16 + ii];
      float4 wv = *(const float4*)&W[c*32+f0];
      ax+=a*wv.x; ay+=a*wv.y; az+=a*wv.z; aw+=a*wv.w;
    }
    sy[h*512 + ii*32 + f0+0]=ax*0.0625f;
    sy[h*512 + ii*32 + f0+1]=ay*0.0625f;
    sy[h*512 + ii*32 + f0+2]=az*0.0625f;
    sy[h*512 + ii*32 + f0+3]=aw*0.0625f;
  }
  __syncthreads();

  float* sXn = sAgg;
  float* sB  = sAgg + 1024;
  #pragma unroll
  for(int q=0;q<4;q++){ int idx=q*256+t;
    sXn[idx] = x[(size_t)(n0+(idx>>9))*512 + (idx&511)]; }

  {
    int p = __builtin_amdgcn_readfirstlane(t>>6);
    int l = t&63, g = l>>4, nq = g&1, ihalf = g>>1, c0 = (l&15)*2;
    int spec = species[n0+nq];
    const float* syn = &sy[nq*512 + c0];
    #pragma unroll
    for(int ii2=0; ii2<2; ii2++){
      int i = ihalf*2 + ii2;
      float r3x=0.f, r3y=0.f;
      #pragma unroll 4
      for(int q=uoff[i]+p; q<uoff[i+1]; q+=4){
        int id=u3i[q]; float v=u3v[q];
        int a=(id>>10)&15, b=(id>>6)&15, j=(id>>2)&15;
        float2 ya=*(const float2*)&syn[a*32];
        float2 yb=*(const float2*)&syn[b*32];
        float2 yj=*(const float2*)&syn[j*32];
        r3x += v*ya.x*yb.x*yj.x;
        r3y += v*ya.y*yb.y*yj.y;
      }
      float r2x=0.f, r2y=0.f;
      #pragma unroll 4
      for(int q=uoff[5+i]+p; q<uoff[5+i+1]; q+=4){
        int id=u2i[q]; float v=u2v[q];
        int a=(id>>6)&15, b=(id>>2)&15;
        float2 ya=*(const float2*)&syn[a*32];
        float2 yb=*(const float2*)&syn[b*32];
        r2x += v*ya.x*yb.x;
        r2y += v*ya.y*yb.y;
      }
      float r1x=0.f, r1y=0.f;
      for(int q=uoff[10+i]+p; q<uoff[10+i+1]; q+=4){
        int id=u1i[q]; float v=u1v[q];
        int a=(id>>2)&15;
        float2 ya=*(const float2*)&syn[a*32];
        r1x += v*ya.x;
        r1y += v*ya.y;
      }
      int wo = spec*64 + ((i==0)?0:32) + c0;
      float2 wa = *(const float2*)&w3[wo];
      float2 wb = *(const float2*)&w2[wo];
      float2 wc = *(const float2*)&w1[wo];
      float2 res;
      res.x = r3x*wa.x + r2x*wb.x + r1x*wc.x;
      res.y = r3y*wa.y + r2y*wb.y + r1y*wc.y;
      *(float2*)&sPart[p*256 + i*64 + nq*32 + c0] = res;
    }
  }
  __syncthreads();

  {
    int nq=t>>7, rem=t&127, c=rem>>2, i=rem&3;
    int o = i*64 + nq*32 + c;
    sB[nq*128 + c*4 + i] = sPart[o]+sPart[256+o]+sPart[512+o]+sPart[768+o];
  }
  __syncthreads();

  {
    int nq=t>>7, rem=t&127, f=rem>>2, i3=rem&3;
    int sp2 = species[n0+nq];
    int sel = (i3==0)?0:1;
    const float* Wo = Wout + sel*1024;
    const float* Ws = Wsc + (size_t)(sel*64+sp2)*1024;
    float o=0.f, sc=0.f;
    for(int c2=0;c2<32;c2++){
      o  += sB[nq*128 + c2*4 + i3]*Wo[c2*32+f];
      sc += sXn[nq*512 + c2*16 + i3]*Ws[c2*32+f];
    }
    out[(size_t)(n0+nq)*128 + f*4 + i3] = o + sc;
  }
}

extern "C" void kernel_launch(void* const* d_in, const int* in_sizes, int n_in,
                              void* d_out, int out_size, void* d_ws, size_t ws_size,
                              hipStream_t stream){
  (void)in_sizes; (void)n_in; (void)out_size; (void)ws_size;
  const float* feats = (const float*)d_in[0];
  const float* vec   = (const float*)d_in[1];
  const float* rad   = (const float*)d_in[2];
  const float* Wup   = (const float*)d_in[3];
  const float* CG    = (const float*)d_in[4];
  const float* Wr1   = (const float*)d_in[5];
  const float* Wr2   = (const float*)d_in[6];
  const float* Wr3   = (const float*)d_in[7];
  const float* Wr4   = (const float*)d_in[8];
  const float* Wdown = (const float*)d_in[9];
  const float* U3    = (const float*)d_in[10];
  const float* U2    = (const float*)d_in[11];
  const float* U1    = (const float*)d_in[12];
  const float* w3    = (const float*)d_in[13];
  const float* w2    = (const float*)d_in[14];
  const float* w1    = (const float*)d_in[15];
  const float* Wsc   = (const float*)d_in[16];
  const float* Wout  = (const float*)d_in[17];
  const int* species = (const int*)d_in[18];
  const int* senders = (const int*)d_in[19];
  const int* recv    = (const int*)d_in[20];
  float* out = (float*)d_out;

  char* w = (char*)d_ws;
  float* x     = (float*)w;  w += (size_t)NN*512*4;
  __half* mixh = (__half*)w; w += (size_t)EE*256*2;
  __half* Mh   = (__half*)w; w += (size_t)EE*256*2;
  float* agg   = (float*)w;  w += (size_t)NN*1024*4;
  int* cnt    = (int*)w;    w += (size_t)NN*4;
  int* off    = (int*)w;    w += (size_t)(NN+1)*4;
  int* pos    = (int*)w;    w += (size_t)EE*4;
  int* elist  = (int*)w;    w += (size_t)EE*4;
  int* epos   = (int*)w;    w += (size_t)EE*4;
  int* ssend  = (int*)w;    w += (size_t)EE*4;
  int* u3i    = (int*)w;    w += 16384*4;
  float* u3v  = (float*)w;  w += 16384*4;
  int* u2i    = (int*)w;    w += 1024*4;
  float* u2v  = (float*)w;  w += 1024*4;
  int* u1i    = (int*)w;    w += 64*4;
  float* u1v  = (float*)w;  w += 64*4;
  int* uoff   = (int*)w;    w += 16*4;

  hipMemsetAsync(cnt, 0, (size_t)NN*4, stream);
  k_xc<<<NN/4+3,512,0,stream>>>(feats,Wup,x,U3,U2,U1,u3i,u3v,u2i,u2v,u1i,u1v,uoff);
  k_count<<<EE/256,256,0,stream>>>(recv,cnt,pos);
  k_scan<<<1,256,0,stream>>>(cnt,off);
  k_fill<<<EE/256,256,0,stream>>>(recv,off,pos,elist);
  k_sort<<<NN/4,256,0,stream>>>(senders,off,elist,epos,ssend);
  k_mixYM<<<EE/64+EE/16,256,0,stream>>>(rad,Wr1,Wr2,Wr3,Wr4,epos,mixh,vec,CG,Mh);
  k_gather<<<NN,256,0,stream>>>(x,mixh,Mh,off,ssend,agg);
  k_tail<<<NN/2,256,0,stream>>>(agg,x,Wdown,u3i,u3v,u2i,u2v,u1i,u1v,uoff,
                                w3,w2,w1,Wsc,Wout,species,out);
}

// Round 20
// 286.782 us; speedup vs baseline: 1.7243x; 1.0322x over previous
//
#include <hip/hip_runtime.h>
#include <hip/hip_fp16.h>
#include <math.h>

#define NN 4096
#define FF 32
#define DD 16
#define EE 65536

__device__ __forceinline__ int l_of(int i){ return (i==0)?0:(i<4)?1:(i<9)?2:3; }
__device__ __forceinline__ float silu(float v){ return v/(1.f+expf(-v)); }

// ---------- x (4 nodes/block) + U-compact merged via block ranges ----------
__global__ __launch_bounds__(512) void k_xc(const float* __restrict__ feats,
        const float* __restrict__ Wup, float* __restrict__ x,
        const float* __restrict__ U3, const float* __restrict__ U2,
        const float* __restrict__ U1,
        int* __restrict__ u3i, float* __restrict__ u3v,
        int* __restrict__ u2i, float* __restrict__ u2v,
        int* __restrict__ u1i, float* __restrict__ u1v, int* __restrict__ uoff){
  __shared__ float sF[4*512];
  __shared__ float sW[4*FF*FF];
  int b = blockIdx.x, t = threadIdx.x;
  if (b < NN/4){
    int n0 = b*4;
    #pragma unroll
    for(int q=0;q<4;q++) sF[q*512+t] = feats[(size_t)(n0+q)*512 + t];
    for (int k=t;k<4*FF*FF;k+=512) sW[k]=Wup[k];
    __syncthreads();
    int f = t>>4, i = t&15;
    const float* W = &sW[l_of(i)*FF*FF];
    #pragma unroll
    for(int q=0;q<4;q++){
      float a=0.f;
      #pragma unroll
      for (int c=0;c<FF;c++) a += sF[q*512 + c*DD+i]*W[c*FF+f];
      x[(size_t)(n0+q)*512 + t] = a;
    }
  } else {
    int slot = b - NN/4;
    int (*cnts)[4]  = (int(*)[4])sF;
    int (*bases)[4] = (int(*)[4])(sF+1024);
    const float* src; int nsz; int* oi; float* ov;
    if(slot==0){src=U3;nsz=16384;oi=u3i;ov=u3v;}
    else if(slot==1){src=U2;nsz=1024;oi=u2i;ov=u2v;}
    else {src=U1;nsz=64;oi=u1i;ov=u1v;}
    if (t < 256){
      int chunk=(nsz+255)/256;
      int lo=t*chunk, hi=min(nsz,lo+chunk); if(lo>nsz) lo=nsz;
      int c0=0,c1=0,c2=0,c3=0;
      for(int q=lo;q<hi;q++) if(src[q]!=0.f){
        int i=q&3;
        if(i==0)c0++; else if(i==1)c1++; else if(i==2)c2++; else c3++;
      }
      cnts[t][0]=c0; cnts[t][1]=c1; cnts[t][2]=c2; cnts[t][3]=c3;
    }
    __syncthreads();
    if(t==0){
      int a=0;
      for(int i=0;i<4;i++){ uoff[slot*5+i]=a;
        for(int q=0;q<256;q++){ bases[q][i]=a; a+=cnts[q][i]; } }
      uoff[slot*5+4]=a;
    }
    __syncthreads();
    if (t < 256){
      int chunk=(nsz+255)/256;
      int lo=t*chunk, hi=min(nsz,lo+chunk); if(lo>nsz) lo=nsz;
      int w0=bases[t][0], w1_=bases[t][1], w2_=bases[t][2], w3_=bases[t][3];
      for(int q=lo;q<hi;q++){ float v=src[q]; if(v!=0.f){
        int i=q&3;
        if(i==0){ oi[w0]=q; ov[w0]=v; w0++; }
        else if(i==1){ oi[w1_]=q; ov[w1_]=v; w1_++; }
        else if(i==2){ oi[w2_]=q; ov[w2_]=v; w2_++; }
        else { oi[w3_]=q; ov[w3_]=v; w3_++; }
      } }
    }
  }
}

// ---------- CSR build ----------
__global__ void k_count(const int* __restrict__ recv, int* cnt, int* pos){
  int e=blockIdx.x*256+threadIdx.x; pos[e]=atomicAdd(&cnt[recv[e]],1); }
__global__ __launch_bounds__(256) void k_scan(const int* __restrict__ cnt, int* __restrict__ off){
  __shared__ int sums[256]; __shared__ int bases[256];
  int t=threadIdx.x;
  int local[16]; int s=0;
  #pragma unroll
  for(int k=0;k<16;k++){ local[k]=cnt[t*16+k]; s+=local[k]; }
  sums[t]=s; __syncthreads();
  if(t==0){ int a=0; for(int q=0;q<256;q++){ bases[q]=a; a+=sums[q]; } }
  __syncthreads();
  int acc=bases[t];
  #pragma unroll
  for(int k=0;k<16;k++){ off[t*16+k]=acc; acc+=local[k]; }
  if(t==255) off[NN]=acc;
}
__global__ void k_fill(const int* __restrict__ recv, const int* __restrict__ off,
                       const int* __restrict__ pos, int* __restrict__ elist){
  int e=blockIdx.x*256+threadIdx.x; elist[off[recv[e]]+pos[e]]=e; }

// ---------- sort + YM fused: rank edges, then compute M=Y.CG into sorted slots ----------
__global__ __launch_bounds__(256) void k_sortYM(const int* __restrict__ senders,
    const int* __restrict__ off, const int* __restrict__ elist,
    const float* __restrict__ vec, const float* __restrict__ CG,
    int* __restrict__ epos, int* __restrict__ ssend, __half* __restrict__ M_h){
  __shared__ int buf[4][256];
  __shared__ int rbuf[4][256];
  int t=threadIdx.x, w=t>>6, l=t&63;
  int n = blockIdx.x*4 + w;
  int base = off[n];
  int deg = off[n+1]-base; if (deg>256) deg=256;
  for(int d=l; d<deg; d+=64) buf[w][d]=elist[base+d];
  __syncthreads();
  for(int d=l; d<deg; d+=64){
    int v=buf[w][d]; int r=0;
    for(int q=0;q<deg;q++) r += (buf[w][q]<v);
    epos[v] = base + r;
    rbuf[w][d] = r;
    ssend[base+r] = senders[v];
  }
  // M = Y.CG for this node's edges: 4 edges at a time, 16 i-lanes each
  int il = l&15;
  const float* cgr = CG + il*240;
  for(int d0=(l>>4); d0<deg; d0+=4){
    int v = buf[w][d0];
    int slot = base + rbuf[w][d0];
    float vx=vec[(size_t)v*3+0], vy=vec[(size_t)v*3+1], vz=vec[(size_t)v*3+2];
    float r2=vx*vx+vy*vy+vz*vz;
    float inv = (r2==0.f)?1.f:rsqrtf(r2);
    float X=vx*inv, Y=vy*inv, Z=vz*inv;
    const float s3=1.7320508075688772f, s5=2.23606797749979f, s7=2.6457513110645907f;
    const float s15=3.872983346207417f, s42=6.48074069840786f, s70=8.366600265340756f, s105=10.246950765959598f;
    float y[15];
    y[0]=s3*X; y[1]=s3*Y; y[2]=s3*Z;
    y[3]=s15*X*Y; y[4]=s15*Y*Z; y[5]=0.5f*s5*(3.f*Z*Z-1.f); y[6]=s15*X*Z; y[7]=0.5f*s15*(X*X-Y*Y);
    y[8]=0.25f*s70*Y*(3.f*X*X-Y*Y); y[9]=s105*X*Y*Z; y[10]=0.25f*s42*Y*(5.f*Z*Z-1.f);
    y[11]=0.5f*s7*Z*(5.f*Z*Z-3.f); y[12]=0.25f*s42*X*(5.f*Z*Z-1.f);
    y[13]=0.5f*s105*Z*(X*X-Y*Y); y[14]=0.25f*s70*X*(X*X-3.f*Y*Y);
    float m[16];
    #pragma unroll
    for(int k=0;k<16;k++) m[k]=0.f;
    #pragma unroll
    for(int j=0;j<15;j++){
      float yj = y[j];
      #pragma unroll
      for(int q=0;q<4;q++){
        float4 c4 = *(const float4*)&cgr[j*16 + q*4];
        m[q*4+0]+=yj*c4.x; m[q*4+1]+=yj*c4.y; m[q*4+2]+=yj*c4.z; m[q*4+3]+=yj*c4.w;
      }
    }
    __half2* dst = (__half2*)&M_h[(size_t)slot*256 + il*16];
    #pragma unroll
    for(int q=0;q<8;q++) dst[q] = __floats2half2_rn(m[2*q], m[2*q+1]);
  }
}

// ---------- radial MLP -> mix_h (fp16, sorted slots), single-H-buffer ----------
__global__ __launch_bounds__(256) void k_mix(const float* __restrict__ rad,
    const float* __restrict__ W1, const float* __restrict__ W2,
    const float* __restrict__ W3, const float* __restrict__ W4,
    const int* __restrict__ epos, __half* __restrict__ mix_h){
  __shared__ float sRadT[8*68];
  __shared__ float sW1[8*64];
  __shared__ float sH[64*68];
  int t = threadIdx.x;
  int be = blockIdx.x*64;
  for (int k=t;k<8*64;k+=256) sW1[k]=W1[k];
  for (int idx=t; idx<64*8; idx+=256){ int e=idx>>3, k=idx&7; sRadT[k*68+e]=rad[(size_t)(be+e)*8+k]; }
  __syncthreads();
  int e0 = (t>>4)*4, j0 = (t&15)*4;
  {
    float acc[4][4];
    #pragma unroll
    for(int a=0;a<4;a++){ acc[a][0]=0;acc[a][1]=0;acc[a][2]=0;acc[a][3]=0; }
    #pragma unroll
    for(int k=0;k<8;k++){
      float4 h = *(const float4*)&sRadT[k*68+e0];
      float4 w = *(const float4*)&sW1[k*64+j0];
      acc[0][0]+=h.x*w.x; acc[0][1]+=h.x*w.y; acc[0][2]+=h.x*w.z; acc[0][3]+=h.x*w.w;
      acc[1][0]+=h.y*w.x; acc[1][1]+=h.y*w.y; acc[1][2]+=h.y*w.z; acc[1][3]+=h.y*w.w;
      acc[2][0]+=h.z*w.x; acc[2][1]+=h.z*w.y; acc[2][2]+=h.z*w.z; acc[2][3]+=h.z*w.w;
      acc[3][0]+=h.w*w.x; acc[3][1]+=h.w*w.y; acc[3][2]+=h.w*w.z; acc[3][3]+=h.w*w.w;
    }
    #pragma unroll
    for(int b=0;b<4;b++){
      float4 v; v.x=silu(acc[0][b]); v.y=silu(acc[1][b]); v.z=silu(acc[2][b]); v.w=silu(acc[3][b]);
      *(float4*)&sH[(j0+b)*68+e0] = v;
    }
  }
  __syncthreads();
  {
    float acc[4][4];
    #pragma unroll
    for(int a=0;a<4;a++){ acc[a][0]=0;acc[a][1]=0;acc[a][2]=0;acc[a][3]=0; }
    for(int k=0;k<64;k++){
      float4 h = *(const float4*)&sH[k*68+e0];
      float4 w = *(const float4*)&W2[k*64+j0];
      acc[0][0]+=h.x*w.x; acc[0][1]+=h.x*w.y; acc[0][2]+=h.x*w.z; acc[0][3]+=h.x*w.w;
      acc[1][0]+=h.y*w.x; acc[1][1]+=h.y*w.y; acc[1][2]+=h.y*w.z; acc[1][3]+=h.y*w.w;
      acc[2][0]+=h.z*w.x; acc[2][1]+=h.z*w.y; acc[2][2]+=h.z*w.z; acc[2][3]+=h.z*w.w;
      acc[3][0]+=h.w*w.x; acc[3][1]+=h.w*w.y; acc[3][2]+=h.w*w.z; acc[3][3]+=h.w*w.w;
    }
    __syncthreads();
    #pragma unroll
    for(int b=0;b<4;b++){
      float4 v; v.x=silu(acc[0][b]); v.y=silu(acc[1][b]); v.z=silu(acc[2][b]); v.w=silu(acc[3][b]);
      *(float4*)&sH[(j0+b)*68+e0] = v;
    }
  }
  __syncthreads();
  {
    float acc[4][4];
    #pragma unroll
    for(int a=0;a<4;a++){ acc[a][0]=0;acc[a][1]=0;acc[a][2]=0;acc[a][3]=0; }
    for(int k=0;k<64;k++){
      float4 h = *(const float4*)&sH[k*68+e0];
      float4 w = *(const float4*)&W3[k*64+j0];
      acc[0][0]+=h.x*w.x; acc[0][1]+=h.x*w.y; acc[0][2]+=h.x*w.z; acc[0][3]+=h.x*w.w;
      acc[1][0]+=h.y*w.x; acc[1][1]+=h.y*w.y; acc[1][2]+=h.y*w.z; acc[1][3]+=h.y*w.w;
      acc[2][0]+=h.z*w.x; acc[2][1]+=h.z*w.y; acc[2][2]+=h.z*w.z; acc[2][3]+=h.z*w.w;
      acc[3][0]+=h.w*w.x; acc[3][1]+=h.w*w.y; acc[3][2]+=h.w*w.z; acc[3][3]+=h.w*w.w;
    }
    __syncthreads();
    #pragma unroll
    for(int b=0;b<4;b++){
      float4 v; v.x=silu(acc[0][b]); v.y=silu(acc[1][b]); v.z=silu(acc[2][b]); v.w=silu(acc[3][b]);
      *(float4*)&sH[(j0+b)*68+e0] = v;
    }
  }
  __syncthreads();
  {
    int cc0 = (t&63)*4, g = t>>6;
    float acc[4][4][4];
    #pragma unroll
    for(int r=0;r<4;r++)
      #pragma unroll
      for(int a=0;a<4;a++){ acc[r][a][0]=0;acc[r][a][1]=0;acc[r][a][2]=0;acc[r][a][3]=0; }
    for(int k=0;k<64;k++){
      float4 w = *(const float4*)&W4[k*256+cc0];
      #pragma unroll
      for(int r=0;r<4;r++){
        float4 h = *(const float4*)&sH[k*68 + (g+4*r)*4];
        acc[r][0][0]+=h.x*w.x; acc[r][0][1]+=h.x*w.y; acc[r][0][2]+=h.x*w.z; acc[r][0][3]+=h.x*w.w;
        acc[r][1][0]+=h.y*w.x; acc[r][1][1]+=h.y*w.y; acc[r][1][2]+=h.y*w.z; acc[r][1][3]+=h.y*w.w;
        acc[r][2][0]+=h.z*w.x; acc[r][2][1]+=h.z*w.y; acc[r][2][2]+=h.z*w.z; acc[r][2][3]+=h.z*w.w;
        acc[r][3][0]+=h.w*w.x; acc[r][3][1]+=h.w*w.y; acc[r][3][2]+=h.w*w.z; acc[r][3][3]+=h.w*w.w;
      }
    }
    #pragma unroll
    for(int r=0;r<4;r++)
      #pragma unroll
      for(int a=0;a<4;a++){
        int e = (g+4*r)*4 + a;
        size_t ep = (size_t)epos[be+e];
        __half2* dst = (__half2*)&mix_h[ep*256 + cc0];
        dst[0]=__floats2half2_rn(acc[r][a][0], acc[r][a][1]);
        dst[1]=__floats2half2_rn(acc[r][a][2], acc[r][a][3]);
      }
  }
}

// ---------- edge gather: array-free + software-pipelined snd/x-row ----------
__global__ __launch_bounds__(256) void k_gather(
    const float* __restrict__ x, const __half* __restrict__ mix_h,
    const __half* __restrict__ M_h,
    const int* __restrict__ off, const int* __restrict__ ssend,
    float* __restrict__ agg)
{
  __shared__ __align__(16) float sP[4096];
  __shared__ int sSnd[256];
  int t=threadIdx.x, w=t>>6, l=t&63, lc=l&31, kh=(l>>5)*8;
  bool lohalf = (l>>5)==0;
  int n = blockIdx.x;
  int base = off[n];
  int deg  = off[n+1]-base; if (deg>256) deg=256;
  for (int d=t; d<deg; d+=256) sSnd[d]=ssend[base+d];
  __syncthreads();

  float a0=0,a1=0,a2=0,a3=0,a4=0,a5=0,a6=0,a7=0;
  float b0=0,b1=0,b2=0,b3=0,b4=0,b5=0,b6=0,b7=0;

  float4 pa,pb,pc,pd;
  if (w < deg){
    int snd0 = sSnd[w];
    const float* xr = x + (size_t)snd0*512 + lc*16;
    pa = *(const float4*)&xr[0];
    pb = *(const float4*)&xr[4];
    pc = *(const float4*)&xr[8];
    pd = *(const float4*)&xr[12];
  }

  for (int d=w; d<deg; d+=4){
    int slot = base+d;
    float4 xa=pa, xb=pb, xc=pc, xd=pd;
    int dn = d+4;
    if (dn < deg){
      int snd2 = sSnd[dn];
      const float* xr2 = x + (size_t)snd2*512 + lc*16;
      pa = *(const float4*)&xr2[0];
      pb = *(const float4*)&xr2[4];
      pc = *(const float4*)&xr2[8];
      pd = *(const float4*)&xr2[12];
    }
    const float* mrowf = (const float*)(mix_h + (size_t)slot*256);
    float2 mraw = *(const float2*)&mrowf[lc*2];
    float2 traw = *(const float2*)&mrowf[64 + lc*2];
    float2 mf01 = __half22float2(__builtin_bit_cast(__half2, mraw.x));
    float2 mf23 = __half22float2(__builtin_bit_cast(__half2, mraw.y));
    float2 mt01 = __half22float2(__builtin_bit_cast(__half2, traw.x));
    float2 mt23 = __half22float2(__builtin_bit_cast(__half2, traw.y));
    const __half* Mrow = M_h + (size_t)slot*256 + kh;
    float t0=0,t1=0,t2=0,t3=0,t4=0,t5=0,t6=0,t7=0;
#define ACCM(F,IOFF) { \
    float4 mr = *(const float4*)&Mrow[(IOFF)*16]; \
    float2 m01=__half22float2(__builtin_bit_cast(__half2, mr.x)); \
    float2 m23=__half22float2(__builtin_bit_cast(__half2, mr.y)); \
    float2 m45=__half22float2(__builtin_bit_cast(__half2, mr.z)); \
    float2 m67=__half22float2(__builtin_bit_cast(__half2, mr.w)); \
    t0+=(F)*m01.x; t1+=(F)*m01.y; t2+=(F)*m23.x; t3+=(F)*m23.y; \
    t4+=(F)*m45.x; t5+=(F)*m45.y; t6+=(F)*m67.x; t7+=(F)*m67.y; }
    ACCM(xa.x,0)  ACCM(xa.y,1)  ACCM(xa.z,2)  ACCM(xa.w,3)
    ACCM(xb.x,4)  ACCM(xb.y,5)  ACCM(xb.z,6)  ACCM(xb.w,7)
    ACCM(xc.x,8)  ACCM(xc.y,9)  ACCM(xc.z,10) ACCM(xc.w,11)
    ACCM(xd.x,12) ACCM(xd.y,13) ACCM(xd.z,14) ACCM(xd.w,15)
#undef ACCM
    float mg0 = lohalf ? mf01.x : mf23.x;
    float mg1 = lohalf ? mf01.y : mf23.y;
    float mg4 = lohalf ? mf23.x : mf23.y;
    float ng0 = lohalf ? mt01.x : mt23.x;
    float ng1 = lohalf ? mt01.y : mt23.y;
    float ng4 = lohalf ? mt23.x : mt23.y;
    float f0 = lohalf ? xa.x : xc.x;
    float f1 = lohalf ? xa.y : xc.y;
    float f2 = lohalf ? xa.z : xc.z;
    float f3 = lohalf ? xa.w : xc.w;
    float f4 = lohalf ? xb.x : xd.x;
    float f5 = lohalf ? xb.y : xd.y;
    float f6 = lohalf ? xb.z : xd.z;
    float f7 = lohalf ? xb.w : xd.w;
    a0 += f0*mg0;  b0 += t0*ng0;
    a1 += f1*mg1;  b1 += t1*ng1;
    a2 += f2*mg1;  b2 += t2*ng1;
    a3 += f3*mg1;  b3 += t3*ng1;
    a4 += f4*mg4;  b4 += t4*ng4;
    a5 += f5*mg4;  b5 += t5*ng4;
    a6 += f6*mg4;  b6 += t6*ng4;
    a7 += f7*mg4;  b7 += t7*ng4;
  }

  int ibF = w*1024 + lc*16 + kh;
  int ibT = w*1024 + (32+lc)*16 + kh;
  sP[ibF+0]=a0; sP[ibF+1]=a1; sP[ibF+2]=a2; sP[ibF+3]=a3;
  sP[ibF+4]=a4; sP[ibF+5]=a5; sP[ibF+6]=a6; sP[ibF+7]=a7;
  sP[ibT+0]=b0; sP[ibT+1]=b1; sP[ibT+2]=b2; sP[ibT+3]=b3;
  sP[ibT+4]=b4; sP[ibT+5]=b5; sP[ibT+6]=b6; sP[ibT+7]=b7;
  __syncthreads();
  for (int idx=t; idx<1024; idx+=256)
    agg[(size_t)n*1024 + idx] = sP[idx]+sP[1024+idx]+sP[2048+idx]+sP[3072+idx];
}

// ---------- tail: Wdown + contraction + output (2 nodes/block, float2 lanes) ----------
__global__ __launch_bounds__(256) void k_tail(
    const float* __restrict__ agg, const float* __restrict__ x,
    const float* __restrict__ Wdown,
    const int* __restrict__ u3i, const float* __restrict__ u3v,
    const int* __restrict__ u2i, const float* __restrict__ u2v,
    const int* __restrict__ u1i, const float* __restrict__ u1v,
    const int* __restrict__ uoff,
    const float* __restrict__ w3, const float* __restrict__ w2,
    const float* __restrict__ w1,
    const float* __restrict__ Wsc, const float* __restrict__ Wout,
    const int* __restrict__ species,
    float* __restrict__ out)
{
  __shared__ float sAgg[2048];
  __shared__ float sy[1024];
  __shared__ float sPart[1024];

  int n0 = blockIdx.x*2, t = threadIdx.x;
  #pragma unroll
  for(int q=0;q<8;q++) sAgg[q*256+t] = agg[(size_t)n0*1024 + q*256 + t];
  __syncthreads();

  {
    int h=t>>7, ii=(t>>3)&15, f0=(t&7)*4;
    const float* W = Wdown + l_of(ii)*2048;
    float ax=0.f, ay=0.f, az=0.f, aw=0.f;
    for(int c=0;c<64;c++){
      float a = sAgg[h*1024 + c*16 + ii];
      float4 wv = *(const float4*)&W[c*32+f0];
      ax+=a*wv.x; ay+=a*wv.y; az+=a*wv.z; aw+=a*wv.w;
    }
    sy[h*512 + ii*32 + f0+0]=ax*0.0625f;
    sy[h*512 + ii*32 + f0+1]=ay*0.0625f;
    sy[h*512 + ii*32 + f0+2]=az*0.0625f;
    sy[h*512 + ii*32 + f0+3]=aw*0.0625f;
  }
  __syncthreads();

  float* sXn = sAgg;
  float* sB  = sAgg + 1024;
  #pragma unroll
  for(int q=0;q<4;q++){ int idx=q*256+t;
    sXn[idx] = x[(size_t)(n0+(idx>>9))*512 + (idx&511)]; }

  {
    int p = __builtin_amdgcn_readfirstlane(t>>6);
    int l = t&63, g = l>>4, nq = g&1, ihalf = g>>1, c0 = (l&15)*2;
    int spec = species[n0+nq];
    const float* syn = &sy[nq*512 + c0];
    #pragma unroll
    for(int ii2=0; ii2<2; ii2++){
      int i = ihalf*2 + ii2;
      float r3x=0.f, r3y=0.f;
      #pragma unroll 4
      for(int q=uoff[i]+p; q<uoff[i+1]; q+=4){
        int id=u3i[q]; float v=u3v[q];
        int a=(id>>10)&15, b=(id>>6)&15, j=(id>>2)&15;
        float2 ya=*(const float2*)&syn[a*32];
        float2 yb=*(const float2*)&syn[b*32];
        float2 yj=*(const float2*)&syn[j*32];
        r3x += v*ya.x*yb.x*yj.x;
        r3y += v*ya.y*yb.y*yj.y;
      }
      float r2x=0.f, r2y=0.f;
      #pragma unroll 4
      for(int q=uoff[5+i]+p; q<uoff[5+i+1]; q+=4){
        int id=u2i[q]; float v=u2v[q];
        int a=(id>>6)&15, b=(id>>2)&15;
        float2 ya=*(const float2*)&syn[a*32];
        float2 yb=*(const float2*)&syn[b*32];
        r2x += v*ya.x*yb.x;
        r2y += v*ya.y*yb.y;
      }
      float r1x=0.f, r1y=0.f;
      for(int q=uoff[10+i]+p; q<uoff[10+i+1]; q+=4){
        int id=u1i[q]; float v=u1v[q];
        int a=(id>>2)&15;
        float2 ya=*(const float2*)&syn[a*32];
        r1x += v*ya.x;
        r1y += v*ya.y;
      }
      int wo = spec*64 + ((i==0)?0:32) + c0;
      float2 wa = *(const float2*)&w3[wo];
      float2 wb = *(const float2*)&w2[wo];
      float2 wc = *(const float2*)&w1[wo];
      float2 res;
      res.x = r3x*wa.x + r2x*wb.x + r1x*wc.x;
      res.y = r3y*wa.y + r2y*wb.y + r1y*wc.y;
      *(float2*)&sPart[p*256 + i*64 + nq*32 + c0] = res;
    }
  }
  __syncthreads();

  {
    int nq=t>>7, rem=t&127, c=rem>>2, i=rem&3;
    int o = i*64 + nq*32 + c;
    sB[nq*128 + c*4 + i] = sPart[o]+sPart[256+o]+sPart[512+o]+sPart[768+o];
  }
  __syncthreads();

  {
    int nq=t>>7, rem=t&127, f=rem>>2, i3=rem&3;
    int sp2 = species[n0+nq];
    int sel = (i3==0)?0:1;
    const float* Wo = Wout + sel*1024;
    const float* Ws = Wsc + (size_t)(sel*64+sp2)*1024;
    float o=0.f, sc=0.f;
    for(int c2=0;c2<32;c2++){
      o  += sB[nq*128 + c2*4 + i3]*Wo[c2*32+f];
      sc += sXn[nq*512 + c2*16 + i3]*Ws[c2*32+f];
    }
    out[(size_t)(n0+nq)*128 + f*4 + i3] = o + sc;
  }
}

extern "C" void kernel_launch(void* const* d_in, const int* in_sizes, int n_in,
                              void* d_out, int out_size, void* d_ws, size_t ws_size,
                              hipStream_t stream){
  (void)in_sizes; (void)n_in; (void)out_size; (void)ws_size;
  const float* feats = (const float*)d_in[0];
  const float* vec   = (const float*)d_in[1];
  const float* rad   = (const float*)d_in[2];
  const float* Wup   = (const float*)d_in[3];
  const float* CG    = (const float*)d_in[4];
  const float* Wr1   = (const float*)d_in[5];
  const float* Wr2   = (const float*)d_in[6];
  const float* Wr3   = (const float*)d_in[7];
  const float* Wr4   = (const float*)d_in[8];
  const float* Wdown = (const float*)d_in[9];
  const float* U3    = (const float*)d_in[10];
  const float* U2    = (const float*)d_in[11];
  const float* U1    = (const float*)d_in[12];
  const float* w3    = (const float*)d_in[13];
  const float* w2    = (const float*)d_in[14];
  const float* w1    = (const float*)d_in[15];
  const float* Wsc   = (const float*)d_in[16];
  const float* Wout  = (const float*)d_in[17];
  const int* species = (const int*)d_in[18];
  const int* senders = (const int*)d_in[19];
  const int* recv    = (const int*)d_in[20];
  float* out = (float*)d_out;

  char* w = (char*)d_ws;
  float* x     = (float*)w;  w += (size_t)NN*512*4;
  __half* mixh = (__half*)w; w += (size_t)EE*256*2;
  __half* Mh   = (__half*)w; w += (size_t)EE*256*2;
  float* agg   = (float*)w;  w += (size_t)NN*1024*4;
  int* cnt    = (int*)w;    w += (size_t)NN*4;
  int* off    = (int*)w;    w += (size_t)(NN+1)*4;
  int* pos    = (int*)w;    w += (size_t)EE*4;
  int* elist  = (int*)w;    w += (size_t)EE*4;
  int* epos   = (int*)w;    w += (size_t)EE*4;
  int* ssend  = (int*)w;    w += (size_t)EE*4;
  int* u3i    = (int*)w;    w += 16384*4;
  float* u3v  = (float*)w;  w += 16384*4;
  int* u2i    = (int*)w;    w += 1024*4;
  float* u2v  = (float*)w;  w += 1024*4;
  int* u1i    = (int*)w;    w += 64*4;
  float* u1v  = (float*)w;  w += 64*4;
  int* uoff   = (int*)w;    w += 16*4;

  hipMemsetAsync(cnt, 0, (size_t)NN*4, stream);
  k_xc<<<NN/4+3,512,0,stream>>>(feats,Wup,x,U3,U2,U1,u3i,u3v,u2i,u2v,u1i,u1v,uoff);
  k_count<<<EE/256,256,0,stream>>>(recv,cnt,pos);
  k_scan<<<1,256,0,stream>>>(cnt,off);
  k_fill<<<EE/256,256,0,stream>>>(recv,off,pos,elist);
  k_sortYM<<<NN/4,256,0,stream>>>(senders,off,elist,vec,CG,epos,ssend,Mh);
  k_mix<<<EE/64,256,0,stream>>>(rad,Wr1,Wr2,Wr3,Wr4,epos,mixh);
  k_gather<<<NN,256,0,stream>>>(x,mixh,Mh,off,ssend,agg);
  k_tail<<<NN/2,256,0,stream>>>(agg,x,Wdown,u3i,u3v,u2i,u2v,u1i,u1v,uoff,
                                w3,w2,w1,Wsc,Wout,species,out);
}

// Round 21
// 281.330 us; speedup vs baseline: 1.7577x; 1.0194x over previous
//
#include <hip/hip_runtime.h>
#include <hip/hip_fp16.h>
#include <math.h>

#define NN 4096
#define FF 32
#define DD 16
#define EE 65536

__device__ __forceinline__ int l_of(int i){ return (i==0)?0:(i<4)?1:(i<9)?2:3; }
__device__ __forceinline__ float silu(float v){ return v/(1.f+expf(-v)); }

// ---------- x (4 nodes/block, fp32 + fp16 copies) + U-compact merged ----------
__global__ __launch_bounds__(512) void k_xc(const float* __restrict__ feats,
        const float* __restrict__ Wup, float* __restrict__ x, __half* __restrict__ xh,
        const float* __restrict__ U3, const float* __restrict__ U2,
        const float* __restrict__ U1,
        int* __restrict__ u3i, float* __restrict__ u3v,
        int* __restrict__ u2i, float* __restrict__ u2v,
        int* __restrict__ u1i, float* __restrict__ u1v, int* __restrict__ uoff){
  __shared__ float sF[4*512];
  __shared__ float sW[4*FF*FF];
  int b = blockIdx.x, t = threadIdx.x;
  if (b < NN/4){
    int n0 = b*4;
    #pragma unroll
    for(int q=0;q<4;q++) sF[q*512+t] = feats[(size_t)(n0+q)*512 + t];
    for (int k=t;k<4*FF*FF;k+=512) sW[k]=Wup[k];
    __syncthreads();
    int f = t>>4, i = t&15;
    const float* W = &sW[l_of(i)*FF*FF];
    #pragma unroll
    for(int q=0;q<4;q++){
      float a=0.f;
      #pragma unroll
      for (int c=0;c<FF;c++) a += sF[q*512 + c*DD+i]*W[c*FF+f];
      x[(size_t)(n0+q)*512 + t] = a;
      xh[(size_t)(n0+q)*512 + t] = __float2half(a);
    }
  } else {
    int slot = b - NN/4;
    int (*cnts)[4]  = (int(*)[4])sF;
    int (*bases)[4] = (int(*)[4])(sF+1024);
    const float* src; int nsz; int* oi; float* ov;
    if(slot==0){src=U3;nsz=16384;oi=u3i;ov=u3v;}
    else if(slot==1){src=U2;nsz=1024;oi=u2i;ov=u2v;}
    else {src=U1;nsz=64;oi=u1i;ov=u1v;}
    if (t < 256){
      int chunk=(nsz+255)/256;
      int lo=t*chunk, hi=min(nsz,lo+chunk); if(lo>nsz) lo=nsz;
      int c0=0,c1=0,c2=0,c3=0;
      for(int q=lo;q<hi;q++) if(src[q]!=0.f){
        int i=q&3;
        if(i==0)c0++; else if(i==1)c1++; else if(i==2)c2++; else c3++;
      }
      cnts[t][0]=c0; cnts[t][1]=c1; cnts[t][2]=c2; cnts[t][3]=c3;
    }
    __syncthreads();
    if(t==0){
      int a=0;
      for(int i=0;i<4;i++){ uoff[slot*5+i]=a;
        for(int q=0;q<256;q++){ bases[q][i]=a; a+=cnts[q][i]; } }
      uoff[slot*5+4]=a;
    }
    __syncthreads();
    if (t < 256){
      int chunk=(nsz+255)/256;
      int lo=t*chunk, hi=min(nsz,lo+chunk); if(lo>nsz) lo=nsz;
      int w0=bases[t][0], w1_=bases[t][1], w2_=bases[t][2], w3_=bases[t][3];
      for(int q=lo;q<hi;q++){ float v=src[q]; if(v!=0.f){
        int i=q&3;
        if(i==0){ oi[w0]=q; ov[w0]=v; w0++; }
        else if(i==1){ oi[w1_]=q; ov[w1_]=v; w1_++; }
        else if(i==2){ oi[w2_]=q; ov[w2_]=v; w2_++; }
        else { oi[w3_]=q; ov[w3_]=v; w3_++; }
      } }
    }
  }
}

// ---------- CSR build ----------
__global__ void k_count(const int* __restrict__ recv, int* cnt, int* pos){
  int e=blockIdx.x*256+threadIdx.x; pos[e]=atomicAdd(&cnt[recv[e]],1); }
__global__ __launch_bounds__(256) void k_scan(const int* __restrict__ cnt, int* __restrict__ off){
  __shared__ int sums[256]; __shared__ int bases[256];
  int t=threadIdx.x;
  int local[16]; int s=0;
  #pragma unroll
  for(int k=0;k<16;k++){ local[k]=cnt[t*16+k]; s+=local[k]; }
  sums[t]=s; __syncthreads();
  if(t==0){ int a=0; for(int q=0;q<256;q++){ bases[q]=a; a+=sums[q]; } }
  __syncthreads();
  int acc=bases[t];
  #pragma unroll
  for(int k=0;k<16;k++){ off[t*16+k]=acc; acc+=local[k]; }
  if(t==255) off[NN]=acc;
}
__global__ void k_fill(const int* __restrict__ recv, const int* __restrict__ off,
                       const int* __restrict__ pos, int* __restrict__ elist){
  int e=blockIdx.x*256+threadIdx.x; elist[off[recv[e]]+pos[e]]=e; }

// ---------- sort + YM fused: rank edges, then compute M=Y.CG into sorted slots ----------
__global__ __launch_bounds__(256) void k_sortYM(const int* __restrict__ senders,
    const int* __restrict__ off, const int* __restrict__ elist,
    const float* __restrict__ vec, const float* __restrict__ CG,
    int* __restrict__ epos, int* __restrict__ ssend, __half* __restrict__ M_h){
  __shared__ int buf[4][256];
  __shared__ int rbuf[4][256];
  int t=threadIdx.x, w=t>>6, l=t&63;
  int n = blockIdx.x*4 + w;
  int base = off[n];
  int deg = off[n+1]-base; if (deg>256) deg=256;
  for(int d=l; d<deg; d+=64) buf[w][d]=elist[base+d];
  __syncthreads();
  for(int d=l; d<deg; d+=64){
    int v=buf[w][d]; int r=0;
    for(int q=0;q<deg;q++) r += (buf[w][q]<v);
    epos[v] = base + r;
    rbuf[w][d] = r;
    ssend[base+r] = senders[v];
  }
  int il = l&15;
  const float* cgr = CG + il*240;
  for(int d0=(l>>4); d0<deg; d0+=4){
    int v = buf[w][d0];
    int slot = base + rbuf[w][d0];
    float vx=vec[(size_t)v*3+0], vy=vec[(size_t)v*3+1], vz=vec[(size_t)v*3+2];
    float r2=vx*vx+vy*vy+vz*vz;
    float inv = (r2==0.f)?1.f:rsqrtf(r2);
    float X=vx*inv, Y=vy*inv, Z=vz*inv;
    const float s3=1.7320508075688772f, s5=2.23606797749979f, s7=2.6457513110645907f;
    const float s15=3.872983346207417f, s42=6.48074069840786f, s70=8.366600265340756f, s105=10.246950765959598f;
    float y[15];
    y[0]=s3*X; y[1]=s3*Y; y[2]=s3*Z;
    y[3]=s15*X*Y; y[4]=s15*Y*Z; y[5]=0.5f*s5*(3.f*Z*Z-1.f); y[6]=s15*X*Z; y[7]=0.5f*s15*(X*X-Y*Y);
    y[8]=0.25f*s70*Y*(3.f*X*X-Y*Y); y[9]=s105*X*Y*Z; y[10]=0.25f*s42*Y*(5.f*Z*Z-1.f);
    y[11]=0.5f*s7*Z*(5.f*Z*Z-3.f); y[12]=0.25f*s42*X*(5.f*Z*Z-1.f);
    y[13]=0.5f*s105*Z*(X*X-Y*Y); y[14]=0.25f*s70*X*(X*X-3.f*Y*Y);
    float m[16];
    #pragma unroll
    for(int k=0;k<16;k++) m[k]=0.f;
    #pragma unroll
    for(int j=0;j<15;j++){
      float yj = y[j];
      #pragma unroll
      for(int q=0;q<4;q++){
        float4 c4 = *(const float4*)&cgr[j*16 + q*4];
        m[q*4+0]+=yj*c4.x; m[q*4+1]+=yj*c4.y; m[q*4+2]+=yj*c4.z; m[q*4+3]+=yj*c4.w;
      }
    }
    __half2* dst = (__half2*)&M_h[(size_t)slot*256 + il*16];
    #pragma unroll
    for(int q=0;q<8;q++) dst[q] = __floats2half2_rn(m[2*q], m[2*q+1]);
  }
}

// ---------- radial MLP -> mix_h (fp16, sorted slots), single-H-buffer ----------
__global__ __launch_bounds__(256) void k_mix(const float* __restrict__ rad,
    const float* __restrict__ W1, const float* __restrict__ W2,
    const float* __restrict__ W3, const float* __restrict__ W4,
    const int* __restrict__ epos, __half* __restrict__ mix_h){
  __shared__ float sRadT[8*68];
  __shared__ float sW1[8*64];
  __shared__ float sH[64*68];
  int t = threadIdx.x;
  int be = blockIdx.x*64;
  for (int k=t;k<8*64;k+=256) sW1[k]=W1[k];
  for (int idx=t; idx<64*8; idx+=256){ int e=idx>>3, k=idx&7; sRadT[k*68+e]=rad[(size_t)(be+e)*8+k]; }
  __syncthreads();
  int e0 = (t>>4)*4, j0 = (t&15)*4;
  {
    float acc[4][4];
    #pragma unroll
    for(int a=0;a<4;a++){ acc[a][0]=0;acc[a][1]=0;acc[a][2]=0;acc[a][3]=0; }
    #pragma unroll
    for(int k=0;k<8;k++){
      float4 h = *(const float4*)&sRadT[k*68+e0];
      float4 w = *(const float4*)&sW1[k*64+j0];
      acc[0][0]+=h.x*w.x; acc[0][1]+=h.x*w.y; acc[0][2]+=h.x*w.z; acc[0][3]+=h.x*w.w;
      acc[1][0]+=h.y*w.x; acc[1][1]+=h.y*w.y; acc[1][2]+=h.y*w.z; acc[1][3]+=h.y*w.w;
      acc[2][0]+=h.z*w.x; acc[2][1]+=h.z*w.y; acc[2][2]+=h.z*w.z; acc[2][3]+=h.z*w.w;
      acc[3][0]+=h.w*w.x; acc[3][1]+=h.w*w.y; acc[3][2]+=h.w*w.z; acc[3][3]+=h.w*w.w;
    }
    #pragma unroll
    for(int b=0;b<4;b++){
      float4 v; v.x=silu(acc[0][b]); v.y=silu(acc[1][b]); v.z=silu(acc[2][b]); v.w=silu(acc[3][b]);
      *(float4*)&sH[(j0+b)*68+e0] = v;
    }
  }
  __syncthreads();
  {
    float acc[4][4];
    #pragma unroll
    for(int a=0;a<4;a++){ acc[a][0]=0;acc[a][1]=0;acc[a][2]=0;acc[a][3]=0; }
    for(int k=0;k<64;k++){
      float4 h = *(const float4*)&sH[k*68+e0];
      float4 w = *(const float4*)&W2[k*64+j0];
      acc[0][0]+=h.x*w.x; acc[0][1]+=h.x*w.y; acc[0][2]+=h.x*w.z; acc[0][3]+=h.x*w.w;
      acc[1][0]+=h.y*w.x; acc[1][1]+=h.y*w.y; acc[1][2]+=h.y*w.z; acc[1][3]+=h.y*w.w;
      acc[2][0]+=h.z*w.x; acc[2][1]+=h.z*w.y; acc[2][2]+=h.z*w.z; acc[2][3]+=h.z*w.w;
      acc[3][0]+=h.w*w.x; acc[3][1]+=h.w*w.y; acc[3][2]+=h.w*w.z; acc[3][3]+=h.w*w.w;
    }
    __syncthreads();
    #pragma unroll
    for(int b=0;b<4;b++){
      float4 v; v.x=silu(acc[0][b]); v.y=silu(acc[1][b]); v.z=silu(acc[2][b]); v.w=silu(acc[3][b]);
      *(float4*)&sH[(j0+b)*68+e0] = v;
    }
  }
  __syncthreads();
  {
    float acc[4][4];
    #pragma unroll
    for(int a=0;a<4;a++){ acc[a][0]=0;acc[a][1]=0;acc[a][2]=0;acc[a][3]=0; }
    for(int k=0;k<64;k++){
      float4 h = *(const float4*)&sH[k*68+e0];
      float4 w = *(const float4*)&W3[k*64+j0];
      acc[0][0]+=h.x*w.x; acc[0][1]+=h.x*w.y; acc[0][2]+=h.x*w.z; acc[0][3]+=h.x*w.w;
      acc[1][0]+=h.y*w.x; acc[1][1]+=h.y*w.y; acc[1][2]+=h.y*w.z; acc[1][3]+=h.y*w.w;
      acc[2][0]+=h.z*w.x; acc[2][1]+=h.z*w.y; acc[2][2]+=h.z*w.z; acc[2][3]+=h.z*w.w;
      acc[3][0]+=h.w*w.x; acc[3][1]+=h.w*w.y; acc[3][2]+=h.w*w.z; acc[3][3]+=h.w*w.w;
    }
    __syncthreads();
    #pragma unroll
    for(int b=0;b<4;b++){
      float4 v; v.x=silu(acc[0][b]); v.y=silu(acc[1][b]); v.z=silu(acc[2][b]); v.w=silu(acc[3][b]);
      *(float4*)&sH[(j0+b)*68+e0] = v;
    }
  }
  __syncthreads();
  {
    int cc0 = (t&63)*4, g = t>>6;
    float acc[4][4][4];
    #pragma unroll
    for(int r=0;r<4;r++)
      #pragma unroll
      for(int a=0;a<4;a++){ acc[r][a][0]=0;acc[r][a][1]=0;acc[r][a][2]=0;acc[r][a][3]=0; }
    for(int k=0;k<64;k++){
      float4 w = *(const float4*)&W4[k*256+cc0];
      #pragma unroll
      for(int r=0;r<4;r++){
        float4 h = *(const float4*)&sH[k*68 + (g+4*r)*4];
        acc[r][0][0]+=h.x*w.x; acc[r][0][1]+=h.x*w.y; acc[r][0][2]+=h.x*w.z; acc[r][0][3]+=h.x*w.w;
        acc[r][1][0]+=h.y*w.x; acc[r][1][1]+=h.y*w.y; acc[r][1][2]+=h.y*w.z; acc[r][1][3]+=h.y*w.w;
        acc[r][2][0]+=h.z*w.x; acc[r][2][1]+=h.z*w.y; acc[r][2][2]+=h.z*w.z; acc[r][2][3]+=h.z*w.w;
        acc[r][3][0]+=h.w*w.x; acc[r][3][1]+=h.w*w.y; acc[r][3][2]+=h.w*w.z; acc[r][3][3]+=h.w*w.w;
      }
    }
    #pragma unroll
    for(int r=0;r<4;r++)
      #pragma unroll
      for(int a=0;a<4;a++){
        int e = (g+4*r)*4 + a;
        size_t ep = (size_t)epos[be+e];
        __half2* dst = (__half2*)&mix_h[ep*256 + cc0];
        dst[0]=__floats2half2_rn(acc[r][a][0], acc[r][a][1]);
        dst[1]=__floats2half2_rn(acc[r][a][2], acc[r][a][3]);
      }
  }
}

// ---------- edge gather: fp16 x, array-free, pipelined ----------
__global__ __launch_bounds__(256) void k_gather(
    const __half* __restrict__ xh, const __half* __restrict__ mix_h,
    const __half* __restrict__ M_h,
    const int* __restrict__ off, const int* __restrict__ ssend,
    float* __restrict__ agg)
{
  __shared__ __align__(16) float sP[4096];
  __shared__ int sSnd[256];
  int t=threadIdx.x, w=t>>6, l=t&63, lc=l&31, kh=(l>>5)*8;
  bool lohalf = (l>>5)==0;
  int n = blockIdx.x;
  int base = off[n];
  int deg  = off[n+1]-base; if (deg>256) deg=256;
  for (int d=t; d<deg; d+=256) sSnd[d]=ssend[base+d];
  __syncthreads();

  float a0=0,a1=0,a2=0,a3=0,a4=0,a5=0,a6=0,a7=0;
  float b0=0,b1=0,b2=0,b3=0,b4=0,b5=0,b6=0,b7=0;

  uint4 pa, pb;   // prefetched fp16 x row: 16 halfs
  if (w < deg){
    int snd0 = sSnd[w];
    const __half* xr = xh + (size_t)snd0*512 + lc*16;
    pa = *(const uint4*)&xr[0];
    pb = *(const uint4*)&xr[8];
  }

  for (int d=w; d<deg; d+=4){
    int slot = base+d;
    uint4 ua=pa, ub=pb;
    int dn = d+4;
    if (dn < deg){
      int snd2 = sSnd[dn];
      const __half* xr2 = xh + (size_t)snd2*512 + lc*16;
      pa = *(const uint4*)&xr2[0];
      pb = *(const uint4*)&xr2[8];
    }
    // convert x halfs -> 16 named floats
    float2 c0=__half22float2(__builtin_bit_cast(__half2, ua.x));
    float2 c1=__half22float2(__builtin_bit_cast(__half2, ua.y));
    float2 c2=__half22float2(__builtin_bit_cast(__half2, ua.z));
    float2 c3=__half22float2(__builtin_bit_cast(__half2, ua.w));
    float2 c4=__half22float2(__builtin_bit_cast(__half2, ub.x));
    float2 c5=__half22float2(__builtin_bit_cast(__half2, ub.y));
    float2 c6=__half22float2(__builtin_bit_cast(__half2, ub.z));
    float2 c7=__half22float2(__builtin_bit_cast(__half2, ub.w));
    float fx0=c0.x, fx1=c0.y, fx2=c1.x, fx3=c1.y;
    float fx4=c2.x, fx5=c2.y, fx6=c3.x, fx7=c3.y;
    float fx8=c4.x, fx9=c4.y, fx10=c5.x, fx11=c5.y;
    float fx12=c6.x, fx13=c6.y, fx14=c7.x, fx15=c7.y;
    // mix factors
    const float* mrowf = (const float*)(mix_h + (size_t)slot*256);
    float2 mraw = *(const float2*)&mrowf[lc*2];
    float2 traw = *(const float2*)&mrowf[64 + lc*2];
    float2 mf01 = __half22float2(__builtin_bit_cast(__half2, mraw.x));
    float2 mf23 = __half22float2(__builtin_bit_cast(__half2, mraw.y));
    float2 mt01 = __half22float2(__builtin_bit_cast(__half2, traw.x));
    float2 mt23 = __half22float2(__builtin_bit_cast(__half2, traw.y));
    const __half* Mrow = M_h + (size_t)slot*256 + kh;
    float t0=0,t1=0,t2=0,t3=0,t4=0,t5=0,t6=0,t7=0;
#define ACCM(F,IOFF) { \
    float4 mr = *(const float4*)&Mrow[(IOFF)*16]; \
    float2 m01=__half22float2(__builtin_bit_cast(__half2, mr.x)); \
    float2 m23=__half22float2(__builtin_bit_cast(__half2, mr.y)); \
    float2 m45=__half22float2(__builtin_bit_cast(__half2, mr.z)); \
    float2 m67=__half22float2(__builtin_bit_cast(__half2, mr.w)); \
    t0+=(F)*m01.x; t1+=(F)*m01.y; t2+=(F)*m23.x; t3+=(F)*m23.y; \
    t4+=(F)*m45.x; t5+=(F)*m45.y; t6+=(F)*m67.x; t7+=(F)*m67.y; }
    ACCM(fx0,0)   ACCM(fx1,1)   ACCM(fx2,2)   ACCM(fx3,3)
    ACCM(fx4,4)   ACCM(fx5,5)   ACCM(fx6,6)   ACCM(fx7,7)
    ACCM(fx8,8)   ACCM(fx9,9)   ACCM(fx10,10) ACCM(fx11,11)
    ACCM(fx12,12) ACCM(fx13,13) ACCM(fx14,14) ACCM(fx15,15)
#undef ACCM
    float mg0 = lohalf ? mf01.x : mf23.x;
    float mg1 = lohalf ? mf01.y : mf23.y;
    float mg4 = lohalf ? mf23.x : mf23.y;
    float ng0 = lohalf ? mt01.x : mt23.x;
    float ng1 = lohalf ? mt01.y : mt23.y;
    float ng4 = lohalf ? mt23.x : mt23.y;
    float f0 = lohalf ? fx0 : fx8;
    float f1 = lohalf ? fx1 : fx9;
    float f2 = lohalf ? fx2 : fx10;
    float f3 = lohalf ? fx3 : fx11;
    float f4 = lohalf ? fx4 : fx12;
    float f5 = lohalf ? fx5 : fx13;
    float f6 = lohalf ? fx6 : fx14;
    float f7 = lohalf ? fx7 : fx15;
    a0 += f0*mg0;  b0 += t0*ng0;
    a1 += f1*mg1;  b1 += t1*ng1;
    a2 += f2*mg1;  b2 += t2*ng1;
    a3 += f3*mg1;  b3 += t3*ng1;
    a4 += f4*mg4;  b4 += t4*ng4;
    a5 += f5*mg4;  b5 += t5*ng4;
    a6 += f6*mg4;  b6 += t6*ng4;
    a7 += f7*mg4;  b7 += t7*ng4;
  }

  int ibF = w*1024 + lc*16 + kh;
  int ibT = w*1024 + (32+lc)*16 + kh;
  sP[ibF+0]=a0; sP[ibF+1]=a1; sP[ibF+2]=a2; sP[ibF+3]=a3;
  sP[ibF+4]=a4; sP[ibF+5]=a5; sP[ibF+6]=a6; sP[ibF+7]=a7;
  sP[ibT+0]=b0; sP[ibT+1]=b1; sP[ibT+2]=b2; sP[ibT+3]=b3;
  sP[ibT+4]=b4; sP[ibT+5]=b5; sP[ibT+6]=b6; sP[ibT+7]=b7;
  __syncthreads();
  for (int idx=t; idx<1024; idx+=256)
    agg[(size_t)n*1024 + idx] = sP[idx]+sP[1024+idx]+sP[2048+idx]+sP[3072+idx];
}

// ---------- tail: Wdown + contraction + output (2 nodes/block, float2 lanes) ----------
__global__ __launch_bounds__(256) void k_tail(
    const float* __restrict__ agg, const float* __restrict__ x,
    const float* __restrict__ Wdown,
    const int* __restrict__ u3i, const float* __restrict__ u3v,
    const int* __restrict__ u2i, const float* __restrict__ u2v,
    const int* __restrict__ u1i, const float* __restrict__ u1v,
    const int* __restrict__ uoff,
    const float* __restrict__ w3, const float* __restrict__ w2,
    const float* __restrict__ w1,
    const float* __restrict__ Wsc, const float* __restrict__ Wout,
    const int* __restrict__ species,
    float* __restrict__ out)
{
  __shared__ float sAgg[2048];
  __shared__ float sy[1024];
  __shared__ float sPart[1024];

  int n0 = blockIdx.x*2, t = threadIdx.x;
  #pragma unroll
  for(int q=0;q<8;q++) sAgg[q*256+t] = agg[(size_t)n0*1024 + q*256 + t];
  __syncthreads();

  {
    int h=t>>7, ii=(t>>3)&15, f0=(t&7)*4;
    const float* W = Wdown + l_of(ii)*2048;
    float ax=0.f, ay=0.f, az=0.f, aw=0.f;
    for(int c=0;c<64;c++){
      float a = sAgg[h*1024 + c*16 + ii];
      float4 wv = *(const float4*)&W[c*32+f0];
      ax+=a*wv.x; ay+=a*wv.y; az+=a*wv.z; aw+=a*wv.w;
    }
    sy[h*512 + ii*32 + f0+0]=ax*0.0625f;
    sy[h*512 + ii*32 + f0+1]=ay*0.0625f;
    sy[h*512 + ii*32 + f0+2]=az*0.0625f;
    sy[h*512 + ii*32 + f0+3]=aw*0.0625f;
  }
  __syncthreads();

  float* sXn = sAgg;
  float* sB  = sAgg + 1024;
  #pragma unroll
  for(int q=0;q<4;q++){ int idx=q*256+t;
    sXn[idx] = x[(size_t)(n0+(idx>>9))*512 + (idx&511)]; }

  {
    int p = __builtin_amdgcn_readfirstlane(t>>6);
    int l = t&63, g = l>>4, nq = g&1, ihalf = g>>1, c0 = (l&15)*2;
    int spec = species[n0+nq];
    const float* syn = &sy[nq*512 + c0];
    #pragma unroll
    for(int ii2=0; ii2<2; ii2++){
      int i = ihalf*2 + ii2;
      float r3x=0.f, r3y=0.f;
      #pragma unroll 4
      for(int q=uoff[i]+p; q<uoff[i+1]; q+=4){
        int id=u3i[q]; float v=u3v[q];
        int a=(id>>10)&15, b=(id>>6)&15, j=(id>>2)&15;
        float2 ya=*(const float2*)&syn[a*32];
        float2 yb=*(const float2*)&syn[b*32];
        float2 yj=*(const float2*)&syn[j*32];
        r3x += v*ya.x*yb.x*yj.x;
        r3y += v*ya.y*yb.y*yj.y;
      }
      float r2x=0.f, r2y=0.f;
      #pragma unroll 4
      for(int q=uoff[5+i]+p; q<uoff[5+i+1]; q+=4){
        int id=u2i[q]; float v=u2v[q];
        int a=(id>>6)&15, b=(id>>2)&15;
        float2 ya=*(const float2*)&syn[a*32];
        float2 yb=*(const float2*)&syn[b*32];
        r2x += v*ya.x*yb.x;
        r2y += v*ya.y*yb.y;
      }
      float r1x=0.f, r1y=0.f;
      for(int q=uoff[10+i]+p; q<uoff[10+i+1]; q+=4){
        int id=u1i[q]; float v=u1v[q];
        int a=(id>>2)&15;
        float2 ya=*(const float2*)&syn[a*32];
        r1x += v*ya.x;
        r1y += v*ya.y;
      }
      int wo = spec*64 + ((i==0)?0:32) + c0;
      float2 wa = *(const float2*)&w3[wo];
      float2 wb = *(const float2*)&w2[wo];
      float2 wc = *(const float2*)&w1[wo];
      float2 res;
      res.x = r3x*wa.x + r2x*wb.x + r1x*wc.x;
      res.y = r3y*wa.y + r2y*wb.y + r1y*wc.y;
      *(float2*)&sPart[p*256 + i*64 + nq*32 + c0] = res;
    }
  }
  __syncthreads();

  {
    int nq=t>>7, rem=t&127, c=rem>>2, i=rem&3;
    int o = i*64 + nq*32 + c;
    sB[nq*128 + c*4 + i] = sPart[o]+sPart[256+o]+sPart[512+o]+sPart[768+o];
  }
  __syncthreads();

  {
    int nq=t>>7, rem=t&127, f=rem>>2, i3=rem&3;
    int sp2 = species[n0+nq];
    int sel = (i3==0)?0:1;
    const float* Wo = Wout + sel*1024;
    const float* Ws = Wsc + (size_t)(sel*64+sp2)*1024;
    float o=0.f, sc=0.f;
    for(int c2=0;c2<32;c2++){
      o  += sB[nq*128 + c2*4 + i3]*Wo[c2*32+f];
      sc += sXn[nq*512 + c2*16 + i3]*Ws[c2*32+f];
    }
    out[(size_t)(n0+nq)*128 + f*4 + i3] = o + sc;
  }
}

extern "C" void kernel_launch(void* const* d_in, const int* in_sizes, int n_in,
                              void* d_out, int out_size, void* d_ws, size_t ws_size,
                              hipStream_t stream){
  (void)in_sizes; (void)n_in; (void)out_size; (void)ws_size;
  const float* feats = (const float*)d_in[0];
  const float* vec   = (const float*)d_in[1];
  const float* rad   = (const float*)d_in[2];
  const float* Wup   = (const float*)d_in[3];
  const float* CG    = (const float*)d_in[4];
  const float* Wr1   = (const float*)d_in[5];
  const float* Wr2   = (const float*)d_in[6];
  const float* Wr3   = (const float*)d_in[7];
  const float* Wr4   = (const float*)d_in[8];
  const float* Wdown = (const float*)d_in[9];
  const float* U3    = (const float*)d_in[10];
  const float* U2    = (const float*)d_in[11];
  const float* U1    = (const float*)d_in[12];
  const float* w3    = (const float*)d_in[13];
  const float* w2    = (const float*)d_in[14];
  const float* w1    = (const float*)d_in[15];
  const float* Wsc   = (const float*)d_in[16];
  const float* Wout  = (const float*)d_in[17];
  const int* species = (const int*)d_in[18];
  const int* senders = (const int*)d_in[19];
  const int* recv    = (const int*)d_in[20];
  float* out = (float*)d_out;

  char* w = (char*)d_ws;
  float* x     = (float*)w;  w += (size_t)NN*512*4;
  __half* xh   = (__half*)w; w += (size_t)NN*512*2;
  __half* mixh = (__half*)w; w += (size_t)EE*256*2;
  __half* Mh   = (__half*)w; w += (size_t)EE*256*2;
  float* agg   = (float*)w;  w += (size_t)NN*1024*4;
  int* cnt    = (int*)w;    w += (size_t)NN*4;
  int* off    = (int*)w;    w += (size_t)(NN+1)*4;
  int* pos    = (int*)w;    w += (size_t)EE*4;
  int* elist  = (int*)w;    w += (size_t)EE*4;
  int* epos   = (int*)w;    w += (size_t)EE*4;
  int* ssend  = (int*)w;    w += (size_t)EE*4;
  int* u3i    = (int*)w;    w += 16384*4;
  float* u3v  = (float*)w;  w += 16384*4;
  int* u2i    = (int*)w;    w += 1024*4;
  float* u2v  = (float*)w;  w += 1024*4;
  int* u1i    = (int*)w;    w += 64*4;
  float* u1v  = (float*)w;  w += 64*4;
  int* uoff   = (int*)w;    w += 16*4;

  hipMemsetAsync(cnt, 0, (size_t)NN*4, stream);
  k_xc<<<NN/4+3,512,0,stream>>>(feats,Wup,x,xh,U3,U2,U1,u3i,u3v,u2i,u2v,u1i,u1v,uoff);
  k_count<<<EE/256,256,0,stream>>>(recv,cnt,pos);
  k_scan<<<1,256,0,stream>>>(cnt,off);
  k_fill<<<EE/256,256,0,stream>>>(recv,off,pos,elist);
  k_sortYM<<<NN/4,256,0,stream>>>(senders,off,elist,vec,CG,epos,ssend,Mh);
  k_mix<<<EE/64,256,0,stream>>>(rad,Wr1,Wr2,Wr3,Wr4,epos,mixh);
  k_gather<<<NN,256,0,stream>>>(xh,mixh,Mh,off,ssend,agg);
  k_tail<<<NN/2,256,0,stream>>>(agg,x,Wdown,u3i,u3v,u2i,u2v,u1i,u1v,uoff,
                                w3,w2,w1,Wsc,Wout,species,out);
}

// Round 22
// 278.504 us; speedup vs baseline: 1.7756x; 1.0101x over previous
//
#include <hip/hip_runtime.h>
#include <hip/hip_fp16.h>
#include <math.h>

#define NN 4096
#define FF 32
#define DD 16
#define EE 65536

__device__ __forceinline__ int l_of(int i){ return (i==0)?0:(i<4)?1:(i<9)?2:3; }
__device__ __forceinline__ float silu(float v){ return v/(1.f+expf(-v)); }

// ---------- x (4 nodes/block) + U-compact + edge-count merged via block ranges ----------
__global__ __launch_bounds__(512) void k_xc(const float* __restrict__ feats,
        const float* __restrict__ Wup, float* __restrict__ x, __half* __restrict__ xh,
        const float* __restrict__ U3, const float* __restrict__ U2,
        const float* __restrict__ U1,
        int* __restrict__ u3i, float* __restrict__ u3v,
        int* __restrict__ u2i, float* __restrict__ u2v,
        int* __restrict__ u1i, float* __restrict__ u1v, int* __restrict__ uoff,
        const int* __restrict__ recv, int* __restrict__ cnt, int* __restrict__ pos){
  __shared__ float sF[4*512];
  __shared__ float sW[4*FF*FF];
  int b = blockIdx.x, t = threadIdx.x;
  if (b < NN/4){
    int n0 = b*4;
    #pragma unroll
    for(int q=0;q<4;q++) sF[q*512+t] = feats[(size_t)(n0+q)*512 + t];
    for (int k=t;k<4*FF*FF;k+=512) sW[k]=Wup[k];
    __syncthreads();
    int f = t>>4, i = t&15;
    const float* W = &sW[l_of(i)*FF*FF];
    #pragma unroll
    for(int q=0;q<4;q++){
      float a=0.f;
      #pragma unroll
      for (int c=0;c<FF;c++) a += sF[q*512 + c*DD+i]*W[c*FF+f];
      x[(size_t)(n0+q)*512 + t] = a;
      xh[(size_t)(n0+q)*512 + t] = __float2half(a);
    }
  } else if (b < NN/4 + 3){
    int slot = b - NN/4;
    int (*cnts)[4]  = (int(*)[4])sF;
    int (*bases)[4] = (int(*)[4])(sF+1024);
    const float* src; int nsz; int* oi; float* ov;
    if(slot==0){src=U3;nsz=16384;oi=u3i;ov=u3v;}
    else if(slot==1){src=U2;nsz=1024;oi=u2i;ov=u2v;}
    else {src=U1;nsz=64;oi=u1i;ov=u1v;}
    if (t < 256){
      int chunk=(nsz+255)/256;
      int lo=t*chunk, hi=min(nsz,lo+chunk); if(lo>nsz) lo=nsz;
      int c0=0,c1=0,c2=0,c3=0;
      for(int q=lo;q<hi;q++) if(src[q]!=0.f){
        int i=q&3;
        if(i==0)c0++; else if(i==1)c1++; else if(i==2)c2++; else c3++;
      }
      cnts[t][0]=c0; cnts[t][1]=c1; cnts[t][2]=c2; cnts[t][3]=c3;
    }
    __syncthreads();
    if(t==0){
      int a=0;
      for(int i=0;i<4;i++){ uoff[slot*5+i]=a;
        for(int q=0;q<256;q++){ bases[q][i]=a; a+=cnts[q][i]; } }
      uoff[slot*5+4]=a;
    }
    __syncthreads();
    if (t < 256){
      int chunk=(nsz+255)/256;
      int lo=t*chunk, hi=min(nsz,lo+chunk); if(lo>nsz) lo=nsz;
      int w0=bases[t][0], w1_=bases[t][1], w2_=bases[t][2], w3_=bases[t][3];
      for(int q=lo;q<hi;q++){ float v=src[q]; if(v!=0.f){
        int i=q&3;
        if(i==0){ oi[w0]=q; ov[w0]=v; w0++; }
        else if(i==1){ oi[w1_]=q; ov[w1_]=v; w1_++; }
        else if(i==2){ oi[w2_]=q; ov[w2_]=v; w2_++; }
        else { oi[w3_]=q; ov[w3_]=v; w3_++; }
      } }
    }
  } else {
    // edge count: 128 blocks × 512 threads == EE  (cnt pre-zeroed by memset)
    int e = (b - (NN/4 + 3))*512 + t;
    pos[e] = atomicAdd(&cnt[recv[e]], 1);
  }
}

// ---------- CSR scan / fill ----------
__global__ __launch_bounds__(256) void k_scan(const int* __restrict__ cnt, int* __restrict__ off){
  __shared__ int sums[256]; __shared__ int bases[256];
  int t=threadIdx.x;
  int local[16]; int s=0;
  #pragma unroll
  for(int k=0;k<16;k++){ local[k]=cnt[t*16+k]; s+=local[k]; }
  sums[t]=s; __syncthreads();
  if(t==0){ int a=0; for(int q=0;q<256;q++){ bases[q]=a; a+=sums[q]; } }
  __syncthreads();
  int acc=bases[t];
  #pragma unroll
  for(int k=0;k<16;k++){ off[t*16+k]=acc; acc+=local[k]; }
  if(t==255) off[NN]=acc;
}
__global__ void k_fill(const int* __restrict__ recv, const int* __restrict__ off,
                       const int* __restrict__ pos, int* __restrict__ elist){
  int e=blockIdx.x*256+threadIdx.x; elist[off[recv[e]]+pos[e]]=e; }

// ---------- sort + YM fused ----------
__global__ __launch_bounds__(256) void k_sortYM(const int* __restrict__ senders,
    const int* __restrict__ off, const int* __restrict__ elist,
    const float* __restrict__ vec, const float* __restrict__ CG,
    int* __restrict__ epos, int* __restrict__ ssend, __half* __restrict__ M_h){
  __shared__ int buf[4][256];
  __shared__ int rbuf[4][256];
  int t=threadIdx.x, w=t>>6, l=t&63;
  int n = blockIdx.x*4 + w;
  int base = off[n];
  int deg = off[n+1]-base; if (deg>256) deg=256;
  for(int d=l; d<deg; d+=64) buf[w][d]=elist[base+d];
  __syncthreads();
  for(int d=l; d<deg; d+=64){
    int v=buf[w][d]; int r=0;
    for(int q=0;q<deg;q++) r += (buf[w][q]<v);
    epos[v] = base + r;
    rbuf[w][d] = r;
    ssend[base+r] = senders[v];
  }
  int il = l&15;
  const float* cgr = CG + il*240;
  for(int d0=(l>>4); d0<deg; d0+=4){
    int v = buf[w][d0];
    int slot = base + rbuf[w][d0];
    float vx=vec[(size_t)v*3+0], vy=vec[(size_t)v*3+1], vz=vec[(size_t)v*3+2];
    float r2=vx*vx+vy*vy+vz*vz;
    float inv = (r2==0.f)?1.f:rsqrtf(r2);
    float X=vx*inv, Y=vy*inv, Z=vz*inv;
    const float s3=1.7320508075688772f, s5=2.23606797749979f, s7=2.6457513110645907f;
    const float s15=3.872983346207417f, s42=6.48074069840786f, s70=8.366600265340756f, s105=10.246950765959598f;
    float y[15];
    y[0]=s3*X; y[1]=s3*Y; y[2]=s3*Z;
    y[3]=s15*X*Y; y[4]=s15*Y*Z; y[5]=0.5f*s5*(3.f*Z*Z-1.f); y[6]=s15*X*Z; y[7]=0.5f*s15*(X*X-Y*Y);
    y[8]=0.25f*s70*Y*(3.f*X*X-Y*Y); y[9]=s105*X*Y*Z; y[10]=0.25f*s42*Y*(5.f*Z*Z-1.f);
    y[11]=0.5f*s7*Z*(5.f*Z*Z-3.f); y[12]=0.25f*s42*X*(5.f*Z*Z-1.f);
    y[13]=0.5f*s105*Z*(X*X-Y*Y); y[14]=0.25f*s70*X*(X*X-3.f*Y*Y);
    float m[16];
    #pragma unroll
    for(int k=0;k<16;k++) m[k]=0.f;
    #pragma unroll
    for(int j=0;j<15;j++){
      float yj = y[j];
      #pragma unroll
      for(int q=0;q<4;q++){
        float4 c4 = *(const float4*)&cgr[j*16 + q*4];
        m[q*4+0]+=yj*c4.x; m[q*4+1]+=yj*c4.y; m[q*4+2]+=yj*c4.z; m[q*4+3]+=yj*c4.w;
      }
    }
    __half2* dst = (__half2*)&M_h[(size_t)slot*256 + il*16];
    #pragma unroll
    for(int q=0;q<8;q++) dst[q] = __floats2half2_rn(m[2*q], m[2*q+1]);
  }
}

// ---------- radial MLP -> mix_h (fp16, sorted slots), single-H-buffer ----------
__global__ __launch_bounds__(256) void k_mix(const float* __restrict__ rad,
    const float* __restrict__ W1, const float* __restrict__ W2,
    const float* __restrict__ W3, const float* __restrict__ W4,
    const int* __restrict__ epos, __half* __restrict__ mix_h){
  __shared__ float sRadT[8*68];
  __shared__ float sW1[8*64];
  __shared__ float sH[64*68];
  int t = threadIdx.x;
  int be = blockIdx.x*64;
  for (int k=t;k<8*64;k+=256) sW1[k]=W1[k];
  for (int idx=t; idx<64*8; idx+=256){ int e=idx>>3, k=idx&7; sRadT[k*68+e]=rad[(size_t)(be+e)*8+k]; }
  __syncthreads();
  int e0 = (t>>4)*4, j0 = (t&15)*4;
  {
    float acc[4][4];
    #pragma unroll
    for(int a=0;a<4;a++){ acc[a][0]=0;acc[a][1]=0;acc[a][2]=0;acc[a][3]=0; }
    #pragma unroll
    for(int k=0;k<8;k++){
      float4 h = *(const float4*)&sRadT[k*68+e0];
      float4 w = *(const float4*)&sW1[k*64+j0];
      acc[0][0]+=h.x*w.x; acc[0][1]+=h.x*w.y; acc[0][2]+=h.x*w.z; acc[0][3]+=h.x*w.w;
      acc[1][0]+=h.y*w.x; acc[1][1]+=h.y*w.y; acc[1][2]+=h.y*w.z; acc[1][3]+=h.y*w.w;
      acc[2][0]+=h.z*w.x; acc[2][1]+=h.z*w.y; acc[2][2]+=h.z*w.z; acc[2][3]+=h.z*w.w;
      acc[3][0]+=h.w*w.x; acc[3][1]+=h.w*w.y; acc[3][2]+=h.w*w.z; acc[3][3]+=h.w*w.w;
    }
    #pragma unroll
    for(int b=0;b<4;b++){
      float4 v; v.x=silu(acc[0][b]); v.y=silu(acc[1][b]); v.z=silu(acc[2][b]); v.w=silu(acc[3][b]);
      *(float4*)&sH[(j0+b)*68+e0] = v;
    }
  }
  __syncthreads();
  {
    float acc[4][4];
    #pragma unroll
    for(int a=0;a<4;a++){ acc[a][0]=0;acc[a][1]=0;acc[a][2]=0;acc[a][3]=0; }
    for(int k=0;k<64;k++){
      float4 h = *(const float4*)&sH[k*68+e0];
      float4 w = *(const float4*)&W2[k*64+j0];
      acc[0][0]+=h.x*w.x; acc[0][1]+=h.x*w.y; acc[0][2]+=h.x*w.z; acc[0][3]+=h.x*w.w;
      acc[1][0]+=h.y*w.x; acc[1][1]+=h.y*w.y; acc[1][2]+=h.y*w.z; acc[1][3]+=h.y*w.w;
      acc[2][0]+=h.z*w.x; acc[2][1]+=h.z*w.y; acc[2][2]+=h.z*w.z; acc[2][3]+=h.z*w.w;
      acc[3][0]+=h.w*w.x; acc[3][1]+=h.w*w.y; acc[3][2]+=h.w*w.z; acc[3][3]+=h.w*w.w;
    }
    __syncthreads();
    #pragma unroll
    for(int b=0;b<4;b++){
      float4 v; v.x=silu(acc[0][b]); v.y=silu(acc[1][b]); v.z=silu(acc[2][b]); v.w=silu(acc[3][b]);
      *(float4*)&sH[(j0+b)*68+e0] = v;
    }
  }
  __syncthreads();
  {
    float acc[4][4];
    #pragma unroll
    for(int a=0;a<4;a++){ acc[a][0]=0;acc[a][1]=0;acc[a][2]=0;acc[a][3]=0; }
    for(int k=0;k<64;k++){
      float4 h = *(const float4*)&sH[k*68+e0];
      float4 w = *(const float4*)&W3[k*64+j0];
      acc[0][0]+=h.x*w.x; acc[0][1]+=h.x*w.y; acc[0][2]+=h.x*w.z; acc[0][3]+=h.x*w.w;
      acc[1][0]+=h.y*w.x; acc[1][1]+=h.y*w.y; acc[1][2]+=h.y*w.z; acc[1][3]+=h.y*w.w;
      acc[2][0]+=h.z*w.x; acc[2][1]+=h.z*w.y; acc[2][2]+=h.z*w.z; acc[2][3]+=h.z*w.w;
      acc[3][0]+=h.w*w.x; acc[3][1]+=h.w*w.y; acc[3][2]+=h.w*w.z; acc[3][3]+=h.w*w.w;
    }
    __syncthreads();
    #pragma unroll
    for(int b=0;b<4;b++){
      float4 v; v.x=silu(acc[0][b]); v.y=silu(acc[1][b]); v.z=silu(acc[2][b]); v.w=silu(acc[3][b]);
      *(float4*)&sH[(j0+b)*68+e0] = v;
    }
  }
  __syncthreads();
  {
    int cc0 = (t&63)*4, g = t>>6;
    float acc[4][4][4];
    #pragma unroll
    for(int r=0;r<4;r++)
      #pragma unroll
      for(int a=0;a<4;a++){ acc[r][a][0]=0;acc[r][a][1]=0;acc[r][a][2]=0;acc[r][a][3]=0; }
    for(int k=0;k<64;k++){
      float4 w = *(const float4*)&W4[k*256+cc0];
      #pragma unroll
      for(int r=0;r<4;r++){
        float4 h = *(const float4*)&sH[k*68 + (g+4*r)*4];
        acc[r][0][0]+=h.x*w.x; acc[r][0][1]+=h.x*w.y; acc[r][0][2]+=h.x*w.z; acc[r][0][3]+=h.x*w.w;
        acc[r][1][0]+=h.y*w.x; acc[r][1][1]+=h.y*w.y; acc[r][1][2]+=h.y*w.z; acc[r][1][3]+=h.y*w.w;
        acc[r][2][0]+=h.z*w.x; acc[r][2][1]+=h.z*w.y; acc[r][2][2]+=h.z*w.z; acc[r][2][3]+=h.z*w.w;
        acc[r][3][0]+=h.w*w.x; acc[r][3][1]+=h.w*w.y; acc[r][3][2]+=h.w*w.z; acc[r][3][3]+=h.w*w.w;
      }
    }
    #pragma unroll
    for(int r=0;r<4;r++)
      #pragma unroll
      for(int a=0;a<4;a++){
        int e = (g+4*r)*4 + a;
        size_t ep = (size_t)epos[be+e];
        __half2* dst = (__half2*)&mix_h[ep*256 + cc0];
        dst[0]=__floats2half2_rn(acc[r][a][0], acc[r][a][1]);
        dst[1]=__floats2half2_rn(acc[r][a][2], acc[r][a][3]);
      }
  }
}

// ---------- edge gather: fp16 x, array-free, pipelined ----------
__global__ __launch_bounds__(256) void k_gather(
    const __half* __restrict__ xh, const __half* __restrict__ mix_h,
    const __half* __restrict__ M_h,
    const int* __restrict__ off, const int* __restrict__ ssend,
    float* __restrict__ agg)
{
  __shared__ __align__(16) float sP[4096];
  __shared__ int sSnd[256];
  int t=threadIdx.x, w=t>>6, l=t&63, lc=l&31, kh=(l>>5)*8;
  bool lohalf = (l>>5)==0;
  int n = blockIdx.x;
  int base = off[n];
  int deg  = off[n+1]-base; if (deg>256) deg=256;
  for (int d=t; d<deg; d+=256) sSnd[d]=ssend[base+d];
  __syncthreads();

  float a0=0,a1=0,a2=0,a3=0,a4=0,a5=0,a6=0,a7=0;
  float b0=0,b1=0,b2=0,b3=0,b4=0,b5=0,b6=0,b7=0;

  uint4 pa, pb;
  if (w < deg){
    int snd0 = sSnd[w];
    const __half* xr = xh + (size_t)snd0*512 + lc*16;
    pa = *(const uint4*)&xr[0];
    pb = *(const uint4*)&xr[8];
  }

  for (int d=w; d<deg; d+=4){
    int slot = base+d;
    uint4 ua=pa, ub=pb;
    int dn = d+4;
    if (dn < deg){
      int snd2 = sSnd[dn];
      const __half* xr2 = xh + (size_t)snd2*512 + lc*16;
      pa = *(const uint4*)&xr2[0];
      pb = *(const uint4*)&xr2[8];
    }
    float2 c0=__half22float2(__builtin_bit_cast(__half2, ua.x));
    float2 c1=__half22float2(__builtin_bit_cast(__half2, ua.y));
    float2 c2=__half22float2(__builtin_bit_cast(__half2, ua.z));
    float2 c3=__half22float2(__builtin_bit_cast(__half2, ua.w));
    float2 c4=__half22float2(__builtin_bit_cast(__half2, ub.x));
    float2 c5=__half22float2(__builtin_bit_cast(__half2, ub.y));
    float2 c6=__half22float2(__builtin_bit_cast(__half2, ub.z));
    float2 c7=__half22float2(__builtin_bit_cast(__half2, ub.w));
    float fx0=c0.x, fx1=c0.y, fx2=c1.x, fx3=c1.y;
    float fx4=c2.x, fx5=c2.y, fx6=c3.x, fx7=c3.y;
    float fx8=c4.x, fx9=c4.y, fx10=c5.x, fx11=c5.y;
    float fx12=c6.x, fx13=c6.y, fx14=c7.x, fx15=c7.y;
    const float* mrowf = (const float*)(mix_h + (size_t)slot*256);
    float2 mraw = *(const float2*)&mrowf[lc*2];
    float2 traw = *(const float2*)&mrowf[64 + lc*2];
    float2 mf01 = __half22float2(__builtin_bit_cast(__half2, mraw.x));
    float2 mf23 = __half22float2(__builtin_bit_cast(__half2, mraw.y));
    float2 mt01 = __half22float2(__builtin_bit_cast(__half2, traw.x));
    float2 mt23 = __half22float2(__builtin_bit_cast(__half2, traw.y));
    const __half* Mrow = M_h + (size_t)slot*256 + kh;
    float t0=0,t1=0,t2=0,t3=0,t4=0,t5=0,t6=0,t7=0;
#define ACCM(F,IOFF) { \
    float4 mr = *(const float4*)&Mrow[(IOFF)*16]; \
    float2 m01=__half22float2(__builtin_bit_cast(__half2, mr.x)); \
    float2 m23=__half22float2(__builtin_bit_cast(__half2, mr.y)); \
    float2 m45=__half22float2(__builtin_bit_cast(__half2, mr.z)); \
    float2 m67=__half22float2(__builtin_bit_cast(__half2, mr.w)); \
    t0+=(F)*m01.x; t1+=(F)*m01.y; t2+=(F)*m23.x; t3+=(F)*m23.y; \
    t4+=(F)*m45.x; t5+=(F)*m45.y; t6+=(F)*m67.x; t7+=(F)*m67.y; }
    ACCM(fx0,0)   ACCM(fx1,1)   ACCM(fx2,2)   ACCM(fx3,3)
    ACCM(fx4,4)   ACCM(fx5,5)   ACCM(fx6,6)   ACCM(fx7,7)
    ACCM(fx8,8)   ACCM(fx9,9)   ACCM(fx10,10) ACCM(fx11,11)
    ACCM(fx12,12) ACCM(fx13,13) ACCM(fx14,14) ACCM(fx15,15)
#undef ACCM
    float mg0 = lohalf ? mf01.x : mf23.x;
    float mg1 = lohalf ? mf01.y : mf23.y;
    float mg4 = lohalf ? mf23.x : mf23.y;
    float ng0 = lohalf ? mt01.x : mt23.x;
    float ng1 = lohalf ? mt01.y : mt23.y;
    float ng4 = lohalf ? mt23.x : mt23.y;
    float f0 = lohalf ? fx0 : fx8;
    float f1 = lohalf ? fx1 : fx9;
    float f2 = lohalf ? fx2 : fx10;
    float f3 = lohalf ? fx3 : fx11;
    float f4 = lohalf ? fx4 : fx12;
    float f5 = lohalf ? fx5 : fx13;
    float f6 = lohalf ? fx6 : fx14;
    float f7 = lohalf ? fx7 : fx15;
    a0 += f0*mg0;  b0 += t0*ng0;
    a1 += f1*mg1;  b1 += t1*ng1;
    a2 += f2*mg1;  b2 += t2*ng1;
    a3 += f3*mg1;  b3 += t3*ng1;
    a4 += f4*mg4;  b4 += t4*ng4;
    a5 += f5*mg4;  b5 += t5*ng4;
    a6 += f6*mg4;  b6 += t6*ng4;
    a7 += f7*mg4;  b7 += t7*ng4;
  }

  int ibF = w*1024 + lc*16 + kh;
  int ibT = w*1024 + (32+lc)*16 + kh;
  sP[ibF+0]=a0; sP[ibF+1]=a1; sP[ibF+2]=a2; sP[ibF+3]=a3;
  sP[ibF+4]=a4; sP[ibF+5]=a5; sP[ibF+6]=a6; sP[ibF+7]=a7;
  sP[ibT+0]=b0; sP[ibT+1]=b1; sP[ibT+2]=b2; sP[ibT+3]=b3;
  sP[ibT+4]=b4; sP[ibT+5]=b5; sP[ibT+6]=b6; sP[ibT+7]=b7;
  __syncthreads();
  for (int idx=t; idx<1024; idx+=256)
    agg[(size_t)n*1024 + idx] = sP[idx]+sP[1024+idx]+sP[2048+idx]+sP[3072+idx];
}

// ---------- tail: Wdown (both-h per thread) + contraction + output (2 nodes/block) ----------
__global__ __launch_bounds__(256) void k_tail(
    const float* __restrict__ agg, const float* __restrict__ x,
    const float* __restrict__ Wdown,
    const int* __restrict__ u3i, const float* __restrict__ u3v,
    const int* __restrict__ u2i, const float* __restrict__ u2v,
    const int* __restrict__ u1i, const float* __restrict__ u1v,
    const int* __restrict__ uoff,
    const float* __restrict__ w3, const float* __restrict__ w2,
    const float* __restrict__ w1,
    const float* __restrict__ Wsc, const float* __restrict__ Wout,
    const int* __restrict__ species,
    float* __restrict__ out)
{
  __shared__ float sAgg[2048];
  __shared__ float sy[1024];
  __shared__ float sPart[1024];

  int n0 = blockIdx.x*2, t = threadIdx.x;
  #pragma unroll
  for(int q=0;q<8;q++) sAgg[q*256+t] = agg[(size_t)n0*1024 + q*256 + t];
  __syncthreads();

  // Wdown: thread -> (ii=t>>4, fp=(t&15)*2), computes BOTH h (2x W reuse, float2 W)
  {
    int ii=t>>4, fp=(t&15)*2;
    const float* W = Wdown + l_of(ii)*2048;
    float s00=0.f,s01=0.f,s10=0.f,s11=0.f;   // [h][f]
    for(int c=0;c<64;c++){
      float2 wv = *(const float2*)&W[c*32+fp];
      float av0 = sAgg[c*16 + ii];
      float av1 = sAgg[1024 + c*16 + ii];
      s00+=av0*wv.x; s01+=av0*wv.y;
      s10+=av1*wv.x; s11+=av1*wv.y;
    }
    sy[ii*32 + fp]       = s00*0.0625f;
    sy[ii*32 + fp+1]     = s01*0.0625f;
    sy[512 + ii*32 + fp]   = s10*0.0625f;
    sy[512 + ii*32 + fp+1] = s11*0.0625f;
  }
  __syncthreads();

  float* sXn = sAgg;
  float* sB  = sAgg + 1024;
  #pragma unroll
  for(int q=0;q<4;q++){ int idx=q*256+t;
    sXn[idx] = x[(size_t)(n0+(idx>>9))*512 + (idx&511)]; }

  {
    int p = __builtin_amdgcn_readfirstlane(t>>6);
    int l = t&63, g = l>>4, nq = g&1, ihalf = g>>1, c0 = (l&15)*2;
    int spec = species[n0+nq];
    const float* syn = &sy[nq*512 + c0];
    #pragma unroll
    for(int ii2=0; ii2<2; ii2++){
      int i = ihalf*2 + ii2;
      float r3x=0.f, r3y=0.f;
      #pragma unroll 4
      for(int q=uoff[i]+p; q<uoff[i+1]; q+=4){
        int id=u3i[q]; float v=u3v[q];
        int a=(id>>10)&15, b=(id>>6)&15, j=(id>>2)&15;
        float2 ya=*(const float2*)&syn[a*32];
        float2 yb=*(const float2*)&syn[b*32];
        float2 yj=*(const float2*)&syn[j*32];
        r3x += v*ya.x*yb.x*yj.x;
        r3y += v*ya.y*yb.y*yj.y;
      }
      float r2x=0.f, r2y=0.f;
      #pragma unroll 4
      for(int q=uoff[5+i]+p; q<uoff[5+i+1]; q+=4){
        int id=u2i[q]; float v=u2v[q];
        int a=(id>>6)&15, b=(id>>2)&15;
        float2 ya=*(const float2*)&syn[a*32];
        float2 yb=*(const float2*)&syn[b*32];
        r2x += v*ya.x*yb.x;
        r2y += v*ya.y*yb.y;
      }
      float r1x=0.f, r1y=0.f;
      for(int q=uoff[10+i]+p; q<uoff[10+i+1]; q+=4){
        int id=u1i[q]; float v=u1v[q];
        int a=(id>>2)&15;
        float2 ya=*(const float2*)&syn[a*32];
        r1x += v*ya.x;
        r1y += v*ya.y;
      }
      int wo = spec*64 + ((i==0)?0:32) + c0;
      float2 wa = *(const float2*)&w3[wo];
      float2 wb = *(const float2*)&w2[wo];
      float2 wc = *(const float2*)&w1[wo];
      float2 res;
      res.x = r3x*wa.x + r2x*wb.x + r1x*wc.x;
      res.y = r3y*wa.y + r2y*wb.y + r1y*wc.y;
      *(float2*)&sPart[p*256 + i*64 + nq*32 + c0] = res;
    }
  }
  __syncthreads();

  {
    int nq=t>>7, rem=t&127, c=rem>>2, i=rem&3;
    int o = i*64 + nq*32 + c;
    sB[nq*128 + c*4 + i] = sPart[o]+sPart[256+o]+sPart[512+o]+sPart[768+o];
  }
  __syncthreads();

  {
    int nq=t>>7, rem=t&127, f=rem>>2, i3=rem&3;
    int sp2 = species[n0+nq];
    int sel = (i3==0)?0:1;
    const float* Wo = Wout + sel*1024;
    const float* Ws = Wsc + (size_t)(sel*64+sp2)*1024;
    float o=0.f, sc=0.f;
    for(int c2=0;c2<32;c2++){
      o  += sB[nq*128 + c2*4 + i3]*Wo[c2*32+f];
      sc += sXn[nq*512 + c2*16 + i3]*Ws[c2*32+f];
    }
    out[(size_t)(n0+nq)*128 + f*4 + i3] = o + sc;
  }
}

extern "C" void kernel_launch(void* const* d_in, const int* in_sizes, int n_in,
                              void* d_out, int out_size, void* d_ws, size_t ws_size,
                              hipStream_t stream){
  (void)in_sizes; (void)n_in; (void)out_size; (void)ws_size;
  const float* feats = (const float*)d_in[0];
  const float* vec   = (const float*)d_in[1];
  const float* rad   = (const float*)d_in[2];
  const float* Wup   = (const float*)d_in[3];
  const float* CG    = (const float*)d_in[4];
  const float* Wr1   = (const float*)d_in[5];
  const float* Wr2   = (const float*)d_in[6];
  const float* Wr3   = (const float*)d_in[7];
  const float* Wr4   = (const float*)d_in[8];
  const float* Wdown = (const float*)d_in[9];
  const float* U3    = (const float*)d_in[10];
  const float* U2    = (const float*)d_in[11];
  const float* U1    = (const float*)d_in[12];
  const float* w3    = (const float*)d_in[13];
  const float* w2    = (const float*)d_in[14];
  const float* w1    = (const float*)d_in[15];
  const float* Wsc   = (const float*)d_in[16];
  const float* Wout  = (const float*)d_in[17];
  const int* species = (const int*)d_in[18];
  const int* senders = (const int*)d_in[19];
  const int* recv    = (const int*)d_in[20];
  float* out = (float*)d_out;

  char* w = (char*)d_ws;
  float* x     = (float*)w;  w += (size_t)NN*512*4;
  __half* xh   = (__half*)w; w += (size_t)NN*512*2;
  __half* mixh = (__half*)w; w += (size_t)EE*256*2;
  __half* Mh   = (__half*)w; w += (size_t)EE*256*2;
  float* agg   = (float*)w;  w += (size_t)NN*1024*4;
  int* cnt    = (int*)w;    w += (size_t)NN*4;
  int* off    = (int*)w;    w += (size_t)(NN+1)*4;
  int* pos    = (int*)w;    w += (size_t)EE*4;
  int* elist  = (int*)w;    w += (size_t)EE*4;
  int* epos   = (int*)w;    w += (size_t)EE*4;
  int* ssend  = (int*)w;    w += (size_t)EE*4;
  int* u3i    = (int*)w;    w += 16384*4;
  float* u3v  = (float*)w;  w += 16384*4;
  int* u2i    = (int*)w;    w += 1024*4;
  float* u2v  = (float*)w;  w += 1024*4;
  int* u1i    = (int*)w;    w += 64*4;
  float* u1v  = (float*)w;  w += 64*4;
  int* uoff   = (int*)w;    w += 16*4;

  hipMemsetAsync(cnt, 0, (size_t)NN*4, stream);
  k_xc<<<NN/4+3+EE/512,512,0,stream>>>(feats,Wup,x,xh,U3,U2,U1,
                                       u3i,u3v,u2i,u2v,u1i,u1v,uoff,recv,cnt,pos);
  k_scan<<<1,256,0,stream>>>(cnt,off);
  k_fill<<<EE/256,256,0,stream>>>(recv,off,pos,elist);
  k_sortYM<<<NN/4,256,0,stream>>>(senders,off,elist,vec,CG,epos,ssend,Mh);
  k_mix<<<EE/64,256,0,stream>>>(rad,Wr1,Wr2,Wr3,Wr4,epos,mixh);
  k_gather<<<NN,256,0,stream>>>(xh,mixh,Mh,off,ssend,agg);
  k_tail<<<NN/2,256,0,stream>>>(agg,x,Wdown,u3i,u3v,u2i,u2v,u1i,u1v,uoff,
                                w3,w2,w1,Wsc,Wout,species,out);
}